// Round 6
// baseline (190.251 us; speedup 1.0000x reference)
//
#include <hip/hip_runtime.h>

typedef _Float16 f16;
typedef f16  f16x8 __attribute__((ext_vector_type(8)));
typedef f16  f16x4 __attribute__((ext_vector_type(4)));
typedef float f32x4 __attribute__((ext_vector_type(4)));

__device__ __forceinline__ void gld_lds16(const f16* g, void* l) {
  __builtin_amdgcn_global_load_lds((const __attribute__((address_space(1))) void*)g,
                                   (__attribute__((address_space(3))) void*)l,
                                   16, 0, 0);
}

enum { EPI_SCORES = 0, EPI_RELU = 2, EPI_OUT = 3, EPI_BIASR = 4 };

// C[M,N] = A[M,K] @ B[N,K]^T, 128x128 tile, BK=32, 4 waves (2x2), 16x16x32 f16 MFMA.
// 3-stage LDS pipeline, counted vmcnt (never 0 mid-loop), raw s_barrier, swizzled LDS.
template<int EPI, bool XMAP>
__global__ __launch_bounds__(256)
void gemm_bt(const f16* __restrict__ A, const f16* __restrict__ B, void* __restrict__ C,
             int lda, int ldb, int ldc, int K,
             long long sA, long long sB, long long sC,
             const float* __restrict__ bias, float scale,
             float* __restrict__ mmarr, int nmm,
             const float* __restrict__ wfb, const float* __restrict__ dvv,
             int nx, int nbz)
{
  __shared__ __align__(16) f16 As[3][128][32];
  __shared__ __align__(16) f16 Bs[3][128][32];
  const int tid  = threadIdx.x;
  const int lane = tid & 63;
  const int w    = tid >> 6;
  const int wm   = w >> 1, wn = w & 1;

  const int lin = blockIdx.x;
  int bz, bj;
  if constexpr (XMAP) {
    const int xcd = lin & 7, rest = lin >> 3;
    const int grp = rest / nbz;
    bj = rest - grp * nbz;
    bz = xcd + (grp << 3);
  } else {
    bz = lin / nbz; bj = lin - bz * nbz;
  }
  const int m0 = (bj / nx) * 128, n0 = (bj % nx) * 128;
  const f16* Ab = A + (size_t)bz * sA + (size_t)m0 * lda;
  const f16* Bb = B + (size_t)bz * sB + (size_t)n0 * ldb;

  f32x4 acc[4][4] = {};
  const int nsteps = K >> 5;

#define STAGE(bufb, ks)                                                              \
  {                                                                                  \
    const int k0_ = (ks) << 5;                                                       \
    _Pragma("unroll")                                                                \
    for (int i = 0; i < 2; ++i) {                                                    \
      const int ci = i * 256 + tid;                                                  \
      const int r  = ci >> 2;                                                        \
      const int sg = (ci & 3) ^ ((r >> 1) & 3);                                      \
      gld_lds16(Ab + (size_t)r * lda + k0_ + sg * 8,                                 \
                (char*)As + (bufb) + (size_t)(i * 256 + w * 64) * 16);               \
      gld_lds16(Bb + (size_t)r * ldb + k0_ + sg * 8,                                 \
                (char*)Bs + (bufb) + (size_t)(i * 256 + w * 64) * 16);               \
    }                                                                                \
  }

  STAGE(0, 0)
  STAGE(8192, 1)

  const int elemoff = (((lane >> 4) ^ ((lane >> 1) & 3)) << 3);

  int cur = 0;
  for (int t = 0; t < nsteps; ++t) {
    if (t + 1 < nsteps) asm volatile("s_waitcnt vmcnt(4)" ::: "memory");
    else                asm volatile("s_waitcnt vmcnt(0)" ::: "memory");
    __builtin_amdgcn_s_barrier();
    __builtin_amdgcn_sched_barrier(0);
    int st = cur + 2; if (st >= 3) st -= 3;
    if (t + 2 < nsteps) STAGE(st * 8192, t + 2)
    f16x8 af[4], bfr[4];
#pragma unroll
    for (int m = 0; m < 4; ++m)
      af[m] = *(const f16x8*)&As[cur][wm * 64 + m * 16 + (lane & 15)][elemoff];
#pragma unroll
    for (int n = 0; n < 4; ++n)
      bfr[n] = *(const f16x8*)&Bs[cur][wn * 64 + n * 16 + (lane & 15)][elemoff];
    __builtin_amdgcn_s_setprio(1);
#pragma unroll
    for (int m = 0; m < 4; ++m)
#pragma unroll
      for (int n = 0; n < 4; ++n)
        acc[m][n] = __builtin_amdgcn_mfma_f32_16x16x32_f16(af[m], bfr[n], acc[m][n], 0, 0, 0);
    __builtin_amdgcn_s_setprio(0);
    cur = (cur + 1 == 3) ? 0 : cur + 1;
  }
#undef STAGE

  const int col_l = lane & 15;
  const int row_l = (lane >> 4) << 2;

  {
    f16* Ch = (f16*)C + (size_t)bz * sC + (size_t)m0 * ldc + n0;
#pragma unroll
    for (int m = 0; m < 4; ++m)
#pragma unroll
      for (int n = 0; n < 4; ++n)
#pragma unroll
        for (int r = 0; r < 4; ++r) {
          const int rr = wm * 64 + m * 16 + row_l + r;
          const int cc = wn * 64 + n * 16 + col_l;
          float val = acc[m][n][r];
          if constexpr (EPI == EPI_RELU) { val += bias[n0 + cc]; val = fmaxf(val, 0.0f); }
          if constexpr (EPI == EPI_BIASR) val += bias[m0 + rr];
          if constexpr (EPI == EPI_OUT)
            val += wfb[bz * 1024 + m0 + rr] * dvv[bz * 512 + n0 + cc];
          Ch[(size_t)rr * ldc + cc] = (f16)val;
        }
  }
  (void)scale; (void)mmarr; (void)nmm;
}

// BM=256 x BN=128 tile, 8 waves (4m x 2n), BK=32, same 3-buffer/stage(t+2)/counted-vmcnt
// skeleton. 3 gld per thread per K-step (A:2, B:1) -> vmcnt(3) steady state.
template<int EPI, bool XMAP>
__global__ __launch_bounds__(512, 2)
void gemm_bt2(const f16* __restrict__ A, const f16* __restrict__ B, void* __restrict__ C,
              int lda, int ldb, int ldc, int K,
              long long sA, long long sB, long long sC,
              const float* __restrict__ bias,
              const float* __restrict__ wfb, const float* __restrict__ dvv,
              int nx, int nbz)
{
  __shared__ __align__(16) f16 As[3][256][32];
  __shared__ __align__(16) f16 Bs[3][128][32];
  const int tid  = threadIdx.x;
  const int lane = tid & 63;
  const int w    = tid >> 6;           // 0..7
  const int wm   = w >> 1, wn = w & 1; // 4m x 2n

  const int lin = blockIdx.x;
  int bz, bj;
  if constexpr (XMAP) {
    const int xcd = lin & 7, rest = lin >> 3;
    const int grp = rest / nbz;
    bj = rest - grp * nbz;
    bz = xcd + (grp << 3);
  } else {
    bz = lin / nbz; bj = lin - bz * nbz;
  }
  const int m0 = (bj / nx) * 256, n0 = (bj % nx) * 128;
  const f16* Ab = A + (size_t)bz * sA + (size_t)m0 * lda;
  const f16* Bb = B + (size_t)bz * sB + (size_t)n0 * ldb;

  f32x4 acc[4][4] = {};
  const int nsteps = K >> 5;

#define STAGE3(bufb, ks)                                                             \
  {                                                                                  \
    const int k0_ = (ks) << 5;                                                       \
    _Pragma("unroll")                                                                \
    for (int i = 0; i < 2; ++i) {                                                    \
      const int ci = i * 512 + tid;                                                  \
      const int r  = ci >> 2;                                                        \
      const int sg = (ci & 3) ^ ((r >> 1) & 3);                                      \
      gld_lds16(Ab + (size_t)r * lda + k0_ + sg * 8,                                 \
                (char*)As + (size_t)(bufb) * 16384 + (size_t)(i * 512 + w * 64) * 16); \
    }                                                                                \
    {                                                                                \
      const int r  = tid >> 2;                                                       \
      const int sg = (tid & 3) ^ ((r >> 1) & 3);                                     \
      gld_lds16(Bb + (size_t)r * ldb + k0_ + sg * 8,                                 \
                (char*)Bs + (size_t)(bufb) * 8192 + (size_t)(w * 64) * 16);          \
    }                                                                                \
  }

  STAGE3(0, 0)
  STAGE3(1, 1)

  const int elemoff = (((lane >> 4) ^ ((lane >> 1) & 3)) << 3);

  int cur = 0;
  for (int t = 0; t < nsteps; ++t) {
    if (t + 1 < nsteps) asm volatile("s_waitcnt vmcnt(3)" ::: "memory");
    else                asm volatile("s_waitcnt vmcnt(0)" ::: "memory");
    __builtin_amdgcn_s_barrier();
    __builtin_amdgcn_sched_barrier(0);
    int st = cur + 2; if (st >= 3) st -= 3;
    if (t + 2 < nsteps) STAGE3(st, t + 2)
    f16x8 af[4], bfr[4];
#pragma unroll
    for (int m = 0; m < 4; ++m)
      af[m] = *(const f16x8*)&As[cur][wm * 64 + m * 16 + (lane & 15)][elemoff];
#pragma unroll
    for (int n = 0; n < 4; ++n)
      bfr[n] = *(const f16x8*)&Bs[cur][wn * 64 + n * 16 + (lane & 15)][elemoff];
    __builtin_amdgcn_s_setprio(1);
#pragma unroll
    for (int m = 0; m < 4; ++m)
#pragma unroll
      for (int n = 0; n < 4; ++n)
        acc[m][n] = __builtin_amdgcn_mfma_f32_16x16x32_f16(af[m], bfr[n], acc[m][n], 0, 0, 0);
    __builtin_amdgcn_s_setprio(0);
    cur = (cur + 1 == 3) ? 0 : cur + 1;
  }
#undef STAGE3

  const int col_l = lane & 15;
  const int row_l = (lane >> 4) << 2;
  f16* Ch = (f16*)C + (size_t)bz * sC + (size_t)m0 * ldc + n0;
#pragma unroll
  for (int m = 0; m < 4; ++m)
#pragma unroll
    for (int n = 0; n < 4; ++n)
#pragma unroll
      for (int r = 0; r < 4; ++r) {
        const int rr = wm * 64 + m * 16 + row_l + r;
        const int cc = wn * 64 + n * 16 + col_l;
        float val = acc[m][n][r];
        if constexpr (EPI == EPI_RELU) { val += bias[n0 + cc]; val = fmaxf(val, 0.0f); }
        if constexpr (EPI == EPI_BIASR) val += bias[m0 + rr];
        if constexpr (EPI == EPI_OUT)
          val += wfb[bz * 1024 + m0 + rr] * dvv[bz * 512 + n0 + cc];
        Ch[(size_t)rr * ldc + cc] = (f16)val;
      }
}

// 256x256 tile scores GEMM: C = (A @ B^T) * scale -> f16, per-block max/min.
__global__ __launch_bounds__(512, 2)
void gemm256_scores(const f16* __restrict__ A, const f16* __restrict__ B, f16* __restrict__ C,
                    float scale, float* __restrict__ mmarr)
{
  __shared__ __align__(16) f16 As[3][256][32];
  __shared__ __align__(16) f16 Bs[3][256][32];
  __shared__ float redm[8], redn[8];
  const int tid  = threadIdx.x;
  const int lane = tid & 63;
  const int w    = tid >> 6;           // 0..7
  const int wm   = w >> 2, wn = w & 3; // 2 x 4
  const int lin  = blockIdx.x;
  const int xcd = lin & 7, rest = lin >> 3;
  const int bj  = rest & 15;
  const int bz  = xcd + ((rest >> 4) << 3);
  const int m0 = (bj >> 2) * 256, n0 = (bj & 3) * 256;
  const f16* Ab = A + (size_t)bz * 524288 + (size_t)m0 * 512;
  const f16* Bb = B + (size_t)bz * 524288 + (size_t)n0 * 512;

  f32x4 acc[8][4] = {};

#define STAGE2(bufb, ks)                                                             \
  {                                                                                  \
    const int k0_ = (ks) << 5;                                                       \
    _Pragma("unroll")                                                                \
    for (int i = 0; i < 2; ++i) {                                                    \
      const int ci = i * 512 + tid;                                                  \
      const int r  = ci >> 2;                                                        \
      const int sg = (ci & 3) ^ ((r >> 1) & 3);                                      \
      gld_lds16(Ab + (size_t)r * 512 + k0_ + sg * 8,                                 \
                (char*)As + (bufb) + (size_t)(i * 512 + w * 64) * 16);               \
      gld_lds16(Bb + (size_t)r * 512 + k0_ + sg * 8,                                 \
                (char*)Bs + (bufb) + (size_t)(i * 512 + w * 64) * 16);               \
    }                                                                                \
  }

  STAGE2(0, 0)
  STAGE2(16384, 1)

  const int elemoff = (((lane >> 4) ^ ((lane >> 1) & 3)) << 3);

  int cur = 0;
  for (int t = 0; t < 16; ++t) {
    if (t + 1 < 16) asm volatile("s_waitcnt vmcnt(4)" ::: "memory");
    else            asm volatile("s_waitcnt vmcnt(0)" ::: "memory");
    __builtin_amdgcn_s_barrier();
    __builtin_amdgcn_sched_barrier(0);
    int st = cur + 2; if (st >= 3) st -= 3;
    if (t + 2 < 16) STAGE2(st * 16384, t + 2)
    f16x8 af[8], bfr[4];
#pragma unroll
    for (int m = 0; m < 8; ++m)
      af[m] = *(const f16x8*)&As[cur][wm * 128 + m * 16 + (lane & 15)][elemoff];
#pragma unroll
    for (int n = 0; n < 4; ++n)
      bfr[n] = *(const f16x8*)&Bs[cur][wn * 64 + n * 16 + (lane & 15)][elemoff];
    __builtin_amdgcn_s_setprio(1);
#pragma unroll
    for (int m = 0; m < 8; ++m)
#pragma unroll
      for (int n = 0; n < 4; ++n)
        acc[m][n] = __builtin_amdgcn_mfma_f32_16x16x32_f16(af[m], bfr[n], acc[m][n], 0, 0, 0);
    __builtin_amdgcn_s_setprio(0);
    cur = (cur + 1 == 3) ? 0 : cur + 1;
  }
#undef STAGE2

  const int col_l = lane & 15;
  const int row_l = (lane >> 4) << 2;
  f16* Ch = C + (size_t)bz * 1048576 + (size_t)m0 * 1024 + n0;
  float lmax = -3.402823466e38f, lmin = 3.402823466e38f;
#pragma unroll
  for (int m = 0; m < 8; ++m)
#pragma unroll
    for (int n = 0; n < 4; ++n)
#pragma unroll
      for (int r = 0; r < 4; ++r) {
        float val = acc[m][n][r] * scale;
        lmax = fmaxf(lmax, val); lmin = fminf(lmin, val);
        Ch[(size_t)(wm * 128 + m * 16 + row_l + r) * 1024 + (wn * 64 + n * 16 + col_l)] = (f16)val;
      }
#pragma unroll
  for (int off = 32; off >= 1; off >>= 1) {
    lmax = fmaxf(lmax, __shfl_xor(lmax, off));
    lmin = fminf(lmin, __shfl_xor(lmin, off));
  }
  if (lane == 0) { redm[w] = lmax; redn[w] = lmin; }
  __syncthreads();
  if (tid == 0) {
    float gm = redm[0], gn = redn[0];
#pragma unroll
    for (int i = 1; i < 8; ++i) { gm = fmaxf(gm, redm[i]); gn = fminf(gn, redn[i]); }
    mmarr[lin] = gm; mmarr[256 + lin] = gn;
  }
}

// reduce per-block max/min -> fb scalar
__global__ __launch_bounds__(256)
void reduce_mm(const float* __restrict__ mmarr, int n,
               const float* __restrict__ fallback, float* __restrict__ fbv)
{
  __shared__ float rm[4], rn[4];
  const int lane = threadIdx.x & 63, w = threadIdx.x >> 6;
  float mx = -3.402823466e38f, mn = 3.402823466e38f;
  for (int i = threadIdx.x; i < n; i += 256) {
    mx = fmaxf(mx, mmarr[i]);
    mn = fminf(mn, mmarr[n + i]);
  }
#pragma unroll
  for (int off = 32; off >= 1; off >>= 1) {
    mx = fmaxf(mx, __shfl_xor(mx, off));
    mn = fminf(mn, __shfl_xor(mn, off));
  }
  if (lane == 0) { rm[w] = mx; rn[w] = mn; }
  __syncthreads();
  if (threadIdx.x == 0) {
    float gmax = fmaxf(fmaxf(rm[0], rm[1]), fmaxf(rm[2], rm[3]));
    float gmin = fminf(fminf(rn[0], rn[1]), fminf(rn[2], rn[3]));
    fbv[0] = 0.99f * fallback[0] + 0.005f * (gmax + gmin);
  }
}

// fused f32->f16 convert of q,k,v
__global__ __launch_bounds__(256)
void conv3_k(const float* __restrict__ a, const float* __restrict__ b,
             const float* __restrict__ c,
             f16* __restrict__ oa, f16* __restrict__ ob, f16* __restrict__ oc,
             int n4each)
{
  int i = blockIdx.x * 256 + threadIdx.x;
  int seg = i / n4each;
  int j = i - seg * n4each;
  const float* src = (seg == 0) ? a : ((seg == 1) ? b : c);
  f16* dst = (seg == 0) ? oa : ((seg == 1) ? ob : oc);
  float4 v = *(const float4*)(src + (size_t)j * 4);
  f16x4 o = { (f16)v.x, (f16)v.y, (f16)v.z, (f16)v.w };
  *(f16x4*)(dst + (size_t)j * 4) = o;
}

__global__ __launch_bounds__(256)
void convw_k(const float* __restrict__ wv, const float* __restrict__ w1,
             const float* __restrict__ w2,
             f16* __restrict__ owv, f16* __restrict__ ow1, f16* __restrict__ ow2)
{
  int i = blockIdx.x * 256 + threadIdx.x;   // 0..163839
  const float* src; f16* dst; int j;
  if (i < 65536)       { src = wv; dst = owv; j = i; }
  else if (i < 131072) { src = w1; dst = ow1; j = i - 65536; }
  else                 { src = w2; dst = ow2; j = i - 131072; }
  float4 v = *(const float4*)(src + (size_t)j * 4);
  f16x4 o = { (f16)v.x, (f16)v.y, (f16)v.z, (f16)v.w };
  *(f16x4*)(dst + (size_t)j * 4) = o;
}

// one block: count nonzero bytes of mask (dtype sniffing)
__global__ void init_count(const unsigned char* __restrict__ mask, unsigned* __restrict__ mm)
{
  __shared__ int red[256];
  int c = 0;
  for (int i = threadIdx.x; i < 16384; i += 256) c += (mask[i] != 0) ? 1 : 0;
  red[threadIdx.x] = c;
  __syncthreads();
  for (int s = 128; s > 0; s >>= 1) {
    if (threadIdx.x < s) red[threadIdx.x] += red[threadIdx.x + s];
    __syncthreads();
  }
  if (threadIdx.x == 0) mm[0] = (unsigned)red[0];
}

__global__ __launch_bounds__(256)
void softmax_rows(const f16* __restrict__ scores, const void* __restrict__ maskp,
                  const float* __restrict__ fbv, const unsigned* __restrict__ mm,
                  f16* __restrict__ Wt, float* __restrict__ wfb)
{
  __shared__ float red[8];
  const int row  = blockIdx.x;
  const int b    = row >> 10;
  const int tid  = threadIdx.x;
  const int lane = tid & 63, w = tid >> 6;
  const float fb = fbv[0];
  const unsigned mode = (mm[0] > 5000u) ? 1u : 0u;
  const f16* s = scores + (size_t)row * 1024;
  const int k0 = tid * 4;
  f16x4 sv = *(const f16x4*)(s + k0);
  float x[4];
  if (mode) {
    const unsigned char* m8 = (const unsigned char*)maskp + b * 1024 + k0;
    x[0] = m8[0] ? -1e9f : (float)sv[0];  x[1] = m8[1] ? -1e9f : (float)sv[1];
    x[2] = m8[2] ? -1e9f : (float)sv[2];  x[3] = m8[3] ? -1e9f : (float)sv[3];
  } else {
    const int* mi = (const int*)maskp + b * 1024 + k0;
    x[0] = mi[0] ? -1e9f : (float)sv[0];  x[1] = mi[1] ? -1e9f : (float)sv[1];
    x[2] = mi[2] ? -1e9f : (float)sv[2];  x[3] = mi[3] ? -1e9f : (float)sv[3];
  }
  float mx = fmaxf(fmaxf(x[0], x[1]), fmaxf(x[2], x[3]));
#pragma unroll
  for (int off = 32; off >= 1; off >>= 1) mx = fmaxf(mx, __shfl_xor(mx, off));
  if (lane == 0) red[w] = mx;
  __syncthreads();
  mx = fmaxf(fmaxf(fmaxf(red[0], red[1]), fmaxf(red[2], red[3])), fb);
  float e0 = expf(x[0] - mx), e1 = expf(x[1] - mx), e2 = expf(x[2] - mx), e3 = expf(x[3] - mx);
  float sum = (e0 + e1) + (e2 + e3);
#pragma unroll
  for (int off = 32; off >= 1; off >>= 1) sum += __shfl_xor(sum, off);
  if (lane == 0) red[4 + w] = sum;
  __syncthreads();
  float efb = expf(fb - mx);
  float Z = ((red[4] + red[5]) + (red[6] + red[7])) + efb;
  float inv = 1.0f / Z;
  f16x4 o = { (f16)(e0 * inv), (f16)(e1 * inv), (f16)(e2 * inv), (f16)(e3 * inv) };
  *(f16x4*)&Wt[(size_t)row * 1024 + k0] = o;
  if (tid == 0) wfb[row] = efb * inv;
}

// wave-per-output FC: Y[b,j] = act(X[b,:] . W[j,:] + bias[j])
template<int IN, int ACT>
__global__ __launch_bounds__(256)
void fc_wave(const float* __restrict__ X, const float* __restrict__ W,
             const float* __restrict__ bias, float* __restrict__ Y, int OutN)
{
  const int gw   = (blockIdx.x * 256 + threadIdx.x) >> 6;
  const int lane = threadIdx.x & 63;
  const int b = gw / OutN, j = gw - b * OutN;
  const float* x  = X + (size_t)b * IN;
  const float* wr = W + (size_t)j * IN;
  float s = 0.f;
  if constexpr (IN == 512) {
    const int o = lane * 8;
    float4 x0 = *(const float4*)(x + o),  x1 = *(const float4*)(x + o + 4);
    float4 w0 = *(const float4*)(wr + o), w1 = *(const float4*)(wr + o + 4);
    s = x0.x*w0.x + x0.y*w0.y + x0.z*w0.z + x0.w*w0.w
      + x1.x*w1.x + x1.y*w1.y + x1.z*w1.z + x1.w*w1.w;
  } else {
    const int o = lane * 4;
    float4 x0 = *(const float4*)(x + o);
    float4 w0 = *(const float4*)(wr + o);
    s = x0.x*w0.x + x0.y*w0.y + x0.z*w0.z + x0.w*w0.w;
  }
#pragma unroll
  for (int off = 32; off >= 1; off >>= 1) s += __shfl_xor(s, off);
  if (lane == 0) {
    float val = s + bias[ACT == 2 ? 0 : j];
    if constexpr (ACT == 1) val = fmaxf(val, 0.f);
    if constexpr (ACT == 2) val = tanhf(val);
    Y[gw] = val;
  }
}

__global__ __launch_bounds__(256)
void y_kernel(const f16* __restrict__ h2, const float* __restrict__ W3,
              const float* __restrict__ b3, float* __restrict__ outp)
{
  int row = blockIdx.x * 16 + (threadIdx.x >> 4);
  int l   = threadIdx.x & 15;
  const f16* h = h2 + (size_t)row * 256 + l * 16;
  float s = 0.f;
#pragma unroll
  for (int j = 0; j < 16; ++j) s += (float)h[j] * W3[l * 16 + j];
#pragma unroll
  for (int off = 1; off < 16; off <<= 1) s += __shfl_xor(s, off);
  if (l == 0) outp[row] = tanhf(s + b3[0]);
}

extern "C" void kernel_launch(void* const* d_in, const int* in_sizes, int n_in,
                              void* d_out, int out_size, void* d_ws, size_t ws_size,
                              hipStream_t stream) {
  const float* uq       = (const float*)d_in[0];
  const float* q        = (const float*)d_in[1];
  const float* kk       = (const float*)d_in[2];
  const float* v        = (const float*)d_in[3];
  const void*  mask     = d_in[4];
  const float* fallback = (const float*)d_in[5];
  const float* Wv = (const float*)d_in[6];
  const float* bv = (const float*)d_in[7];
  const float* Wf = (const float*)d_in[8];
  const float* bf = (const float*)d_in[9];
  const float* W1 = (const float*)d_in[10];
  const float* b1 = (const float*)d_in[11];
  const float* W2 = (const float*)d_in[12];
  const float* b2 = (const float*)d_in[13];
  const float* W3 = (const float*)d_in[14];
  const float* b3 = (const float*)d_in[15];
  float* outp = (float*)d_out;

  char* ws = (char*)d_ws;
  const size_t MB = 1ull << 20;
  f16*  scores = (f16*)ws;
  f16*  h1b  = (f16*)ws;
  f16*  h2b  = (f16*)(ws + 16 * MB);
  f16*  vpt  = (f16*)(ws + 32 * MB);
  f16*  outb = (f16*)(ws + 48 * MB);
  f16*  q16  = (f16*)(ws + 64 * MB);
  f16*  wts  = (f16*)(ws + 64 * MB);
  f16*  k16  = (f16*)(ws + 80 * MB);
  f16*  v16  = (f16*)(ws + 96 * MB);
  char* cst  = ws + 112 * MB;
  f16*  Wv16 = (f16*)(cst);
  f16*  W116 = (f16*)(cst + 512 * 1024);
  f16*  W216 = (f16*)(cst + 1024 * 1024);
  float* dv   = (float*)(cst + 1280 * 1024);
  float* wfb  = (float*)(cst + 1312 * 1024);
  float* h1d  = (float*)(cst + 1376 * 1024);
  float* h2d  = (float*)(cst + 1408 * 1024);
  unsigned* mm = (unsigned*)(cst + 1424 * 1024);
  float* fbv   = (float*)(cst + 1428 * 1024);
  float* mmarr = (float*)(cst + 1432 * 1024);   // 2 * 256 floats

  init_count<<<1, 256, 0, stream>>>((const unsigned char*)mask, mm);

  conv3_k<<<24576, 256, 0, stream>>>(q, kk, v, q16, k16, v16, 2097152);
  convw_k<<<640, 256, 0, stream>>>(Wv, W1, W2, Wv16, W116, W216);

  // dv = uq @ Wf^T + bf
  fc_wave<512, 0><<<2048, 256, 0, stream>>>(uq, Wf, bf, dv, 512);

  // scores = q @ k^T / sqrt(512) -> f16, per-block max/min (256x256 tiles, 8 waves)
  gemm256_scores<<<256, 512, 0, stream>>>(q16, k16, scores, 0.04419417382415922f, mmarr);

  reduce_mm<<<1, 256, 0, stream>>>(mmarr, 256, fallback, fbv);

  softmax_rows<<<16384, 256, 0, stream>>>(scores, mask, fbv, mm, wts, wfb);

  // vpt[d][k] = sum_e Wv[d][e] v[k][e] + bv[d]  (256x128 tiles, 8 waves)
  gemm_bt2<EPI_BIASR, true><<<256, 512, 0, stream>>>(
      Wv16, v16, vpt, 512, 512, 1024, 512,
      0LL, 524288LL, 524288LL,
      bv, nullptr, nullptr, 8, 16);

  // out = weights @ vp + wfb*dv  (256x128 tiles, 8 waves)
  gemm_bt2<EPI_OUT, true><<<256, 512, 0, stream>>>(
      wts, vpt, outb, 1024, 1024, 512, 1024,
      1048576LL, 524288LL, 524288LL,
      nullptr, wfb, dv, 4, 16);

  // h1 = relu(out @ W1^T + b1)  (256x128 tiles, 8 waves)
  gemm_bt2<EPI_RELU, false><<<256, 512, 0, stream>>>(
      outb, W116, h1b, 512, 512, 512, 512, 0LL, 0LL, 0LL,
      b1, nullptr, nullptr, 4, 256);

  // h2 = relu(h1 @ W2^T + b2)
  gemm_bt<EPI_RELU, false><<<256, 256, 0, stream>>>(
      h1b, W216, h2b, 512, 512, 256, 512, 0LL, 0LL, 0LL,
      b2, 1.f, nullptr, 0, nullptr, nullptr, 2, 256);

  y_kernel<<<1024, 256, 0, stream>>>(h2b, W3, b3, outp);

  // default-values scorer branch (f32, wave-per-output)
  fc_wave<512, 1><<<2048, 256, 0, stream>>>(dv, W1, b1, h1d, 512);
  fc_wave<512, 1><<<1024, 256, 0, stream>>>(h1d, W2, b2, h2d, 256);
  fc_wave<256, 2><<<4, 256, 0, stream>>>(h2d, W3, b3, outp + 16384, 1);

  (void)in_sizes; (void)n_in; (void)out_size; (void)ws_size;
}

// Round 7
// 186.036 us; speedup vs baseline: 1.0227x; 1.0227x over previous
//
#include <hip/hip_runtime.h>

typedef _Float16 f16;
typedef f16  f16x8 __attribute__((ext_vector_type(8)));
typedef f16  f16x4 __attribute__((ext_vector_type(4)));
typedef float f32x4 __attribute__((ext_vector_type(4)));

__device__ __forceinline__ void gld_lds16(const f16* g, void* l) {
  __builtin_amdgcn_global_load_lds((const __attribute__((address_space(1))) void*)g,
                                   (__attribute__((address_space(3))) void*)l,
                                   16, 0, 0);
}

enum { EPI_SCORES = 0, EPI_RELU = 2, EPI_OUT = 3, EPI_BIASR = 4 };

// C[M,N] = A[M,K] @ B[N,K]^T, 128x128 tile, BK=32, 4 waves (2x2), 16x16x32 f16 MFMA.
// 3-stage LDS pipeline, counted vmcnt (never 0 mid-loop), raw s_barrier, swizzled LDS.
// NOTE (R6 post-mortem): keep 128x128 with >=2 blocks/CU. A 256x128 8-wave variant at
// 1 block/CU regressed ~9us: same waves/CU but a single barrier stalls the whole CU,
// losing cross-block overlap. Only adopt fatter tiles when MFMA:load per barrier ~2x.
template<int EPI, bool XMAP>
__global__ __launch_bounds__(256)
void gemm_bt(const f16* __restrict__ A, const f16* __restrict__ B, void* __restrict__ C,
             int lda, int ldb, int ldc, int K,
             long long sA, long long sB, long long sC,
             const float* __restrict__ bias, float scale,
             float* __restrict__ mmarr, int nmm,
             const float* __restrict__ wfb, const float* __restrict__ dvv,
             int nx, int nbz)
{
  __shared__ __align__(16) f16 As[3][128][32];
  __shared__ __align__(16) f16 Bs[3][128][32];
  const int tid  = threadIdx.x;
  const int lane = tid & 63;
  const int w    = tid >> 6;
  const int wm   = w >> 1, wn = w & 1;

  const int lin = blockIdx.x;
  int bz, bj;
  if constexpr (XMAP) {
    const int xcd = lin & 7, rest = lin >> 3;
    const int grp = rest / nbz;
    bj = rest - grp * nbz;
    bz = xcd + (grp << 3);
  } else {
    bz = lin / nbz; bj = lin - bz * nbz;
  }
  const int m0 = (bj / nx) * 128, n0 = (bj % nx) * 128;
  const f16* Ab = A + (size_t)bz * sA + (size_t)m0 * lda;
  const f16* Bb = B + (size_t)bz * sB + (size_t)n0 * ldb;

  f32x4 acc[4][4] = {};
  const int nsteps = K >> 5;

#define STAGE(bufb, ks)                                                              \
  {                                                                                  \
    const int k0_ = (ks) << 5;                                                       \
    _Pragma("unroll")                                                                \
    for (int i = 0; i < 2; ++i) {                                                    \
      const int ci = i * 256 + tid;                                                  \
      const int r  = ci >> 2;                                                        \
      const int sg = (ci & 3) ^ ((r >> 1) & 3);                                      \
      gld_lds16(Ab + (size_t)r * lda + k0_ + sg * 8,                                 \
                (char*)As + (bufb) + (size_t)(i * 256 + w * 64) * 16);               \
      gld_lds16(Bb + (size_t)r * ldb + k0_ + sg * 8,                                 \
                (char*)Bs + (bufb) + (size_t)(i * 256 + w * 64) * 16);               \
    }                                                                                \
  }

  STAGE(0, 0)
  STAGE(8192, 1)

  const int elemoff = (((lane >> 4) ^ ((lane >> 1) & 3)) << 3);

  int cur = 0;
  for (int t = 0; t < nsteps; ++t) {
    if (t + 1 < nsteps) asm volatile("s_waitcnt vmcnt(4)" ::: "memory");
    else                asm volatile("s_waitcnt vmcnt(0)" ::: "memory");
    __builtin_amdgcn_s_barrier();
    __builtin_amdgcn_sched_barrier(0);
    int st = cur + 2; if (st >= 3) st -= 3;
    if (t + 2 < nsteps) STAGE(st * 8192, t + 2)
    f16x8 af[4], bfr[4];
#pragma unroll
    for (int m = 0; m < 4; ++m)
      af[m] = *(const f16x8*)&As[cur][wm * 64 + m * 16 + (lane & 15)][elemoff];
#pragma unroll
    for (int n = 0; n < 4; ++n)
      bfr[n] = *(const f16x8*)&Bs[cur][wn * 64 + n * 16 + (lane & 15)][elemoff];
    __builtin_amdgcn_s_setprio(1);
#pragma unroll
    for (int m = 0; m < 4; ++m)
#pragma unroll
      for (int n = 0; n < 4; ++n)
        acc[m][n] = __builtin_amdgcn_mfma_f32_16x16x32_f16(af[m], bfr[n], acc[m][n], 0, 0, 0);
    __builtin_amdgcn_s_setprio(0);
    cur = (cur + 1 == 3) ? 0 : cur + 1;
  }
#undef STAGE

  const int col_l = lane & 15;
  const int row_l = (lane >> 4) << 2;

  {
    f16* Ch = (f16*)C + (size_t)bz * sC + (size_t)m0 * ldc + n0;
#pragma unroll
    for (int m = 0; m < 4; ++m)
#pragma unroll
      for (int n = 0; n < 4; ++n)
#pragma unroll
        for (int r = 0; r < 4; ++r) {
          const int rr = wm * 64 + m * 16 + row_l + r;
          const int cc = wn * 64 + n * 16 + col_l;
          float val = acc[m][n][r];
          if constexpr (EPI == EPI_RELU) { val += bias[n0 + cc]; val = fmaxf(val, 0.0f); }
          if constexpr (EPI == EPI_BIASR) val += bias[m0 + rr];
          if constexpr (EPI == EPI_OUT)
            val += wfb[bz * 1024 + m0 + rr] * dvv[bz * 512 + n0 + cc];
          Ch[(size_t)rr * ldc + cc] = (f16)val;
        }
  }
  (void)scale; (void)mmarr; (void)nmm;
}

// 256x256 tile scores GEMM: C = (A @ B^T) * scale -> f16, per-block max/min.
// 8 waves (2m x 4n), BK=32, 3-buffer / stage(t+2) / vmcnt(4) skeleton. Grid 256 (1/CU);
// pays for the single-barrier stall via 32 MFMA : 4 loads per thread per K-step.
__global__ __launch_bounds__(512, 2)
void gemm256_scores(const f16* __restrict__ A, const f16* __restrict__ B, f16* __restrict__ C,
                    float scale, float* __restrict__ mmarr)
{
  __shared__ __align__(16) f16 As[3][256][32];
  __shared__ __align__(16) f16 Bs[3][256][32];
  __shared__ float redm[8], redn[8];
  const int tid  = threadIdx.x;
  const int lane = tid & 63;
  const int w    = tid >> 6;           // 0..7
  const int wm   = w >> 2, wn = w & 3; // 2 x 4
  const int lin  = blockIdx.x;
  const int xcd = lin & 7, rest = lin >> 3;
  const int bj  = rest & 15;
  const int bz  = xcd + ((rest >> 4) << 3);
  const int m0 = (bj >> 2) * 256, n0 = (bj & 3) * 256;
  const f16* Ab = A + (size_t)bz * 524288 + (size_t)m0 * 512;
  const f16* Bb = B + (size_t)bz * 524288 + (size_t)n0 * 512;

  f32x4 acc[8][4] = {};

#define STAGE2(bufb, ks)                                                             \
  {                                                                                  \
    const int k0_ = (ks) << 5;                                                       \
    _Pragma("unroll")                                                                \
    for (int i = 0; i < 2; ++i) {                                                    \
      const int ci = i * 512 + tid;                                                  \
      const int r  = ci >> 2;                                                        \
      const int sg = (ci & 3) ^ ((r >> 1) & 3);                                      \
      gld_lds16(Ab + (size_t)r * 512 + k0_ + sg * 8,                                 \
                (char*)As + (bufb) + (size_t)(i * 512 + w * 64) * 16);               \
      gld_lds16(Bb + (size_t)r * 512 + k0_ + sg * 8,                                 \
                (char*)Bs + (bufb) + (size_t)(i * 512 + w * 64) * 16);               \
    }                                                                                \
  }

  STAGE2(0, 0)
  STAGE2(16384, 1)

  const int elemoff = (((lane >> 4) ^ ((lane >> 1) & 3)) << 3);

  int cur = 0;
  for (int t = 0; t < 16; ++t) {
    if (t + 1 < 16) asm volatile("s_waitcnt vmcnt(4)" ::: "memory");
    else            asm volatile("s_waitcnt vmcnt(0)" ::: "memory");
    __builtin_amdgcn_s_barrier();
    __builtin_amdgcn_sched_barrier(0);
    int st = cur + 2; if (st >= 3) st -= 3;
    if (t + 2 < 16) STAGE2(st * 16384, t + 2)
    f16x8 af[8], bfr[4];
#pragma unroll
    for (int m = 0; m < 8; ++m)
      af[m] = *(const f16x8*)&As[cur][wm * 128 + m * 16 + (lane & 15)][elemoff];
#pragma unroll
    for (int n = 0; n < 4; ++n)
      bfr[n] = *(const f16x8*)&Bs[cur][wn * 64 + n * 16 + (lane & 15)][elemoff];
    __builtin_amdgcn_s_setprio(1);
#pragma unroll
    for (int m = 0; m < 8; ++m)
#pragma unroll
      for (int n = 0; n < 4; ++n)
        acc[m][n] = __builtin_amdgcn_mfma_f32_16x16x32_f16(af[m], bfr[n], acc[m][n], 0, 0, 0);
    __builtin_amdgcn_s_setprio(0);
    cur = (cur + 1 == 3) ? 0 : cur + 1;
  }
#undef STAGE2

  const int col_l = lane & 15;
  const int row_l = (lane >> 4) << 2;
  f16* Ch = C + (size_t)bz * 1048576 + (size_t)m0 * 1024 + n0;
  float lmax = -3.402823466e38f, lmin = 3.402823466e38f;
#pragma unroll
  for (int m = 0; m < 8; ++m)
#pragma unroll
    for (int n = 0; n < 4; ++n)
#pragma unroll
      for (int r = 0; r < 4; ++r) {
        float val = acc[m][n][r] * scale;
        lmax = fmaxf(lmax, val); lmin = fminf(lmin, val);
        Ch[(size_t)(wm * 128 + m * 16 + row_l + r) * 1024 + (wn * 64 + n * 16 + col_l)] = (f16)val;
      }
#pragma unroll
  for (int off = 32; off >= 1; off >>= 1) {
    lmax = fmaxf(lmax, __shfl_xor(lmax, off));
    lmin = fminf(lmin, __shfl_xor(lmin, off));
  }
  if (lane == 0) { redm[w] = lmax; redn[w] = lmin; }
  __syncthreads();
  if (tid == 0) {
    float gm = redm[0], gn = redn[0];
#pragma unroll
    for (int i = 1; i < 8; ++i) { gm = fmaxf(gm, redm[i]); gn = fminf(gn, redn[i]); }
    mmarr[lin] = gm; mmarr[256 + lin] = gn;
  }
}

// reduce per-block max/min -> fb scalar
__global__ __launch_bounds__(256)
void reduce_mm(const float* __restrict__ mmarr, int n,
               const float* __restrict__ fallback, float* __restrict__ fbv)
{
  __shared__ float rm[4], rn[4];
  const int lane = threadIdx.x & 63, w = threadIdx.x >> 6;
  float mx = -3.402823466e38f, mn = 3.402823466e38f;
  for (int i = threadIdx.x; i < n; i += 256) {
    mx = fmaxf(mx, mmarr[i]);
    mn = fminf(mn, mmarr[n + i]);
  }
#pragma unroll
  for (int off = 32; off >= 1; off >>= 1) {
    mx = fmaxf(mx, __shfl_xor(mx, off));
    mn = fminf(mn, __shfl_xor(mn, off));
  }
  if (lane == 0) { rm[w] = mx; rn[w] = mn; }
  __syncthreads();
  if (threadIdx.x == 0) {
    float gmax = fmaxf(fmaxf(rm[0], rm[1]), fmaxf(rm[2], rm[3]));
    float gmin = fminf(fminf(rn[0], rn[1]), fminf(rn[2], rn[3]));
    fbv[0] = 0.99f * fallback[0] + 0.005f * (gmax + gmin);
  }
}

// fused f32->f16 convert of q,k,v. 2048 blocks; each thread does 12 statically-unrolled
// float4 chunks (3 tensors x 4) -> deep MLP, shift-based indexing, uniform pointers.
// Sizes hardcoded: each tensor = 2^21 float4 (16*1024*512 f32).
__global__ __launch_bounds__(256)
void conv3_k(const float* __restrict__ a, const float* __restrict__ b,
             const float* __restrict__ c,
             f16* __restrict__ oa, f16* __restrict__ ob, f16* __restrict__ oc)
{
  const int t = blockIdx.x * 256 + threadIdx.x;   // 0..524287
#pragma unroll
  for (int s = 0; s < 3; ++s) {
    const float* src = (s == 0) ? a : ((s == 1) ? b : c);
    f16*       dst = (s == 0) ? oa : ((s == 1) ? ob : oc);
#pragma unroll
    for (int it = 0; it < 4; ++it) {
      const size_t j = (size_t)t + (size_t)it * 524288;
      float4 v = *(const float4*)(src + j * 4);
      f16x4 o = { (f16)v.x, (f16)v.y, (f16)v.z, (f16)v.w };
      *(f16x4*)(dst + j * 4) = o;
    }
  }
}

__global__ __launch_bounds__(256)
void convw_k(const float* __restrict__ wv, const float* __restrict__ w1,
             const float* __restrict__ w2,
             f16* __restrict__ owv, f16* __restrict__ ow1, f16* __restrict__ ow2)
{
  int i = blockIdx.x * 256 + threadIdx.x;   // 0..163839
  const float* src; f16* dst; int j;
  if (i < 65536)       { src = wv; dst = owv; j = i; }
  else if (i < 131072) { src = w1; dst = ow1; j = i - 65536; }
  else                 { src = w2; dst = ow2; j = i - 131072; }
  float4 v = *(const float4*)(src + (size_t)j * 4);
  f16x4 o = { (f16)v.x, (f16)v.y, (f16)v.z, (f16)v.w };
  *(f16x4*)(dst + (size_t)j * 4) = o;
}

// one block: count nonzero bytes of mask (dtype sniffing)
__global__ void init_count(const unsigned char* __restrict__ mask, unsigned* __restrict__ mm)
{
  __shared__ int red[256];
  int c = 0;
  for (int i = threadIdx.x; i < 16384; i += 256) c += (mask[i] != 0) ? 1 : 0;
  red[threadIdx.x] = c;
  __syncthreads();
  for (int s = 128; s > 0; s >>= 1) {
    if (threadIdx.x < s) red[threadIdx.x] += red[threadIdx.x + s];
    __syncthreads();
  }
  if (threadIdx.x == 0) mm[0] = (unsigned)red[0];
}

__global__ __launch_bounds__(256)
void softmax_rows(const f16* __restrict__ scores, const void* __restrict__ maskp,
                  const float* __restrict__ fbv, const unsigned* __restrict__ mm,
                  f16* __restrict__ Wt, float* __restrict__ wfb)
{
  __shared__ float red[8];
  const int row  = blockIdx.x;
  const int b    = row >> 10;
  const int tid  = threadIdx.x;
  const int lane = tid & 63, w = tid >> 6;
  const float fb = fbv[0];
  const unsigned mode = (mm[0] > 5000u) ? 1u : 0u;
  const f16* s = scores + (size_t)row * 1024;
  const int k0 = tid * 4;
  f16x4 sv = *(const f16x4*)(s + k0);
  float x[4];
  if (mode) {
    const unsigned char* m8 = (const unsigned char*)maskp + b * 1024 + k0;
    x[0] = m8[0] ? -1e9f : (float)sv[0];  x[1] = m8[1] ? -1e9f : (float)sv[1];
    x[2] = m8[2] ? -1e9f : (float)sv[2];  x[3] = m8[3] ? -1e9f : (float)sv[3];
  } else {
    const int* mi = (const int*)maskp + b * 1024 + k0;
    x[0] = mi[0] ? -1e9f : (float)sv[0];  x[1] = mi[1] ? -1e9f : (float)sv[1];
    x[2] = mi[2] ? -1e9f : (float)sv[2];  x[3] = mi[3] ? -1e9f : (float)sv[3];
  }
  float mx = fmaxf(fmaxf(x[0], x[1]), fmaxf(x[2], x[3]));
#pragma unroll
  for (int off = 32; off >= 1; off >>= 1) mx = fmaxf(mx, __shfl_xor(mx, off));
  if (lane == 0) red[w] = mx;
  __syncthreads();
  mx = fmaxf(fmaxf(fmaxf(red[0], red[1]), fmaxf(red[2], red[3])), fb);
  float e0 = expf(x[0] - mx), e1 = expf(x[1] - mx), e2 = expf(x[2] - mx), e3 = expf(x[3] - mx);
  float sum = (e0 + e1) + (e2 + e3);
#pragma unroll
  for (int off = 32; off >= 1; off >>= 1) sum += __shfl_xor(sum, off);
  if (lane == 0) red[4 + w] = sum;
  __syncthreads();
  float efb = expf(fb - mx);
  float Z = ((red[4] + red[5]) + (red[6] + red[7])) + efb;
  float inv = 1.0f / Z;
  f16x4 o = { (f16)(e0 * inv), (f16)(e1 * inv), (f16)(e2 * inv), (f16)(e3 * inv) };
  *(f16x4*)&Wt[(size_t)row * 1024 + k0] = o;
  if (tid == 0) wfb[row] = efb * inv;
}

// wave-per-output FC: Y[b,j] = act(X[b,:] . W[j,:] + bias[j])
template<int IN, int ACT>
__global__ __launch_bounds__(256)
void fc_wave(const float* __restrict__ X, const float* __restrict__ W,
             const float* __restrict__ bias, float* __restrict__ Y, int OutN)
{
  const int gw   = (blockIdx.x * 256 + threadIdx.x) >> 6;
  const int lane = threadIdx.x & 63;
  const int b = gw / OutN, j = gw - b * OutN;
  const float* x  = X + (size_t)b * IN;
  const float* wr = W + (size_t)j * IN;
  float s = 0.f;
  if constexpr (IN == 512) {
    const int o = lane * 8;
    float4 x0 = *(const float4*)(x + o),  x1 = *(const float4*)(x + o + 4);
    float4 w0 = *(const float4*)(wr + o), w1 = *(const float4*)(wr + o + 4);
    s = x0.x*w0.x + x0.y*w0.y + x0.z*w0.z + x0.w*w0.w
      + x1.x*w1.x + x1.y*w1.y + x1.z*w1.z + x1.w*w1.w;
  } else {
    const int o = lane * 4;
    float4 x0 = *(const float4*)(x + o);
    float4 w0 = *(const float4*)(wr + o);
    s = x0.x*w0.x + x0.y*w0.y + x0.z*w0.z + x0.w*w0.w;
  }
#pragma unroll
  for (int off = 32; off >= 1; off >>= 1) s += __shfl_xor(s, off);
  if (lane == 0) {
    float val = s + bias[ACT == 2 ? 0 : j];
    if constexpr (ACT == 1) val = fmaxf(val, 0.f);
    if constexpr (ACT == 2) val = tanhf(val);
    Y[gw] = val;
  }
}

__global__ __launch_bounds__(256)
void y_kernel(const f16* __restrict__ h2, const float* __restrict__ W3,
              const float* __restrict__ b3, float* __restrict__ outp)
{
  int row = blockIdx.x * 16 + (threadIdx.x >> 4);
  int l   = threadIdx.x & 15;
  const f16* h = h2 + (size_t)row * 256 + l * 16;
  float s = 0.f;
#pragma unroll
  for (int j = 0; j < 16; ++j) s += (float)h[j] * W3[l * 16 + j];
#pragma unroll
  for (int off = 1; off < 16; off <<= 1) s += __shfl_xor(s, off);
  if (l == 0) outp[row] = tanhf(s + b3[0]);
}

extern "C" void kernel_launch(void* const* d_in, const int* in_sizes, int n_in,
                              void* d_out, int out_size, void* d_ws, size_t ws_size,
                              hipStream_t stream) {
  const float* uq       = (const float*)d_in[0];
  const float* q        = (const float*)d_in[1];
  const float* kk       = (const float*)d_in[2];
  const float* v        = (const float*)d_in[3];
  const void*  mask     = d_in[4];
  const float* fallback = (const float*)d_in[5];
  const float* Wv = (const float*)d_in[6];
  const float* bv = (const float*)d_in[7];
  const float* Wf = (const float*)d_in[8];
  const float* bf = (const float*)d_in[9];
  const float* W1 = (const float*)d_in[10];
  const float* b1 = (const float*)d_in[11];
  const float* W2 = (const float*)d_in[12];
  const float* b2 = (const float*)d_in[13];
  const float* W3 = (const float*)d_in[14];
  const float* b3 = (const float*)d_in[15];
  float* outp = (float*)d_out;

  char* ws = (char*)d_ws;
  const size_t MB = 1ull << 20;
  f16*  scores = (f16*)ws;
  f16*  h1b  = (f16*)ws;
  f16*  h2b  = (f16*)(ws + 16 * MB);
  f16*  vpt  = (f16*)(ws + 32 * MB);
  f16*  outb = (f16*)(ws + 48 * MB);
  f16*  q16  = (f16*)(ws + 64 * MB);
  f16*  wts  = (f16*)(ws + 64 * MB);
  f16*  k16  = (f16*)(ws + 80 * MB);
  f16*  v16  = (f16*)(ws + 96 * MB);
  char* cst  = ws + 112 * MB;
  f16*  Wv16 = (f16*)(cst);
  f16*  W116 = (f16*)(cst + 512 * 1024);
  f16*  W216 = (f16*)(cst + 1024 * 1024);
  float* dv   = (float*)(cst + 1280 * 1024);
  float* wfb  = (float*)(cst + 1312 * 1024);
  float* h1d  = (float*)(cst + 1376 * 1024);
  float* h2d  = (float*)(cst + 1408 * 1024);
  unsigned* mm = (unsigned*)(cst + 1424 * 1024);
  float* fbv   = (float*)(cst + 1428 * 1024);
  float* mmarr = (float*)(cst + 1432 * 1024);   // 2 * 256 floats

  init_count<<<1, 256, 0, stream>>>((const unsigned char*)mask, mm);

  conv3_k<<<2048, 256, 0, stream>>>(q, kk, v, q16, k16, v16);
  convw_k<<<640, 256, 0, stream>>>(Wv, W1, W2, Wv16, W116, W216);

  // dv = uq @ Wf^T + bf
  fc_wave<512, 0><<<2048, 256, 0, stream>>>(uq, Wf, bf, dv, 512);

  // scores = q @ k^T / sqrt(512) -> f16, per-block max/min (256x256 tiles, 8 waves)
  gemm256_scores<<<256, 512, 0, stream>>>(q16, k16, scores, 0.04419417382415922f, mmarr);

  reduce_mm<<<1, 256, 0, stream>>>(mmarr, 256, fallback, fbv);

  softmax_rows<<<16384, 256, 0, stream>>>(scores, mask, fbv, mm, wts, wfb);

  // vpt[d][k] = sum_e Wv[d][e] v[k][e] + bv[d]
  gemm_bt<EPI_BIASR, true><<<512, 256, 0, stream>>>(
      Wv16, v16, vpt, 512, 512, 1024, 512,
      0LL, 524288LL, 524288LL,
      bv, 1.f, nullptr, 0, nullptr, nullptr, 8, 32);

  // out = weights @ vp + wfb*dv
  gemm_bt<EPI_OUT, true><<<512, 256, 0, stream>>>(
      wts, vpt, outb, 1024, 1024, 512, 1024,
      1048576LL, 524288LL, 524288LL,
      nullptr, 1.f, nullptr, 0, wfb, dv, 4, 32);

  // h1 = relu(out @ W1^T + b1)
  gemm_bt<EPI_RELU, false><<<512, 256, 0, stream>>>(
      outb, W116, h1b, 512, 512, 512, 512, 0LL, 0LL, 0LL,
      b1, 1.f, nullptr, 0, nullptr, nullptr, 4, 512);

  // h2 = relu(h1 @ W2^T + b2)
  gemm_bt<EPI_RELU, false><<<256, 256, 0, stream>>>(
      h1b, W216, h2b, 512, 512, 256, 512, 0LL, 0LL, 0LL,
      b2, 1.f, nullptr, 0, nullptr, nullptr, 2, 256);

  y_kernel<<<1024, 256, 0, stream>>>(h2b, W3, b3, outp);

  // default-values scorer branch (f32, wave-per-output)
  fc_wave<512, 1><<<2048, 256, 0, stream>>>(dv, W1, b1, h1d, 512);
  fc_wave<512, 1><<<1024, 256, 0, stream>>>(h1d, W2, b2, h2d, 256);
  fc_wave<256, 2><<<4, 256, 0, stream>>>(h2d, W3, b3, outp + 16384, 1);

  (void)in_sizes; (void)n_in; (void)out_size; (void)ws_size;
}

// Round 8
// 180.679 us; speedup vs baseline: 1.0530x; 1.0296x over previous
//
#include <hip/hip_runtime.h>

typedef _Float16 f16;
typedef f16  f16x8 __attribute__((ext_vector_type(8)));
typedef f16  f16x4 __attribute__((ext_vector_type(4)));
typedef float f32x4 __attribute__((ext_vector_type(4)));

__device__ __forceinline__ void gld_lds16(const f16* g, void* l) {
  __builtin_amdgcn_global_load_lds((const __attribute__((address_space(1))) void*)g,
                                   (__attribute__((address_space(3))) void*)l,
                                   16, 0, 0);
}

enum { EPI_SCORES = 0, EPI_RELU = 2, EPI_OUT = 3, EPI_BIASR = 4 };

// C[M,N] = A[M,K] @ B[N,K]^T, 128x128 tile, BK=32, 4 waves (2x2), 16x16x32 f16 MFMA.
// 3-stage LDS pipeline, counted vmcnt (never 0 mid-loop), raw s_barrier, swizzled LDS.
// NOTE (R6 post-mortem): keep 128x128 with >=2 blocks/CU. A 256x128 8-wave variant at
// 1 block/CU regressed ~9us: same waves/CU but a single barrier stalls the whole CU,
// losing cross-block overlap. Only adopt fatter tiles when MFMA:load per barrier ~2x.
template<int EPI, bool XMAP>
__global__ __launch_bounds__(256)
void gemm_bt(const f16* __restrict__ A, const f16* __restrict__ B, void* __restrict__ C,
             int lda, int ldb, int ldc, int K,
             long long sA, long long sB, long long sC,
             const float* __restrict__ bias, float scale,
             float* __restrict__ mmarr, int nmm,
             const float* __restrict__ wfb, const float* __restrict__ dvv,
             int nx, int nbz)
{
  __shared__ __align__(16) f16 As[3][128][32];
  __shared__ __align__(16) f16 Bs[3][128][32];
  const int tid  = threadIdx.x;
  const int lane = tid & 63;
  const int w    = tid >> 6;
  const int wm   = w >> 1, wn = w & 1;

  const int lin = blockIdx.x;
  int bz, bj;
  if constexpr (XMAP) {
    const int xcd = lin & 7, rest = lin >> 3;
    const int grp = rest / nbz;
    bj = rest - grp * nbz;
    bz = xcd + (grp << 3);
  } else {
    bz = lin / nbz; bj = lin - bz * nbz;
  }
  const int m0 = (bj / nx) * 128, n0 = (bj % nx) * 128;
  const f16* Ab = A + (size_t)bz * sA + (size_t)m0 * lda;
  const f16* Bb = B + (size_t)bz * sB + (size_t)n0 * ldb;

  f32x4 acc[4][4] = {};
  const int nsteps = K >> 5;

#define STAGE(bufb, ks)                                                              \
  {                                                                                  \
    const int k0_ = (ks) << 5;                                                       \
    _Pragma("unroll")                                                                \
    for (int i = 0; i < 2; ++i) {                                                    \
      const int ci = i * 256 + tid;                                                  \
      const int r  = ci >> 2;                                                        \
      const int sg = (ci & 3) ^ ((r >> 1) & 3);                                      \
      gld_lds16(Ab + (size_t)r * lda + k0_ + sg * 8,                                 \
                (char*)As + (bufb) + (size_t)(i * 256 + w * 64) * 16);               \
      gld_lds16(Bb + (size_t)r * ldb + k0_ + sg * 8,                                 \
                (char*)Bs + (bufb) + (size_t)(i * 256 + w * 64) * 16);               \
    }                                                                                \
  }

  STAGE(0, 0)
  STAGE(8192, 1)

  const int elemoff = (((lane >> 4) ^ ((lane >> 1) & 3)) << 3);

  int cur = 0;
  for (int t = 0; t < nsteps; ++t) {
    if (t + 1 < nsteps) asm volatile("s_waitcnt vmcnt(4)" ::: "memory");
    else                asm volatile("s_waitcnt vmcnt(0)" ::: "memory");
    __builtin_amdgcn_s_barrier();
    __builtin_amdgcn_sched_barrier(0);
    int st = cur + 2; if (st >= 3) st -= 3;
    if (t + 2 < nsteps) STAGE(st * 8192, t + 2)
    f16x8 af[4], bfr[4];
#pragma unroll
    for (int m = 0; m < 4; ++m)
      af[m] = *(const f16x8*)&As[cur][wm * 64 + m * 16 + (lane & 15)][elemoff];
#pragma unroll
    for (int n = 0; n < 4; ++n)
      bfr[n] = *(const f16x8*)&Bs[cur][wn * 64 + n * 16 + (lane & 15)][elemoff];
    __builtin_amdgcn_s_setprio(1);
#pragma unroll
    for (int m = 0; m < 4; ++m)
#pragma unroll
      for (int n = 0; n < 4; ++n)
        acc[m][n] = __builtin_amdgcn_mfma_f32_16x16x32_f16(af[m], bfr[n], acc[m][n], 0, 0, 0);
    __builtin_amdgcn_s_setprio(0);
    cur = (cur + 1 == 3) ? 0 : cur + 1;
  }
#undef STAGE

  const int col_l = lane & 15;
  const int row_l = (lane >> 4) << 2;

  {
    f16* Ch = (f16*)C + (size_t)bz * sC + (size_t)m0 * ldc + n0;
#pragma unroll
    for (int m = 0; m < 4; ++m)
#pragma unroll
      for (int n = 0; n < 4; ++n)
#pragma unroll
        for (int r = 0; r < 4; ++r) {
          const int rr = wm * 64 + m * 16 + row_l + r;
          const int cc = wn * 64 + n * 16 + col_l;
          float val = acc[m][n][r];
          if constexpr (EPI == EPI_RELU) { val += bias[n0 + cc]; val = fmaxf(val, 0.0f); }
          if constexpr (EPI == EPI_BIASR) val += bias[m0 + rr];
          if constexpr (EPI == EPI_OUT)
            val += wfb[bz * 1024 + m0 + rr] * dvv[bz * 512 + n0 + cc];
          Ch[(size_t)rr * ldc + cc] = (f16)val;
        }
  }
  (void)scale; (void)mmarr; (void)nmm;
}

// 256x256 tile scores GEMM: C = (A @ B^T) * scale -> f16, per-block max/min.
// 8 waves (2m x 4n), BK=32, 3-buffer / stage(t+2) / vmcnt(4) skeleton. Grid 256 (1/CU);
// pays for the single-barrier stall via 32 MFMA : 4 loads per thread per K-step.
__global__ __launch_bounds__(512, 2)
void gemm256_scores(const f16* __restrict__ A, const f16* __restrict__ B, f16* __restrict__ C,
                    float scale, float* __restrict__ mmarr)
{
  __shared__ __align__(16) f16 As[3][256][32];
  __shared__ __align__(16) f16 Bs[3][256][32];
  __shared__ float redm[8], redn[8];
  const int tid  = threadIdx.x;
  const int lane = tid & 63;
  const int w    = tid >> 6;           // 0..7
  const int wm   = w >> 2, wn = w & 3; // 2 x 4
  const int lin  = blockIdx.x;
  const int xcd = lin & 7, rest = lin >> 3;
  const int bj  = rest & 15;
  const int bz  = xcd + ((rest >> 4) << 3);
  const int m0 = (bj >> 2) * 256, n0 = (bj & 3) * 256;
  const f16* Ab = A + (size_t)bz * 524288 + (size_t)m0 * 512;
  const f16* Bb = B + (size_t)bz * 524288 + (size_t)n0 * 512;

  f32x4 acc[8][4] = {};

#define STAGE2(bufb, ks)                                                             \
  {                                                                                  \
    const int k0_ = (ks) << 5;                                                       \
    _Pragma("unroll")                                                                \
    for (int i = 0; i < 2; ++i) {                                                    \
      const int ci = i * 512 + tid;                                                  \
      const int r  = ci >> 2;                                                        \
      const int sg = (ci & 3) ^ ((r >> 1) & 3);                                      \
      gld_lds16(Ab + (size_t)r * 512 + k0_ + sg * 8,                                 \
                (char*)As + (bufb) + (size_t)(i * 512 + w * 64) * 16);               \
      gld_lds16(Bb + (size_t)r * 512 + k0_ + sg * 8,                                 \
                (char*)Bs + (bufb) + (size_t)(i * 512 + w * 64) * 16);               \
    }                                                                                \
  }

  STAGE2(0, 0)
  STAGE2(16384, 1)

  const int elemoff = (((lane >> 4) ^ ((lane >> 1) & 3)) << 3);

  int cur = 0;
  for (int t = 0; t < 16; ++t) {
    if (t + 1 < 16) asm volatile("s_waitcnt vmcnt(4)" ::: "memory");
    else            asm volatile("s_waitcnt vmcnt(0)" ::: "memory");
    __builtin_amdgcn_s_barrier();
    __builtin_amdgcn_sched_barrier(0);
    int st = cur + 2; if (st >= 3) st -= 3;
    if (t + 2 < 16) STAGE2(st * 16384, t + 2)
    f16x8 af[8], bfr[4];
#pragma unroll
    for (int m = 0; m < 8; ++m)
      af[m] = *(const f16x8*)&As[cur][wm * 128 + m * 16 + (lane & 15)][elemoff];
#pragma unroll
    for (int n = 0; n < 4; ++n)
      bfr[n] = *(const f16x8*)&Bs[cur][wn * 64 + n * 16 + (lane & 15)][elemoff];
    __builtin_amdgcn_s_setprio(1);
#pragma unroll
    for (int m = 0; m < 8; ++m)
#pragma unroll
      for (int n = 0; n < 4; ++n)
        acc[m][n] = __builtin_amdgcn_mfma_f32_16x16x32_f16(af[m], bfr[n], acc[m][n], 0, 0, 0);
    __builtin_amdgcn_s_setprio(0);
    cur = (cur + 1 == 3) ? 0 : cur + 1;
  }
#undef STAGE2

  const int col_l = lane & 15;
  const int row_l = (lane >> 4) << 2;
  f16* Ch = C + (size_t)bz * 1048576 + (size_t)m0 * 1024 + n0;
  float lmax = -3.402823466e38f, lmin = 3.402823466e38f;
#pragma unroll
  for (int m = 0; m < 8; ++m)
#pragma unroll
    for (int n = 0; n < 4; ++n)
#pragma unroll
      for (int r = 0; r < 4; ++r) {
        float val = acc[m][n][r] * scale;
        lmax = fmaxf(lmax, val); lmin = fminf(lmin, val);
        Ch[(size_t)(wm * 128 + m * 16 + row_l + r) * 1024 + (wn * 64 + n * 16 + col_l)] = (f16)val;
      }
#pragma unroll
  for (int off = 32; off >= 1; off >>= 1) {
    lmax = fmaxf(lmax, __shfl_xor(lmax, off));
    lmin = fminf(lmin, __shfl_xor(lmin, off));
  }
  if (lane == 0) { redm[w] = lmax; redn[w] = lmin; }
  __syncthreads();
  if (tid == 0) {
    float gm = redm[0], gn = redn[0];
#pragma unroll
    for (int i = 1; i < 8; ++i) { gm = fmaxf(gm, redm[i]); gn = fminf(gn, redn[i]); }
    mmarr[lin] = gm; mmarr[256 + lin] = gn;
  }
}

// reduce per-block max/min -> fb scalar; also counts nonzero mask bytes (dtype sniff)
__global__ __launch_bounds__(256)
void reduce_mm(const float* __restrict__ mmarr, int n,
               const float* __restrict__ fallback, float* __restrict__ fbv,
               const unsigned char* __restrict__ mask, unsigned* __restrict__ mm)
{
  __shared__ float rm[4], rn[4];
  __shared__ int redc[256];
  const int lane = threadIdx.x & 63, w = threadIdx.x >> 6;
  float mx = -3.402823466e38f, mn = 3.402823466e38f;
  for (int i = threadIdx.x; i < n; i += 256) {
    mx = fmaxf(mx, mmarr[i]);
    mn = fminf(mn, mmarr[n + i]);
  }
#pragma unroll
  for (int off = 32; off >= 1; off >>= 1) {
    mx = fmaxf(mx, __shfl_xor(mx, off));
    mn = fminf(mn, __shfl_xor(mn, off));
  }
  if (lane == 0) { rm[w] = mx; rn[w] = mn; }
  int c = 0;
  for (int i = threadIdx.x; i < 16384; i += 256) c += (mask[i] != 0) ? 1 : 0;
  redc[threadIdx.x] = c;
  __syncthreads();
  for (int s = 128; s > 0; s >>= 1) {
    if (threadIdx.x < s) redc[threadIdx.x] += redc[threadIdx.x + s];
    __syncthreads();
  }
  if (threadIdx.x == 0) {
    float gmax = fmaxf(fmaxf(rm[0], rm[1]), fmaxf(rm[2], rm[3]));
    float gmin = fminf(fminf(rn[0], rn[1]), fminf(rn[2], rn[3]));
    fbv[0] = 0.99f * fallback[0] + 0.005f * (gmax + gmin);
    mm[0] = (unsigned)redc[0];
  }
}

// fused f32->f16 convert of q,k,v. Block-uniform tensor select (blk>>10); per thread:
// load 8 float4 into named regs (all in flight), then 4x f16x8 16B stores.
// 3 x 1024 blocks x 256 thr x 4 units x 8 floats = 3 x 8M floats.
__global__ __launch_bounds__(256)
void conv3_k(const float* __restrict__ a, const float* __restrict__ b,
             const float* __restrict__ c,
             f16* __restrict__ oa, f16* __restrict__ ob, f16* __restrict__ oc)
{
  const int blk = blockIdx.x;
  const int s   = blk >> 10;
  const int lb  = blk & 1023;
  const float* src = (s == 0) ? a : ((s == 1) ? b : c);
  f16*         dst = (s == 0) ? oa : ((s == 1) ? ob : oc);
  const size_t base = (size_t)lb * 8192 + threadIdx.x * 8;
  float4 v0a = *(const float4*)(src + base);
  float4 v0b = *(const float4*)(src + base + 4);
  float4 v1a = *(const float4*)(src + base + 2048);
  float4 v1b = *(const float4*)(src + base + 2052);
  float4 v2a = *(const float4*)(src + base + 4096);
  float4 v2b = *(const float4*)(src + base + 4100);
  float4 v3a = *(const float4*)(src + base + 6144);
  float4 v3b = *(const float4*)(src + base + 6148);
  f16x8 o0 = { (f16)v0a.x,(f16)v0a.y,(f16)v0a.z,(f16)v0a.w,(f16)v0b.x,(f16)v0b.y,(f16)v0b.z,(f16)v0b.w };
  *(f16x8*)(dst + base) = o0;
  f16x8 o1 = { (f16)v1a.x,(f16)v1a.y,(f16)v1a.z,(f16)v1a.w,(f16)v1b.x,(f16)v1b.y,(f16)v1b.z,(f16)v1b.w };
  *(f16x8*)(dst + base + 2048) = o1;
  f16x8 o2 = { (f16)v2a.x,(f16)v2a.y,(f16)v2a.z,(f16)v2a.w,(f16)v2b.x,(f16)v2b.y,(f16)v2b.z,(f16)v2b.w };
  *(f16x8*)(dst + base + 4096) = o2;
  f16x8 o3 = { (f16)v3a.x,(f16)v3a.y,(f16)v3a.z,(f16)v3a.w,(f16)v3b.x,(f16)v3b.y,(f16)v3b.z,(f16)v3b.w };
  *(f16x8*)(dst + base + 6144) = o3;
}

__global__ __launch_bounds__(256)
void convw_k(const float* __restrict__ wv, const float* __restrict__ w1,
             const float* __restrict__ w2,
             f16* __restrict__ owv, f16* __restrict__ ow1, f16* __restrict__ ow2)
{
  int i = blockIdx.x * 256 + threadIdx.x;   // 0..163839
  const float* src; f16* dst; int j;
  if (i < 65536)       { src = wv; dst = owv; j = i; }
  else if (i < 131072) { src = w1; dst = ow1; j = i - 65536; }
  else                 { src = w2; dst = ow2; j = i - 131072; }
  float4 v = *(const float4*)(src + (size_t)j * 4);
  f16x4 o = { (f16)v.x, (f16)v.y, (f16)v.z, (f16)v.w };
  *(f16x4*)(dst + (size_t)j * 4) = o;
}

__global__ __launch_bounds__(256)
void softmax_rows(const f16* __restrict__ scores, const void* __restrict__ maskp,
                  const float* __restrict__ fbv, const unsigned* __restrict__ mm,
                  f16* __restrict__ Wt, float* __restrict__ wfb)
{
  __shared__ float red[8];
  const int row  = blockIdx.x;
  const int b    = row >> 10;
  const int tid  = threadIdx.x;
  const int lane = tid & 63, w = tid >> 6;
  const float fb = fbv[0];
  const unsigned mode = (mm[0] > 5000u) ? 1u : 0u;
  const f16* s = scores + (size_t)row * 1024;
  const int k0 = tid * 4;
  f16x4 sv = *(const f16x4*)(s + k0);
  float x[4];
  if (mode) {
    const unsigned char* m8 = (const unsigned char*)maskp + b * 1024 + k0;
    x[0] = m8[0] ? -1e9f : (float)sv[0];  x[1] = m8[1] ? -1e9f : (float)sv[1];
    x[2] = m8[2] ? -1e9f : (float)sv[2];  x[3] = m8[3] ? -1e9f : (float)sv[3];
  } else {
    const int* mi = (const int*)maskp + b * 1024 + k0;
    x[0] = mi[0] ? -1e9f : (float)sv[0];  x[1] = mi[1] ? -1e9f : (float)sv[1];
    x[2] = mi[2] ? -1e9f : (float)sv[2];  x[3] = mi[3] ? -1e9f : (float)sv[3];
  }
  float mx = fmaxf(fmaxf(x[0], x[1]), fmaxf(x[2], x[3]));
#pragma unroll
  for (int off = 32; off >= 1; off >>= 1) mx = fmaxf(mx, __shfl_xor(mx, off));
  if (lane == 0) red[w] = mx;
  __syncthreads();
  mx = fmaxf(fmaxf(fmaxf(red[0], red[1]), fmaxf(red[2], red[3])), fb);
  float e0 = expf(x[0] - mx), e1 = expf(x[1] - mx), e2 = expf(x[2] - mx), e3 = expf(x[3] - mx);
  float sum = (e0 + e1) + (e2 + e3);
#pragma unroll
  for (int off = 32; off >= 1; off >>= 1) sum += __shfl_xor(sum, off);
  if (lane == 0) red[4 + w] = sum;
  __syncthreads();
  float efb = expf(fb - mx);
  float Z = ((red[4] + red[5]) + (red[6] + red[7])) + efb;
  float inv = 1.0f / Z;
  f16x4 o = { (f16)(e0 * inv), (f16)(e1 * inv), (f16)(e2 * inv), (f16)(e3 * inv) };
  *(f16x4*)&Wt[(size_t)row * 1024 + k0] = o;
  if (tid == 0) wfb[row] = efb * inv;
}

// wave-per-output FC: Y[b,j] = act(X[b,:] . W[j,:] + bias[j])
template<int IN, int ACT>
__global__ __launch_bounds__(256)
void fc_wave(const float* __restrict__ X, const float* __restrict__ W,
             const float* __restrict__ bias, float* __restrict__ Y, int OutN)
{
  const int gw   = (blockIdx.x * 256 + threadIdx.x) >> 6;
  const int lane = threadIdx.x & 63;
  const int b = gw / OutN, j = gw - b * OutN;
  const float* x  = X + (size_t)b * IN;
  const float* wr = W + (size_t)j * IN;
  float s = 0.f;
  if constexpr (IN == 512) {
    const int o = lane * 8;
    float4 x0 = *(const float4*)(x + o),  x1 = *(const float4*)(x + o + 4);
    float4 w0 = *(const float4*)(wr + o), w1 = *(const float4*)(wr + o + 4);
    s = x0.x*w0.x + x0.y*w0.y + x0.z*w0.z + x0.w*w0.w
      + x1.x*w1.x + x1.y*w1.y + x1.z*w1.z + x1.w*w1.w;
  } else {
    const int o = lane * 4;
    float4 x0 = *(const float4*)(x + o);
    float4 w0 = *(const float4*)(wr + o);
    s = x0.x*w0.x + x0.y*w0.y + x0.z*w0.z + x0.w*w0.w;
  }
#pragma unroll
  for (int off = 32; off >= 1; off >>= 1) s += __shfl_xor(s, off);
  if (lane == 0) {
    float val = s + bias[ACT == 2 ? 0 : j];
    if constexpr (ACT == 1) val = fmaxf(val, 0.f);
    if constexpr (ACT == 2) val = tanhf(val);
    Y[gw] = val;
  }
}

__global__ __launch_bounds__(256)
void y_kernel(const f16* __restrict__ h2, const float* __restrict__ W3,
              const float* __restrict__ b3, float* __restrict__ outp)
{
  int row = blockIdx.x * 16 + (threadIdx.x >> 4);
  int l   = threadIdx.x & 15;
  const f16* h = h2 + (size_t)row * 256 + l * 16;
  float s = 0.f;
#pragma unroll
  for (int j = 0; j < 16; ++j) s += (float)h[j] * W3[l * 16 + j];
#pragma unroll
  for (int off = 1; off < 16; off <<= 1) s += __shfl_xor(s, off);
  if (l == 0) outp[row] = tanhf(s + b3[0]);
}

extern "C" void kernel_launch(void* const* d_in, const int* in_sizes, int n_in,
                              void* d_out, int out_size, void* d_ws, size_t ws_size,
                              hipStream_t stream) {
  const float* uq       = (const float*)d_in[0];
  const float* q        = (const float*)d_in[1];
  const float* kk       = (const float*)d_in[2];
  const float* v        = (const float*)d_in[3];
  const void*  mask     = d_in[4];
  const float* fallback = (const float*)d_in[5];
  const float* Wv = (const float*)d_in[6];
  const float* bv = (const float*)d_in[7];
  const float* Wf = (const float*)d_in[8];
  const float* bf = (const float*)d_in[9];
  const float* W1 = (const float*)d_in[10];
  const float* b1 = (const float*)d_in[11];
  const float* W2 = (const float*)d_in[12];
  const float* b2 = (const float*)d_in[13];
  const float* W3 = (const float*)d_in[14];
  const float* b3 = (const float*)d_in[15];
  float* outp = (float*)d_out;

  char* ws = (char*)d_ws;
  const size_t MB = 1ull << 20;
  f16*  scores = (f16*)ws;
  f16*  h1b  = (f16*)ws;
  f16*  h2b  = (f16*)(ws + 16 * MB);
  f16*  vpt  = (f16*)(ws + 32 * MB);
  f16*  outb = (f16*)(ws + 48 * MB);
  f16*  q16  = (f16*)(ws + 64 * MB);
  f16*  wts  = (f16*)(ws + 64 * MB);
  f16*  k16  = (f16*)(ws + 80 * MB);
  f16*  v16  = (f16*)(ws + 96 * MB);
  char* cst  = ws + 112 * MB;
  f16*  Wv16 = (f16*)(cst);
  f16*  W116 = (f16*)(cst + 512 * 1024);
  f16*  W216 = (f16*)(cst + 1024 * 1024);
  float* dv   = (float*)(cst + 1280 * 1024);
  float* wfb  = (float*)(cst + 1312 * 1024);
  float* h1d  = (float*)(cst + 1376 * 1024);
  float* h2d  = (float*)(cst + 1408 * 1024);
  unsigned* mm = (unsigned*)(cst + 1424 * 1024);
  float* fbv   = (float*)(cst + 1428 * 1024);
  float* mmarr = (float*)(cst + 1432 * 1024);   // 2 * 256 floats

  conv3_k<<<3072, 256, 0, stream>>>(q, kk, v, q16, k16, v16);
  convw_k<<<640, 256, 0, stream>>>(Wv, W1, W2, Wv16, W116, W216);

  // dv = uq @ Wf^T + bf
  fc_wave<512, 0><<<2048, 256, 0, stream>>>(uq, Wf, bf, dv, 512);

  // scores = q @ k^T / sqrt(512) -> f16, per-block max/min (256x256 tiles, 8 waves)
  gemm256_scores<<<256, 512, 0, stream>>>(q16, k16, scores, 0.04419417382415922f, mmarr);

  reduce_mm<<<1, 256, 0, stream>>>(mmarr, 256, fallback, fbv,
                                   (const unsigned char*)mask, mm);

  softmax_rows<<<16384, 256, 0, stream>>>(scores, mask, fbv, mm, wts, wfb);

  // vpt[d][k] = sum_e Wv[d][e] v[k][e] + bv[d]
  gemm_bt<EPI_BIASR, true><<<512, 256, 0, stream>>>(
      Wv16, v16, vpt, 512, 512, 1024, 512,
      0LL, 524288LL, 524288LL,
      bv, 1.f, nullptr, 0, nullptr, nullptr, 8, 32);

  // out = weights @ vp + wfb*dv
  gemm_bt<EPI_OUT, true><<<512, 256, 0, stream>>>(
      wts, vpt, outb, 1024, 1024, 512, 1024,
      1048576LL, 524288LL, 524288LL,
      nullptr, 1.f, nullptr, 0, wfb, dv, 4, 32);

  // h1 = relu(out @ W1^T + b1)
  gemm_bt<EPI_RELU, false><<<512, 256, 0, stream>>>(
      outb, W116, h1b, 512, 512, 512, 512, 0LL, 0LL, 0LL,
      b1, 1.f, nullptr, 0, nullptr, nullptr, 4, 512);

  // h2 = relu(h1 @ W2^T + b2)
  gemm_bt<EPI_RELU, false><<<256, 256, 0, stream>>>(
      h1b, W216, h2b, 512, 512, 256, 512, 0LL, 0LL, 0LL,
      b2, 1.f, nullptr, 0, nullptr, nullptr, 2, 256);

  y_kernel<<<1024, 256, 0, stream>>>(h2b, W3, b3, outp);

  // default-values scorer branch (f32, wave-per-output)
  fc_wave<512, 1><<<2048, 256, 0, stream>>>(dv, W1, b1, h1d, 512);
  fc_wave<512, 1><<<1024, 256, 0, stream>>>(h1d, W2, b2, h2d, 256);
  fc_wave<256, 2><<<4, 256, 0, stream>>>(h2d, W3, b3, outp + 16384, 1);

  (void)in_sizes; (void)n_in; (void)out_size; (void)ws_size;
}

// Round 10
// 175.063 us; speedup vs baseline: 1.0868x; 1.0321x over previous
//
#include <hip/hip_runtime.h>

typedef _Float16 f16;
typedef f16  f16x8 __attribute__((ext_vector_type(8)));
typedef f16  f16x4 __attribute__((ext_vector_type(4)));
typedef __fp16 fp16x2 __attribute__((ext_vector_type(2)));
typedef float f32x4 __attribute__((ext_vector_type(4)));

__device__ __forceinline__ void gld_lds16(const f16* g, void* l) {
  __builtin_amdgcn_global_load_lds((const __attribute__((address_space(1))) void*)g,
                                   (__attribute__((address_space(3))) void*)l,
                                   16, 0, 0);
}
__device__ __forceinline__ void gld_lds16f(const float* g, void* l) {
  __builtin_amdgcn_global_load_lds((const __attribute__((address_space(1))) void*)g,
                                   (__attribute__((address_space(3))) void*)l,
                                   16, 0, 0);
}

// pack 8 f32 -> f16x8 via v_cvt_pkrtz (RTZ)
__device__ __forceinline__ f16x8 pack8(float4 a, float4 b) {
  union { f16x8 v; fp16x2 h[4]; } u;
  u.h[0] = __builtin_amdgcn_cvt_pkrtz(a.x, a.y);
  u.h[1] = __builtin_amdgcn_cvt_pkrtz(a.z, a.w);
  u.h[2] = __builtin_amdgcn_cvt_pkrtz(b.x, b.y);
  u.h[3] = __builtin_amdgcn_cvt_pkrtz(b.z, b.w);
  return u.v;
}

enum { EPI_SCORES = 0, EPI_RELU = 2, EPI_OUT = 3, EPI_BIASR = 4 };

// C[M,N] = A[M,K] @ B[N,K]^T, 128x128 tile, BK=32, 4 waves (2x2), 16x16x32 f16 MFMA.
// 3-stage LDS pipeline, counted vmcnt (never 0 mid-loop), raw s_barrier, swizzled LDS.
// NOTE (R6): keep 128x128 with >=2 blocks/CU; fatter tiles at 1 block/CU regressed.
template<int EPI, bool XMAP>
__global__ __launch_bounds__(256)
void gemm_bt(const f16* __restrict__ A, const f16* __restrict__ B, void* __restrict__ C,
             int lda, int ldb, int ldc, int K,
             long long sA, long long sB, long long sC,
             const float* __restrict__ bias, float scale,
             float* __restrict__ mmarr, int nmm,
             const float* __restrict__ wfb, const float* __restrict__ dvv,
             int nx, int nbz)
{
  __shared__ __align__(16) f16 As[3][128][32];
  __shared__ __align__(16) f16 Bs[3][128][32];
  const int tid  = threadIdx.x;
  const int lane = tid & 63;
  const int w    = tid >> 6;
  const int wm   = w >> 1, wn = w & 1;

  const int lin = blockIdx.x;
  int bz, bj;
  if constexpr (XMAP) {
    const int xcd = lin & 7, rest = lin >> 3;
    const int grp = rest / nbz;
    bj = rest - grp * nbz;
    bz = xcd + (grp << 3);
  } else {
    bz = lin / nbz; bj = lin - bz * nbz;
  }
  const int m0 = (bj / nx) * 128, n0 = (bj % nx) * 128;
  const f16* Ab = A + (size_t)bz * sA + (size_t)m0 * lda;
  const f16* Bb = B + (size_t)bz * sB + (size_t)n0 * ldb;

  f32x4 acc[4][4] = {};
  const int nsteps = K >> 5;

#define STAGE(bufb, ks)                                                              \
  {                                                                                  \
    const int k0_ = (ks) << 5;                                                       \
    _Pragma("unroll")                                                                \
    for (int i = 0; i < 2; ++i) {                                                    \
      const int ci = i * 256 + tid;                                                  \
      const int r  = ci >> 2;                                                        \
      const int sg = (ci & 3) ^ ((r >> 1) & 3);                                      \
      gld_lds16(Ab + (size_t)r * lda + k0_ + sg * 8,                                 \
                (char*)As + (bufb) + (size_t)(i * 256 + w * 64) * 16);               \
      gld_lds16(Bb + (size_t)r * ldb + k0_ + sg * 8,                                 \
                (char*)Bs + (bufb) + (size_t)(i * 256 + w * 64) * 16);               \
    }                                                                                \
  }

  STAGE(0, 0)
  STAGE(8192, 1)

  const int elemoff = (((lane >> 4) ^ ((lane >> 1) & 3)) << 3);

  int cur = 0;
  for (int t = 0; t < nsteps; ++t) {
    if (t + 1 < nsteps) asm volatile("s_waitcnt vmcnt(4)" ::: "memory");
    else                asm volatile("s_waitcnt vmcnt(0)" ::: "memory");
    __builtin_amdgcn_s_barrier();
    __builtin_amdgcn_sched_barrier(0);
    int st = cur + 2; if (st >= 3) st -= 3;
    if (t + 2 < nsteps) STAGE(st * 8192, t + 2)
    f16x8 af[4], bfr[4];
#pragma unroll
    for (int m = 0; m < 4; ++m)
      af[m] = *(const f16x8*)&As[cur][wm * 64 + m * 16 + (lane & 15)][elemoff];
#pragma unroll
    for (int n = 0; n < 4; ++n)
      bfr[n] = *(const f16x8*)&Bs[cur][wn * 64 + n * 16 + (lane & 15)][elemoff];
    __builtin_amdgcn_s_setprio(1);
#pragma unroll
    for (int m = 0; m < 4; ++m)
#pragma unroll
      for (int n = 0; n < 4; ++n)
        acc[m][n] = __builtin_amdgcn_mfma_f32_16x16x32_f16(af[m], bfr[n], acc[m][n], 0, 0, 0);
    __builtin_amdgcn_s_setprio(0);
    cur = (cur + 1 == 3) ? 0 : cur + 1;
  }
#undef STAGE

  const int col_l = lane & 15;
  const int row_l = (lane >> 4) << 2;

  {
    f16* Ch = (f16*)C + (size_t)bz * sC + (size_t)m0 * ldc + n0;
#pragma unroll
    for (int m = 0; m < 4; ++m)
#pragma unroll
      for (int n = 0; n < 4; ++n)
#pragma unroll
        for (int r = 0; r < 4; ++r) {
          const int rr = wm * 64 + m * 16 + row_l + r;
          const int cc = wn * 64 + n * 16 + col_l;
          float val = acc[m][n][r];
          if constexpr (EPI == EPI_RELU) { val += bias[n0 + cc]; val = fmaxf(val, 0.0f); }
          if constexpr (EPI == EPI_BIASR) val += bias[m0 + rr];
          if constexpr (EPI == EPI_OUT)
            val += wfb[bz * 1024 + m0 + rr] * dvv[bz * 512 + n0 + cc];
          Ch[(size_t)rr * ldc + cc] = (f16)val;
        }
  }
  (void)scale; (void)mmarr; (void)nmm;
}

// 256x256 scores GEMM reading q,k DIRECTLY in f32 (no pre-convert kernel).
// f32 tiles staged to LDS via global_load_lds (2-stage dbuf, 128KB), converted to f16
// during the LDS->reg fragment read (v_cvt_pkrtz). 8 loads/thread/stage -> vmcnt(8).
// Swizzle (rule #21): src chunk sg=(ci&7)^(((ci>>4)&3)<<1); read eo in f32 units.
__global__ __launch_bounds__(512, 2)
void gemm256_scores(const float* __restrict__ A, const float* __restrict__ B, f16* __restrict__ C,
                    float scale, float* __restrict__ mmarr)
{
  __shared__ __align__(16) float AsF[2][256][32];
  __shared__ __align__(16) float BsF[2][256][32];
  __shared__ float redm[8], redn[8];
  const int tid  = threadIdx.x;
  const int lane = tid & 63;
  const int w    = tid >> 6;           // 0..7
  const int wm   = w >> 2, wn = w & 3; // 2 x 4
  const int lin  = blockIdx.x;
  const int xcd = lin & 7, rest = lin >> 3;
  const int bj  = rest & 15;
  const int bz  = xcd + ((rest >> 4) << 3);
  const int m0 = (bj >> 2) * 256, n0 = (bj & 3) * 256;
  const float* Ab = A + (size_t)bz * 524288 + (size_t)m0 * 512;
  const float* Bb = B + (size_t)bz * 524288 + (size_t)n0 * 512;

  f32x4 acc[8][4] = {};

  // per stage: A tile 256x32 f32 = 32KB = 2048 16B-chunks; 4 chunks/thread each for A,B
#define STAGEF(bufb, ks)                                                             \
  {                                                                                  \
    const int k0_ = (ks) << 5;                                                       \
    _Pragma("unroll")                                                                \
    for (int i = 0; i < 4; ++i) {                                                    \
      const int ci = i * 512 + tid;                                                  \
      const int r  = ci >> 3;                                                        \
      const int sg = (ci & 7) ^ (((ci >> 4) & 3) << 1);                              \
      gld_lds16f(Ab + (size_t)r * 512 + k0_ + sg * 4,                                \
                 (char*)AsF + (bufb) + (size_t)ci * 16);                             \
      gld_lds16f(Bb + (size_t)r * 512 + k0_ + sg * 4,                                \
                 (char*)BsF + (bufb) + (size_t)ci * 16);                             \
    }                                                                                \
  }

  STAGEF(0, 0)
  STAGEF(32768, 1)

  const int fr = lane & 15;
  const int eo = (((lane >> 4) ^ ((lane >> 1) & 3)) << 3);  // f32 elements

  int cur = 0;
  for (int t = 0; t < 16; ++t) {
    if (t < 15) asm volatile("s_waitcnt vmcnt(8)" ::: "memory");
    else        asm volatile("s_waitcnt vmcnt(0)" ::: "memory");
    __builtin_amdgcn_s_barrier();
    __builtin_amdgcn_sched_barrier(0);
    const float* Ac = (const float*)((const char*)AsF + cur * 32768);
    const float* Bc = (const float*)((const char*)BsF + cur * 32768);
    f16x8 af[8], bfr[4];
#pragma unroll
    for (int m = 0; m < 8; ++m) {
      const float* p = Ac + (size_t)(wm * 128 + m * 16 + fr) * 32 + eo;
      af[m] = pack8(*(const float4*)p, *(const float4*)(p + 4));
    }
#pragma unroll
    for (int n = 0; n < 4; ++n) {
      const float* p = Bc + (size_t)(wn * 64 + n * 16 + fr) * 32 + eo;
      bfr[n] = pack8(*(const float4*)p, *(const float4*)(p + 4));
    }
    __builtin_amdgcn_s_setprio(1);
#pragma unroll
    for (int m = 0; m < 8; ++m)
#pragma unroll
      for (int n = 0; n < 4; ++n)
        acc[m][n] = __builtin_amdgcn_mfma_f32_16x16x32_f16(af[m], bfr[n], acc[m][n], 0, 0, 0);
    __builtin_amdgcn_s_setprio(0);
    __builtin_amdgcn_s_barrier();       // all waves done reading buf[cur]
    if (t + 2 < 16) STAGEF(cur * 32768, t + 2)
    cur ^= 1;
  }
#undef STAGEF

  const int col_l = lane & 15;
  const int row_l = (lane >> 4) << 2;
  f16* Ch = C + (size_t)bz * 1048576 + (size_t)m0 * 1024 + n0;
  float lmax = -3.402823466e38f, lmin = 3.402823466e38f;
#pragma unroll
  for (int m = 0; m < 8; ++m)
#pragma unroll
    for (int n = 0; n < 4; ++n)
#pragma unroll
      for (int r = 0; r < 4; ++r) {
        float val = acc[m][n][r] * scale;
        lmax = fmaxf(lmax, val); lmin = fminf(lmin, val);
        Ch[(size_t)(wm * 128 + m * 16 + row_l + r) * 1024 + (wn * 64 + n * 16 + col_l)] = (f16)val;
      }
#pragma unroll
  for (int off = 32; off >= 1; off >>= 1) {
    lmax = fmaxf(lmax, __shfl_xor(lmax, off));
    lmin = fminf(lmin, __shfl_xor(lmin, off));
  }
  if (lane == 0) { redm[w] = lmax; redn[w] = lmin; }
  __syncthreads();
  if (tid == 0) {
    float gm = redm[0], gn = redn[0];
#pragma unroll
    for (int i = 1; i < 8; ++i) { gm = fmaxf(gm, redm[i]); gn = fminf(gn, redn[i]); }
    mmarr[lin] = gm; mmarr[256 + lin] = gn;
  }
}

// reduce per-block max/min -> fb scalar; also counts nonzero mask bytes (dtype sniff)
__global__ __launch_bounds__(256)
void reduce_mm(const float* __restrict__ mmarr, int n,
               const float* __restrict__ fallback, float* __restrict__ fbv,
               const unsigned char* __restrict__ mask, unsigned* __restrict__ mm)
{
  __shared__ float rm[4], rn[4];
  __shared__ int redc[256];
  const int lane = threadIdx.x & 63, w = threadIdx.x >> 6;
  float mx = -3.402823466e38f, mn = 3.402823466e38f;
  for (int i = threadIdx.x; i < n; i += 256) {
    mx = fmaxf(mx, mmarr[i]);
    mn = fminf(mn, mmarr[n + i]);
  }
#pragma unroll
  for (int off = 32; off >= 1; off >>= 1) {
    mx = fmaxf(mx, __shfl_xor(mx, off));
    mn = fminf(mn, __shfl_xor(mn, off));
  }
  if (lane == 0) { rm[w] = mx; rn[w] = mn; }
  int c = 0;
  for (int i = threadIdx.x; i < 16384; i += 256) c += (mask[i] != 0) ? 1 : 0;
  redc[threadIdx.x] = c;
  __syncthreads();
  for (int s = 128; s > 0; s >>= 1) {
    if (threadIdx.x < s) redc[threadIdx.x] += redc[threadIdx.x + s];
    __syncthreads();
  }
  if (threadIdx.x == 0) {
    float gmax = fmaxf(fmaxf(rm[0], rm[1]), fmaxf(rm[2], rm[3]));
    float gmin = fminf(fminf(rn[0], rn[1]), fminf(rn[2], rn[3]));
    fbv[0] = 0.99f * fallback[0] + 0.005f * (gmax + gmin);
    mm[0] = (unsigned)redc[0];
  }
}

// f32->f16 convert of v only (q,k consumed in f32 by the scores GEMM now)
__global__ __launch_bounds__(256)
void conv_v(const float* __restrict__ v, f16* __restrict__ v16)
{
  const int i = blockIdx.x * 256 + threadIdx.x;   // 524288 threads, 4 float4 each
#pragma unroll
  for (int it = 0; it < 4; ++it) {
    const size_t j = (size_t)i + (size_t)it * 524288;
    float4 x = *(const float4*)(v + j * 4);
    f16x4 o = { (f16)x.x, (f16)x.y, (f16)x.z, (f16)x.w };
    *(f16x4*)(v16 + j * 4) = o;
  }
}

__global__ __launch_bounds__(256)
void convw_k(const float* __restrict__ wv, const float* __restrict__ w1,
             const float* __restrict__ w2,
             f16* __restrict__ owv, f16* __restrict__ ow1, f16* __restrict__ ow2)
{
  int i = blockIdx.x * 256 + threadIdx.x;   // 0..163839
  const float* src; f16* dst; int j;
  if (i < 65536)       { src = wv; dst = owv; j = i; }
  else if (i < 131072) { src = w1; dst = ow1; j = i - 65536; }
  else                 { src = w2; dst = ow2; j = i - 131072; }
  float4 v = *(const float4*)(src + (size_t)j * 4);
  f16x4 o = { (f16)v.x, (f16)v.y, (f16)v.z, (f16)v.w };
  *(f16x4*)(dst + (size_t)j * 4) = o;
}

__global__ __launch_bounds__(256)
void softmax_rows(const f16* __restrict__ scores, const void* __restrict__ maskp,
                  const float* __restrict__ fbv, const unsigned* __restrict__ mm,
                  f16* __restrict__ Wt, float* __restrict__ wfb)
{
  __shared__ float red[8];
  const int row  = blockIdx.x;
  const int b    = row >> 10;
  const int tid  = threadIdx.x;
  const int lane = tid & 63, w = tid >> 6;
  const float fb = fbv[0];
  const unsigned mode = (mm[0] > 5000u) ? 1u : 0u;
  const f16* s = scores + (size_t)row * 1024;
  const int k0 = tid * 4;
  f16x4 sv = *(const f16x4*)(s + k0);
  float x[4];
  if (mode) {
    const unsigned char* m8 = (const unsigned char*)maskp + b * 1024 + k0;
    x[0] = m8[0] ? -1e9f : (float)sv[0];  x[1] = m8[1] ? -1e9f : (float)sv[1];
    x[2] = m8[2] ? -1e9f : (float)sv[2];  x[3] = m8[3] ? -1e9f : (float)sv[3];
  } else {
    const int* mi = (const int*)maskp + b * 1024 + k0;
    x[0] = mi[0] ? -1e9f : (float)sv[0];  x[1] = mi[1] ? -1e9f : (float)sv[1];
    x[2] = mi[2] ? -1e9f : (float)sv[2];  x[3] = mi[3] ? -1e9f : (float)sv[3];
  }
  float mx = fmaxf(fmaxf(x[0], x[1]), fmaxf(x[2], x[3]));
#pragma unroll
  for (int off = 32; off >= 1; off >>= 1) mx = fmaxf(mx, __shfl_xor(mx, off));
  if (lane == 0) red[w] = mx;
  __syncthreads();
  mx = fmaxf(fmaxf(fmaxf(red[0], red[1]), fmaxf(red[2], red[3])), fb);
  float e0 = expf(x[0] - mx), e1 = expf(x[1] - mx), e2 = expf(x[2] - mx), e3 = expf(x[3] - mx);
  float sum = (e0 + e1) + (e2 + e3);
#pragma unroll
  for (int off = 32; off >= 1; off >>= 1) sum += __shfl_xor(sum, off);
  if (lane == 0) red[4 + w] = sum;
  __syncthreads();
  float efb = expf(fb - mx);
  float Z = ((red[4] + red[5]) + (red[6] + red[7])) + efb;
  float inv = 1.0f / Z;
  f16x4 o = { (f16)(e0 * inv), (f16)(e1 * inv), (f16)(e2 * inv), (f16)(e3 * inv) };
  *(f16x4*)&Wt[(size_t)row * 1024 + k0] = o;
  if (tid == 0) wfb[row] = efb * inv;
}

// wave-per-output FC: Y[b,j] = act(X[b,:] . W[j,:] + bias[j])
template<int IN, int ACT>
__global__ __launch_bounds__(256)
void fc_wave(const float* __restrict__ X, const float* __restrict__ W,
             const float* __restrict__ bias, float* __restrict__ Y, int OutN)
{
  const int gw   = (blockIdx.x * 256 + threadIdx.x) >> 6;
  const int lane = threadIdx.x & 63;
  const int b = gw / OutN, j = gw - b * OutN;
  const float* x  = X + (size_t)b * IN;
  const float* wr = W + (size_t)j * IN;
  float s = 0.f;
  if constexpr (IN == 512) {
    const int o = lane * 8;
    float4 x0 = *(const float4*)(x + o),  x1 = *(const float4*)(x + o + 4);
    float4 w0 = *(const float4*)(wr + o), w1 = *(const float4*)(wr + o + 4);
    s = x0.x*w0.x + x0.y*w0.y + x0.z*w0.z + x0.w*w0.w
      + x1.x*w1.x + x1.y*w1.y + x1.z*w1.z + x1.w*w1.w;
  } else {
    const int o = lane * 4;
    float4 x0 = *(const float4*)(x + o);
    float4 w0 = *(const float4*)(wr + o);
    s = x0.x*w0.x + x0.y*w0.y + x0.z*w0.z + x0.w*w0.w;
  }
#pragma unroll
  for (int off = 32; off >= 1; off >>= 1) s += __shfl_xor(s, off);
  if (lane == 0) {
    float val = s + bias[ACT == 2 ? 0 : j];
    if constexpr (ACT == 1) val = fmaxf(val, 0.f);
    if constexpr (ACT == 2) val = tanhf(val);
    Y[gw] = val;
  }
}

__global__ __launch_bounds__(256)
void y_kernel(const f16* __restrict__ h2, const float* __restrict__ W3,
              const float* __restrict__ b3, float* __restrict__ outp)
{
  int row = blockIdx.x * 16 + (threadIdx.x >> 4);
  int l   = threadIdx.x & 15;
  const f16* h = h2 + (size_t)row * 256 + l * 16;
  float s = 0.f;
#pragma unroll
  for (int j = 0; j < 16; ++j) s += (float)h[j] * W3[l * 16 + j];
#pragma unroll
  for (int off = 1; off < 16; off <<= 1) s += __shfl_xor(s, off);
  if (l == 0) outp[row] = tanhf(s + b3[0]);
}

extern "C" void kernel_launch(void* const* d_in, const int* in_sizes, int n_in,
                              void* d_out, int out_size, void* d_ws, size_t ws_size,
                              hipStream_t stream) {
  const float* uq       = (const float*)d_in[0];
  const float* q        = (const float*)d_in[1];
  const float* kk       = (const float*)d_in[2];
  const float* v        = (const float*)d_in[3];
  const void*  mask     = d_in[4];
  const float* fallback = (const float*)d_in[5];
  const float* Wv = (const float*)d_in[6];
  const float* bv = (const float*)d_in[7];
  const float* Wf = (const float*)d_in[8];
  const float* bf = (const float*)d_in[9];
  const float* W1 = (const float*)d_in[10];
  const float* b1 = (const float*)d_in[11];
  const float* W2 = (const float*)d_in[12];
  const float* b2 = (const float*)d_in[13];
  const float* W3 = (const float*)d_in[14];
  const float* b3 = (const float*)d_in[15];
  float* outp = (float*)d_out;

  char* ws = (char*)d_ws;
  const size_t MB = 1ull << 20;
  f16*  scores = (f16*)ws;
  f16*  h1b  = (f16*)ws;
  f16*  h2b  = (f16*)(ws + 16 * MB);
  f16*  vpt  = (f16*)(ws + 32 * MB);
  f16*  outb = (f16*)(ws + 48 * MB);
  f16*  wts  = (f16*)(ws + 64 * MB);
  f16*  v16  = (f16*)(ws + 96 * MB);
  char* cst  = ws + 112 * MB;
  f16*  Wv16 = (f16*)(cst);
  f16*  W116 = (f16*)(cst + 512 * 1024);
  f16*  W216 = (f16*)(cst + 1024 * 1024);
  float* dv   = (float*)(cst + 1280 * 1024);
  float* wfb  = (float*)(cst + 1312 * 1024);
  float* h1d  = (float*)(cst + 1376 * 1024);
  float* h2d  = (float*)(cst + 1408 * 1024);
  unsigned* mm = (unsigned*)(cst + 1424 * 1024);
  float* fbv   = (float*)(cst + 1428 * 1024);
  float* mmarr = (float*)(cst + 1432 * 1024);   // 2 * 256 floats

  conv_v<<<2048, 256, 0, stream>>>(v, v16);
  convw_k<<<640, 256, 0, stream>>>(Wv, W1, W2, Wv16, W116, W216);

  // dv = uq @ Wf^T + bf
  fc_wave<512, 0><<<2048, 256, 0, stream>>>(uq, Wf, bf, dv, 512);

  // scores = q @ k^T / sqrt(512) -> f16, q/k read as f32 (256x256 tiles, 8 waves)
  gemm256_scores<<<256, 512, 0, stream>>>(q, kk, scores, 0.04419417382415922f, mmarr);

  reduce_mm<<<1, 256, 0, stream>>>(mmarr, 256, fallback, fbv,
                                   (const unsigned char*)mask, mm);

  softmax_rows<<<16384, 256, 0, stream>>>(scores, mask, fbv, mm, wts, wfb);

  // vpt[d][k] = sum_e Wv[d][e] v[k][e] + bv[d]
  gemm_bt<EPI_BIASR, true><<<512, 256, 0, stream>>>(
      Wv16, v16, vpt, 512, 512, 1024, 512,
      0LL, 524288LL, 524288LL,
      bv, 1.f, nullptr, 0, nullptr, nullptr, 8, 32);

  // out = weights @ vp + wfb*dv
  gemm_bt<EPI_OUT, true><<<512, 256, 0, stream>>>(
      wts, vpt, outb, 1024, 1024, 512, 1024,
      1048576LL, 524288LL, 524288LL,
      nullptr, 1.f, nullptr, 0, wfb, dv, 4, 32);

  // h1 = relu(out @ W1^T + b1)
  gemm_bt<EPI_RELU, false><<<512, 256, 0, stream>>>(
      outb, W116, h1b, 512, 512, 512, 512, 0LL, 0LL, 0LL,
      b1, 1.f, nullptr, 0, nullptr, nullptr, 4, 512);

  // h2 = relu(h1 @ W2^T + b2)
  gemm_bt<EPI_RELU, false><<<256, 256, 0, stream>>>(
      h1b, W216, h2b, 512, 512, 256, 512, 0LL, 0LL, 0LL,
      b2, 1.f, nullptr, 0, nullptr, nullptr, 2, 256);

  y_kernel<<<1024, 256, 0, stream>>>(h2b, W3, b3, outp);

  // default-values scorer branch (f32, wave-per-output)
  fc_wave<512, 1><<<2048, 256, 0, stream>>>(dv, W1, b1, h1d, 512);
  fc_wave<512, 1><<<1024, 256, 0, stream>>>(h1d, W2, b2, h2d, 256);
  fc_wave<256, 2><<<4, 256, 0, stream>>>(h2d, W3, b3, outp + 16384, 1);

  (void)in_sizes; (void)n_in; (void)out_size; (void)ws_size;
}

// Round 11
// 169.669 us; speedup vs baseline: 1.1213x; 1.0318x over previous
//
#include <hip/hip_runtime.h>

typedef _Float16 f16;
typedef f16  f16x8 __attribute__((ext_vector_type(8)));
typedef f16  f16x4 __attribute__((ext_vector_type(4)));
typedef __fp16 fp16x2 __attribute__((ext_vector_type(2)));
typedef float f32x4 __attribute__((ext_vector_type(4)));

__device__ __forceinline__ void gld_lds16(const f16* g, void* l) {
  __builtin_amdgcn_global_load_lds((const __attribute__((address_space(1))) void*)g,
                                   (__attribute__((address_space(3))) void*)l,
                                   16, 0, 0);
}
__device__ __forceinline__ void gld_lds16f(const float* g, void* l) {
  __builtin_amdgcn_global_load_lds((const __attribute__((address_space(1))) void*)g,
                                   (__attribute__((address_space(3))) void*)l,
                                   16, 0, 0);
}

// pack 8 f32 -> f16x8 via v_cvt_pkrtz (RTZ)
__device__ __forceinline__ f16x8 pack8(float4 a, float4 b) {
  union { f16x8 v; fp16x2 h[4]; } u;
  u.h[0] = __builtin_amdgcn_cvt_pkrtz(a.x, a.y);
  u.h[1] = __builtin_amdgcn_cvt_pkrtz(a.z, a.w);
  u.h[2] = __builtin_amdgcn_cvt_pkrtz(b.x, b.y);
  u.h[3] = __builtin_amdgcn_cvt_pkrtz(b.z, b.w);
  return u.v;
}

enum { EPI_SCORES = 0, EPI_RELU = 2, EPI_OUT = 3, EPI_BIASR = 4 };

// C[M,N] = A[M,K] @ B[N,K]^T, 128x128 tile, BK=32, 4 waves (2x2), 16x16x32 f16 MFMA.
// 4-stage LDS pipeline (2 stages prefetch-ahead), counted vmcnt with epilogue drain
// 8->4->0, raw s_barrier, swizzled LDS. 64KB LDS -> 2 blocks/CU.
// NOTE (R6): keep 128x128 with >=2 blocks/CU; fatter tiles at 1 block/CU regressed.
template<int EPI, bool XMAP>
__global__ __launch_bounds__(256)
void gemm_bt(const f16* __restrict__ A, const f16* __restrict__ B, void* __restrict__ C,
             int lda, int ldb, int ldc, int K,
             long long sA, long long sB, long long sC,
             const float* __restrict__ bias, float scale,
             float* __restrict__ mmarr, int nmm,
             const float* __restrict__ wfb, const float* __restrict__ dvv,
             int nx, int nbz)
{
  __shared__ __align__(16) f16 As[4][128][32];
  __shared__ __align__(16) f16 Bs[4][128][32];
  const int tid  = threadIdx.x;
  const int lane = tid & 63;
  const int w    = tid >> 6;
  const int wm   = w >> 1, wn = w & 1;

  const int lin = blockIdx.x;
  int bz, bj;
  if constexpr (XMAP) {
    const int xcd = lin & 7, rest = lin >> 3;
    const int grp = rest / nbz;
    bj = rest - grp * nbz;
    bz = xcd + (grp << 3);
  } else {
    bz = lin / nbz; bj = lin - bz * nbz;
  }
  const int m0 = (bj / nx) * 128, n0 = (bj % nx) * 128;
  const f16* Ab = A + (size_t)bz * sA + (size_t)m0 * lda;
  const f16* Bb = B + (size_t)bz * sB + (size_t)n0 * ldb;

  f32x4 acc[4][4] = {};
  const int nsteps = K >> 5;

#define STAGE(bufb, ks)                                                              \
  {                                                                                  \
    const int k0_ = (ks) << 5;                                                       \
    _Pragma("unroll")                                                                \
    for (int i = 0; i < 2; ++i) {                                                    \
      const int ci = i * 256 + tid;                                                  \
      const int r  = ci >> 2;                                                        \
      const int sg = (ci & 3) ^ ((r >> 1) & 3);                                      \
      gld_lds16(Ab + (size_t)r * lda + k0_ + sg * 8,                                 \
                (char*)As + (bufb) + (size_t)(i * 256 + w * 64) * 16);               \
      gld_lds16(Bb + (size_t)r * ldb + k0_ + sg * 8,                                 \
                (char*)Bs + (bufb) + (size_t)(i * 256 + w * 64) * 16);               \
    }                                                                                \
  }

  STAGE(0, 0)
  if (1 < nsteps) STAGE(8192, 1)
  if (2 < nsteps) STAGE(16384, 2)

  const int elemoff = (((lane >> 4) ^ ((lane >> 1) & 3)) << 3);

  int cur = 0;
  for (int t = 0; t < nsteps; ++t) {
    if (t + 2 < nsteps)      asm volatile("s_waitcnt vmcnt(8)" ::: "memory");
    else if (t + 1 < nsteps) asm volatile("s_waitcnt vmcnt(4)" ::: "memory");
    else                     asm volatile("s_waitcnt vmcnt(0)" ::: "memory");
    __builtin_amdgcn_s_barrier();
    __builtin_amdgcn_sched_barrier(0);
    if (t + 3 < nsteps) STAGE(((cur + 3) & 3) * 8192, t + 3)
    f16x8 af[4], bfr[4];
#pragma unroll
    for (int m = 0; m < 4; ++m)
      af[m] = *(const f16x8*)&As[cur][wm * 64 + m * 16 + (lane & 15)][elemoff];
#pragma unroll
    for (int n = 0; n < 4; ++n)
      bfr[n] = *(const f16x8*)&Bs[cur][wn * 64 + n * 16 + (lane & 15)][elemoff];
    __builtin_amdgcn_s_setprio(1);
#pragma unroll
    for (int m = 0; m < 4; ++m)
#pragma unroll
      for (int n = 0; n < 4; ++n)
        acc[m][n] = __builtin_amdgcn_mfma_f32_16x16x32_f16(af[m], bfr[n], acc[m][n], 0, 0, 0);
    __builtin_amdgcn_s_setprio(0);
    cur = (cur + 1) & 3;
  }
#undef STAGE

  const int col_l = lane & 15;
  const int row_l = (lane >> 4) << 2;

  {
    f16* Ch = (f16*)C + (size_t)bz * sC + (size_t)m0 * ldc + n0;
#pragma unroll
    for (int m = 0; m < 4; ++m)
#pragma unroll
      for (int n = 0; n < 4; ++n)
#pragma unroll
        for (int r = 0; r < 4; ++r) {
          const int rr = wm * 64 + m * 16 + row_l + r;
          const int cc = wn * 64 + n * 16 + col_l;
          float val = acc[m][n][r];
          if constexpr (EPI == EPI_RELU) { val += bias[n0 + cc]; val = fmaxf(val, 0.0f); }
          if constexpr (EPI == EPI_BIASR) val += bias[m0 + rr];
          if constexpr (EPI == EPI_OUT)
            val += wfb[bz * 1024 + m0 + rr] * dvv[bz * 512 + n0 + cc];
          Ch[(size_t)rr * ldc + cc] = (f16)val;
        }
  }
  (void)scale; (void)mmarr; (void)nmm;
}

// 256x256 scores GEMM reading q,k DIRECTLY in f32 (no pre-convert kernel).
// f32 tiles staged to LDS via global_load_lds (2-stage dbuf, 128KB), converted to f16
// during the LDS->reg fragment read (v_cvt_pkrtz). 8 loads/thread/stage -> vmcnt(8).
__global__ __launch_bounds__(512, 2)
void gemm256_scores(const float* __restrict__ A, const float* __restrict__ B, f16* __restrict__ C,
                    float scale, float* __restrict__ mmarr)
{
  __shared__ __align__(16) float AsF[2][256][32];
  __shared__ __align__(16) float BsF[2][256][32];
  __shared__ float redm[8], redn[8];
  const int tid  = threadIdx.x;
  const int lane = tid & 63;
  const int w    = tid >> 6;           // 0..7
  const int wm   = w >> 2, wn = w & 3; // 2 x 4
  const int lin  = blockIdx.x;
  const int xcd = lin & 7, rest = lin >> 3;
  const int bj  = rest & 15;
  const int bz  = xcd + ((rest >> 4) << 3);
  const int m0 = (bj >> 2) * 256, n0 = (bj & 3) * 256;
  const float* Ab = A + (size_t)bz * 524288 + (size_t)m0 * 512;
  const float* Bb = B + (size_t)bz * 524288 + (size_t)n0 * 512;

  f32x4 acc[8][4] = {};

#define STAGEF(bufb, ks)                                                             \
  {                                                                                  \
    const int k0_ = (ks) << 5;                                                       \
    _Pragma("unroll")                                                                \
    for (int i = 0; i < 4; ++i) {                                                    \
      const int ci = i * 512 + tid;                                                  \
      const int r  = ci >> 3;                                                        \
      const int sg = (ci & 7) ^ (((ci >> 4) & 3) << 1);                              \
      gld_lds16f(Ab + (size_t)r * 512 + k0_ + sg * 4,                                \
                 (char*)AsF + (bufb) + (size_t)ci * 16);                             \
      gld_lds16f(Bb + (size_t)r * 512 + k0_ + sg * 4,                                \
                 (char*)BsF + (bufb) + (size_t)ci * 16);                             \
    }                                                                                \
  }

  STAGEF(0, 0)
  STAGEF(32768, 1)

  const int fr = lane & 15;
  const int eo = (((lane >> 4) ^ ((lane >> 1) & 3)) << 3);  // f32 elements

  int cur = 0;
  for (int t = 0; t < 16; ++t) {
    if (t < 15) asm volatile("s_waitcnt vmcnt(8)" ::: "memory");
    else        asm volatile("s_waitcnt vmcnt(0)" ::: "memory");
    __builtin_amdgcn_s_barrier();
    __builtin_amdgcn_sched_barrier(0);
    const float* Ac = (const float*)((const char*)AsF + cur * 32768);
    const float* Bc = (const float*)((const char*)BsF + cur * 32768);
    f16x8 af[8], bfr[4];
#pragma unroll
    for (int m = 0; m < 8; ++m) {
      const float* p = Ac + (size_t)(wm * 128 + m * 16 + fr) * 32 + eo;
      af[m] = pack8(*(const float4*)p, *(const float4*)(p + 4));
    }
#pragma unroll
    for (int n = 0; n < 4; ++n) {
      const float* p = Bc + (size_t)(wn * 64 + n * 16 + fr) * 32 + eo;
      bfr[n] = pack8(*(const float4*)p, *(const float4*)(p + 4));
    }
    __builtin_amdgcn_s_setprio(1);
#pragma unroll
    for (int m = 0; m < 8; ++m)
#pragma unroll
      for (int n = 0; n < 4; ++n)
        acc[m][n] = __builtin_amdgcn_mfma_f32_16x16x32_f16(af[m], bfr[n], acc[m][n], 0, 0, 0);
    __builtin_amdgcn_s_setprio(0);
    __builtin_amdgcn_s_barrier();       // all waves done reading buf[cur]
    if (t + 2 < 16) STAGEF(cur * 32768, t + 2)
    cur ^= 1;
  }
#undef STAGEF

  const int col_l = lane & 15;
  const int row_l = (lane >> 4) << 2;
  f16* Ch = C + (size_t)bz * 1048576 + (size_t)m0 * 1024 + n0;
  float lmax = -3.402823466e38f, lmin = 3.402823466e38f;
#pragma unroll
  for (int m = 0; m < 8; ++m)
#pragma unroll
    for (int n = 0; n < 4; ++n)
#pragma unroll
      for (int r = 0; r < 4; ++r) {
        float val = acc[m][n][r] * scale;
        lmax = fmaxf(lmax, val); lmin = fminf(lmin, val);
        Ch[(size_t)(wm * 128 + m * 16 + row_l + r) * 1024 + (wn * 64 + n * 16 + col_l)] = (f16)val;
      }
#pragma unroll
  for (int off = 32; off >= 1; off >>= 1) {
    lmax = fmaxf(lmax, __shfl_xor(lmax, off));
    lmin = fminf(lmin, __shfl_xor(lmin, off));
  }
  if (lane == 0) { redm[w] = lmax; redn[w] = lmin; }
  __syncthreads();
  if (tid == 0) {
    float gm = redm[0], gn = redn[0];
#pragma unroll
    for (int i = 1; i < 8; ++i) { gm = fmaxf(gm, redm[i]); gn = fminf(gn, redn[i]); }
    mmarr[lin] = gm; mmarr[256 + lin] = gn;
  }
}

// reduce per-block max/min -> fb scalar; also counts nonzero mask bytes (dtype sniff)
__global__ __launch_bounds__(256)
void reduce_mm(const float* __restrict__ mmarr, int n,
               const float* __restrict__ fallback, float* __restrict__ fbv,
               const unsigned char* __restrict__ mask, unsigned* __restrict__ mm)
{
  __shared__ float rm[4], rn[4];
  __shared__ int redc[256];
  const int lane = threadIdx.x & 63, w = threadIdx.x >> 6;
  float mx = -3.402823466e38f, mn = 3.402823466e38f;
  for (int i = threadIdx.x; i < n; i += 256) {
    mx = fmaxf(mx, mmarr[i]);
    mn = fminf(mn, mmarr[n + i]);
  }
#pragma unroll
  for (int off = 32; off >= 1; off >>= 1) {
    mx = fmaxf(mx, __shfl_xor(mx, off));
    mn = fminf(mn, __shfl_xor(mn, off));
  }
  if (lane == 0) { rm[w] = mx; rn[w] = mn; }
  int c = 0;
  for (int i = threadIdx.x; i < 16384; i += 256) c += (mask[i] != 0) ? 1 : 0;
  redc[threadIdx.x] = c;
  __syncthreads();
  for (int s = 128; s > 0; s >>= 1) {
    if (threadIdx.x < s) redc[threadIdx.x] += redc[threadIdx.x + s];
    __syncthreads();
  }
  if (threadIdx.x == 0) {
    float gmax = fmaxf(fmaxf(rm[0], rm[1]), fmaxf(rm[2], rm[3]));
    float gmin = fminf(fminf(rn[0], rn[1]), fminf(rn[2], rn[3]));
    fbv[0] = 0.99f * fallback[0] + 0.005f * (gmax + gmin);
    mm[0] = (unsigned)redc[0];
  }
}

// merged front work: [0,2048) conv_v; [2048,2688) weight converts; [2688,4736) dv FC
__global__ __launch_bounds__(256)
void front_k(const float* __restrict__ v, f16* __restrict__ v16,
             const float* __restrict__ wv, const float* __restrict__ w1,
             const float* __restrict__ w2,
             f16* __restrict__ owv, f16* __restrict__ ow1, f16* __restrict__ ow2,
             const float* __restrict__ uq, const float* __restrict__ Wf,
             const float* __restrict__ bfv, float* __restrict__ dv)
{
  const int blk = blockIdx.x;
  if (blk < 2048) {
    const int i = blk * 256 + threadIdx.x;
#pragma unroll
    for (int it = 0; it < 4; ++it) {
      const size_t j = (size_t)i + (size_t)it * 524288;
      float4 x = *(const float4*)(v + j * 4);
      f16x4 o = { (f16)x.x, (f16)x.y, (f16)x.z, (f16)x.w };
      *(f16x4*)(v16 + j * 4) = o;
    }
  } else if (blk < 2688) {
    int i = (blk - 2048) * 256 + threadIdx.x;   // 0..163839
    const float* src; f16* dst; int j;
    if (i < 65536)       { src = wv; dst = owv; j = i; }
    else if (i < 131072) { src = w1; dst = ow1; j = i - 65536; }
    else                 { src = w2; dst = ow2; j = i - 131072; }
    float4 x = *(const float4*)(src + (size_t)j * 4);
    f16x4 o = { (f16)x.x, (f16)x.y, (f16)x.z, (f16)x.w };
    *(f16x4*)(dst + (size_t)j * 4) = o;
  } else {
    const int gw   = ((blk - 2688) * 256 + threadIdx.x) >> 6;  // 0..8191
    const int lane = threadIdx.x & 63;
    const int b = gw >> 9, j = gw & 511;
    const float* x  = uq + (size_t)b * 512;
    const float* wr = Wf + (size_t)j * 512;
    const int o = lane * 8;
    float4 x0 = *(const float4*)(x + o),  x1 = *(const float4*)(x + o + 4);
    float4 w0 = *(const float4*)(wr + o), w1v = *(const float4*)(wr + o + 4);
    float s = x0.x*w0.x + x0.y*w0.y + x0.z*w0.z + x0.w*w0.w
            + x1.x*w1v.x + x1.y*w1v.y + x1.z*w1v.z + x1.w*w1v.w;
#pragma unroll
    for (int off = 32; off >= 1; off >>= 1) s += __shfl_xor(s, off);
    if (lane == 0) dv[gw] = s + bfv[j];
  }
}

__global__ __launch_bounds__(256)
void softmax_rows(const f16* __restrict__ scores, const void* __restrict__ maskp,
                  const float* __restrict__ fbv, const unsigned* __restrict__ mm,
                  f16* __restrict__ Wt, float* __restrict__ wfb)
{
  __shared__ float red[8];
  const int row  = blockIdx.x;
  const int b    = row >> 10;
  const int tid  = threadIdx.x;
  const int lane = tid & 63, w = tid >> 6;
  const float fb = fbv[0];
  const unsigned mode = (mm[0] > 5000u) ? 1u : 0u;
  const f16* s = scores + (size_t)row * 1024;
  const int k0 = tid * 4;
  f16x4 sv = *(const f16x4*)(s + k0);
  float x[4];
  if (mode) {
    const unsigned char* m8 = (const unsigned char*)maskp + b * 1024 + k0;
    x[0] = m8[0] ? -1e9f : (float)sv[0];  x[1] = m8[1] ? -1e9f : (float)sv[1];
    x[2] = m8[2] ? -1e9f : (float)sv[2];  x[3] = m8[3] ? -1e9f : (float)sv[3];
  } else {
    const int* mi = (const int*)maskp + b * 1024 + k0;
    x[0] = mi[0] ? -1e9f : (float)sv[0];  x[1] = mi[1] ? -1e9f : (float)sv[1];
    x[2] = mi[2] ? -1e9f : (float)sv[2];  x[3] = mi[3] ? -1e9f : (float)sv[3];
  }
  float mx = fmaxf(fmaxf(x[0], x[1]), fmaxf(x[2], x[3]));
#pragma unroll
  for (int off = 32; off >= 1; off >>= 1) mx = fmaxf(mx, __shfl_xor(mx, off));
  if (lane == 0) red[w] = mx;
  __syncthreads();
  mx = fmaxf(fmaxf(fmaxf(red[0], red[1]), fmaxf(red[2], red[3])), fb);
  float e0 = expf(x[0] - mx), e1 = expf(x[1] - mx), e2 = expf(x[2] - mx), e3 = expf(x[3] - mx);
  float sum = (e0 + e1) + (e2 + e3);
#pragma unroll
  for (int off = 32; off >= 1; off >>= 1) sum += __shfl_xor(sum, off);
  if (lane == 0) red[4 + w] = sum;
  __syncthreads();
  float efb = expf(fb - mx);
  float Z = ((red[4] + red[5]) + (red[6] + red[7])) + efb;
  float inv = 1.0f / Z;
  f16x4 o = { (f16)(e0 * inv), (f16)(e1 * inv), (f16)(e2 * inv), (f16)(e3 * inv) };
  *(f16x4*)&Wt[(size_t)row * 1024 + k0] = o;
  if (tid == 0) wfb[row] = efb * inv;
}

// wave-per-output FC: Y[b,j] = act(X[b,:] . W[j,:] + bias[j])
template<int IN, int ACT>
__global__ __launch_bounds__(256)
void fc_wave(const float* __restrict__ X, const float* __restrict__ W,
             const float* __restrict__ bias, float* __restrict__ Y, int OutN)
{
  const int gw   = (blockIdx.x * 256 + threadIdx.x) >> 6;
  const int lane = threadIdx.x & 63;
  const int b = gw / OutN, j = gw - b * OutN;
  const float* x  = X + (size_t)b * IN;
  const float* wr = W + (size_t)j * IN;
  float s = 0.f;
  if constexpr (IN == 512) {
    const int o = lane * 8;
    float4 x0 = *(const float4*)(x + o),  x1 = *(const float4*)(x + o + 4);
    float4 w0 = *(const float4*)(wr + o), w1 = *(const float4*)(wr + o + 4);
    s = x0.x*w0.x + x0.y*w0.y + x0.z*w0.z + x0.w*w0.w
      + x1.x*w1.x + x1.y*w1.y + x1.z*w1.z + x1.w*w1.w;
  } else {
    const int o = lane * 4;
    float4 x0 = *(const float4*)(x + o);
    float4 w0 = *(const float4*)(wr + o);
    s = x0.x*w0.x + x0.y*w0.y + x0.z*w0.z + x0.w*w0.w;
  }
#pragma unroll
  for (int off = 32; off >= 1; off >>= 1) s += __shfl_xor(s, off);
  if (lane == 0) {
    float val = s + bias[ACT == 2 ? 0 : j];
    if constexpr (ACT == 1) val = fmaxf(val, 0.f);
    if constexpr (ACT == 2) val = tanhf(val);
    Y[gw] = val;
  }
}

__global__ __launch_bounds__(256)
void y_kernel(const f16* __restrict__ h2, const float* __restrict__ W3,
              const float* __restrict__ b3, float* __restrict__ outp)
{
  int row = blockIdx.x * 16 + (threadIdx.x >> 4);
  int l   = threadIdx.x & 15;
  const f16* h = h2 + (size_t)row * 256 + l * 16;
  float s = 0.f;
#pragma unroll
  for (int j = 0; j < 16; ++j) s += (float)h[j] * W3[l * 16 + j];
#pragma unroll
  for (int off = 1; off < 16; off <<= 1) s += __shfl_xor(s, off);
  if (l == 0) outp[row] = tanhf(s + b3[0]);
}

extern "C" void kernel_launch(void* const* d_in, const int* in_sizes, int n_in,
                              void* d_out, int out_size, void* d_ws, size_t ws_size,
                              hipStream_t stream) {
  const float* uq       = (const float*)d_in[0];
  const float* q        = (const float*)d_in[1];
  const float* kk       = (const float*)d_in[2];
  const float* v        = (const float*)d_in[3];
  const void*  mask     = d_in[4];
  const float* fallback = (const float*)d_in[5];
  const float* Wv = (const float*)d_in[6];
  const float* bv = (const float*)d_in[7];
  const float* Wf = (const float*)d_in[8];
  const float* bf = (const float*)d_in[9];
  const float* W1 = (const float*)d_in[10];
  const float* b1 = (const float*)d_in[11];
  const float* W2 = (const float*)d_in[12];
  const float* b2 = (const float*)d_in[13];
  const float* W3 = (const float*)d_in[14];
  const float* b3 = (const float*)d_in[15];
  float* outp = (float*)d_out;

  char* ws = (char*)d_ws;
  const size_t MB = 1ull << 20;
  f16*  scores = (f16*)ws;
  f16*  h1b  = (f16*)ws;
  f16*  h2b  = (f16*)(ws + 16 * MB);
  f16*  vpt  = (f16*)(ws + 32 * MB);
  f16*  outb = (f16*)(ws + 48 * MB);
  f16*  wts  = (f16*)(ws + 64 * MB);
  f16*  v16  = (f16*)(ws + 96 * MB);
  char* cst  = ws + 112 * MB;
  f16*  Wv16 = (f16*)(cst);
  f16*  W116 = (f16*)(cst + 512 * 1024);
  f16*  W216 = (f16*)(cst + 1024 * 1024);
  float* dv   = (float*)(cst + 1280 * 1024);
  float* wfb  = (float*)(cst + 1312 * 1024);
  float* h1d  = (float*)(cst + 1376 * 1024);
  float* h2d  = (float*)(cst + 1408 * 1024);
  unsigned* mm = (unsigned*)(cst + 1424 * 1024);
  float* fbv   = (float*)(cst + 1428 * 1024);
  float* mmarr = (float*)(cst + 1432 * 1024);   // 2 * 256 floats

  // conv_v + weight converts + dv FC in one dispatch
  front_k<<<4736, 256, 0, stream>>>(v, v16, Wv, W1, W2, Wv16, W116, W216,
                                    uq, Wf, bf, dv);

  // scores = q @ k^T / sqrt(512) -> f16, q/k read as f32 (256x256 tiles, 8 waves)
  gemm256_scores<<<256, 512, 0, stream>>>(q, kk, scores, 0.04419417382415922f, mmarr);

  reduce_mm<<<1, 256, 0, stream>>>(mmarr, 256, fallback, fbv,
                                   (const unsigned char*)mask, mm);

  softmax_rows<<<16384, 256, 0, stream>>>(scores, mask, fbv, mm, wts, wfb);

  // vpt[d][k] = sum_e Wv[d][e] v[k][e] + bv[d]
  gemm_bt<EPI_BIASR, true><<<512, 256, 0, stream>>>(
      Wv16, v16, vpt, 512, 512, 1024, 512,
      0LL, 524288LL, 524288LL,
      bv, 1.f, nullptr, 0, nullptr, nullptr, 8, 32);

  // out = weights @ vp + wfb*dv
  gemm_bt<EPI_OUT, true><<<512, 256, 0, stream>>>(
      wts, vpt, outb, 1024, 1024, 512, 1024,
      1048576LL, 524288LL, 524288LL,
      nullptr, 1.f, nullptr, 0, wfb, dv, 4, 32);

  // h1 = relu(out @ W1^T + b1)
  gemm_bt<EPI_RELU, false><<<512, 256, 0, stream>>>(
      outb, W116, h1b, 512, 512, 512, 512, 0LL, 0LL, 0LL,
      b1, 1.f, nullptr, 0, nullptr, nullptr, 4, 512);

  // h2 = relu(h1 @ W2^T + b2)
  gemm_bt<EPI_RELU, false><<<256, 256, 0, stream>>>(
      h1b, W216, h2b, 512, 512, 256, 512, 0LL, 0LL, 0LL,
      b2, 1.f, nullptr, 0, nullptr, nullptr, 2, 256);

  y_kernel<<<1024, 256, 0, stream>>>(h2b, W3, b3, outp);

  // default-values scorer branch (f32, wave-per-output)
  fc_wave<512, 1><<<2048, 256, 0, stream>>>(dv, W1, b1, h1d, 512);
  fc_wave<512, 1><<<1024, 256, 0, stream>>>(h1d, W2, b2, h2d, 256);
  fc_wave<256, 2><<<4, 256, 0, stream>>>(h2d, W3, b3, outp + 16384, 1);

  (void)in_sizes; (void)n_in; (void)out_size; (void)ws_size;
}

// Round 12
// 169.200 us; speedup vs baseline: 1.1244x; 1.0028x over previous
//
#include <hip/hip_runtime.h>

typedef _Float16 f16;
typedef f16  f16x8 __attribute__((ext_vector_type(8)));
typedef f16  f16x4 __attribute__((ext_vector_type(4)));
typedef __fp16 fp16x2 __attribute__((ext_vector_type(2)));
typedef float f32x4 __attribute__((ext_vector_type(4)));

__device__ __forceinline__ void gld_lds16(const f16* g, void* l) {
  __builtin_amdgcn_global_load_lds((const __attribute__((address_space(1))) void*)g,
                                   (__attribute__((address_space(3))) void*)l,
                                   16, 0, 0);
}
__device__ __forceinline__ void gld_lds16f(const float* g, void* l) {
  __builtin_amdgcn_global_load_lds((const __attribute__((address_space(1))) void*)g,
                                   (__attribute__((address_space(3))) void*)l,
                                   16, 0, 0);
}

// pack 8 f32 -> f16x8 via v_cvt_pkrtz (RTZ)
__device__ __forceinline__ f16x8 pack8(float4 a, float4 b) {
  union { f16x8 v; fp16x2 h[4]; } u;
  u.h[0] = __builtin_amdgcn_cvt_pkrtz(a.x, a.y);
  u.h[1] = __builtin_amdgcn_cvt_pkrtz(a.z, a.w);
  u.h[2] = __builtin_amdgcn_cvt_pkrtz(b.x, b.y);
  u.h[3] = __builtin_amdgcn_cvt_pkrtz(b.z, b.w);
  return u.v;
}

enum { EPI_SCORES = 0, EPI_RELU = 2, EPI_OUT = 3, EPI_BIASR = 4 };

// C[M,N] = A[M,K] @ B[N,K]^T, 128x128 tile, BK=32, 4 waves (2x2), 16x16x32 f16 MFMA.
// 4-stage LDS pipeline (2 stages prefetch-ahead), counted vmcnt with epilogue drain
// 8->4->0, raw s_barrier, swizzled LDS. 64KB LDS -> 2 blocks/CU.
// NOTE (R6): keep 128x128 with >=2 blocks/CU; fatter tiles at 1 block/CU regressed.
template<int EPI, bool XMAP>
__global__ __launch_bounds__(256)
void gemm_bt(const f16* __restrict__ A, const f16* __restrict__ B, void* __restrict__ C,
             int lda, int ldb, int ldc, int K,
             long long sA, long long sB, long long sC,
             const float* __restrict__ bias, float scale,
             float* __restrict__ mmarr, int nmm,
             const float* __restrict__ wfb, const float* __restrict__ dvv,
             int nx, int nbz)
{
  __shared__ __align__(16) f16 As[4][128][32];
  __shared__ __align__(16) f16 Bs[4][128][32];
  const int tid  = threadIdx.x;
  const int lane = tid & 63;
  const int w    = tid >> 6;
  const int wm   = w >> 1, wn = w & 1;

  const int lin = blockIdx.x;
  int bz, bj;
  if constexpr (XMAP) {
    const int xcd = lin & 7, rest = lin >> 3;
    const int grp = rest / nbz;
    bj = rest - grp * nbz;
    bz = xcd + (grp << 3);
  } else {
    bz = lin / nbz; bj = lin - bz * nbz;
  }
  const int m0 = (bj / nx) * 128, n0 = (bj % nx) * 128;
  const f16* Ab = A + (size_t)bz * sA + (size_t)m0 * lda;
  const f16* Bb = B + (size_t)bz * sB + (size_t)n0 * ldb;

  f32x4 acc[4][4] = {};
  const int nsteps = K >> 5;

#define STAGE(bufb, ks)                                                              \
  {                                                                                  \
    const int k0_ = (ks) << 5;                                                       \
    _Pragma("unroll")                                                                \
    for (int i = 0; i < 2; ++i) {                                                    \
      const int ci = i * 256 + tid;                                                  \
      const int r  = ci >> 2;                                                        \
      const int sg = (ci & 3) ^ ((r >> 1) & 3);                                      \
      gld_lds16(Ab + (size_t)r * lda + k0_ + sg * 8,                                 \
                (char*)As + (bufb) + (size_t)(i * 256 + w * 64) * 16);               \
      gld_lds16(Bb + (size_t)r * ldb + k0_ + sg * 8,                                 \
                (char*)Bs + (bufb) + (size_t)(i * 256 + w * 64) * 16);               \
    }                                                                                \
  }

  STAGE(0, 0)
  if (1 < nsteps) STAGE(8192, 1)
  if (2 < nsteps) STAGE(16384, 2)

  const int elemoff = (((lane >> 4) ^ ((lane >> 1) & 3)) << 3);

  int cur = 0;
  for (int t = 0; t < nsteps; ++t) {
    if (t + 2 < nsteps)      asm volatile("s_waitcnt vmcnt(8)" ::: "memory");
    else if (t + 1 < nsteps) asm volatile("s_waitcnt vmcnt(4)" ::: "memory");
    else                     asm volatile("s_waitcnt vmcnt(0)" ::: "memory");
    __builtin_amdgcn_s_barrier();
    __builtin_amdgcn_sched_barrier(0);
    if (t + 3 < nsteps) STAGE(((cur + 3) & 3) * 8192, t + 3)
    f16x8 af[4], bfr[4];
#pragma unroll
    for (int m = 0; m < 4; ++m)
      af[m] = *(const f16x8*)&As[cur][wm * 64 + m * 16 + (lane & 15)][elemoff];
#pragma unroll
    for (int n = 0; n < 4; ++n)
      bfr[n] = *(const f16x8*)&Bs[cur][wn * 64 + n * 16 + (lane & 15)][elemoff];
    __builtin_amdgcn_s_setprio(1);
#pragma unroll
    for (int m = 0; m < 4; ++m)
#pragma unroll
      for (int n = 0; n < 4; ++n)
        acc[m][n] = __builtin_amdgcn_mfma_f32_16x16x32_f16(af[m], bfr[n], acc[m][n], 0, 0, 0);
    __builtin_amdgcn_s_setprio(0);
    cur = (cur + 1) & 3;
  }
#undef STAGE

  const int col_l = lane & 15;
  const int row_l = (lane >> 4) << 2;

  {
    f16* Ch = (f16*)C + (size_t)bz * sC + (size_t)m0 * ldc + n0;
#pragma unroll
    for (int m = 0; m < 4; ++m)
#pragma unroll
      for (int n = 0; n < 4; ++n)
#pragma unroll
        for (int r = 0; r < 4; ++r) {
          const int rr = wm * 64 + m * 16 + row_l + r;
          const int cc = wn * 64 + n * 16 + col_l;
          float val = acc[m][n][r];
          if constexpr (EPI == EPI_RELU) { val += bias[n0 + cc]; val = fmaxf(val, 0.0f); }
          if constexpr (EPI == EPI_BIASR) val += bias[m0 + rr];
          if constexpr (EPI == EPI_OUT)
            val += wfb[bz * 1024 + m0 + rr] * dvv[bz * 512 + n0 + cc];
          Ch[(size_t)rr * ldc + cc] = (f16)val;
        }
  }
  (void)scale; (void)mmarr; (void)nmm;
}

// 256x256 scores GEMM reading q,k DIRECTLY in f32 (no pre-convert kernel).
// f32 tiles staged to LDS via global_load_lds (2-stage dbuf, 128KB), converted to f16
// during the LDS->reg fragment read (v_cvt_pkrtz). 8 loads/thread/stage -> vmcnt(8).
// Full 3-bit chunk swizzle (R12): physical_chunk = logical ^ (row&7). Write side:
// sg = (ci&7)^((ci>>3)&7); read side: two independent b128 at px=(2j)^(lane&7), py=px^1
// (row&7 == lane&7 for all fragment rows). 8 lanes per slot-position = 2/bank = free.
__global__ __launch_bounds__(512, 2)
void gemm256_scores(const float* __restrict__ A, const float* __restrict__ B, f16* __restrict__ C,
                    float scale, float* __restrict__ mmarr)
{
  __shared__ __align__(16) float AsF[2][256][32];
  __shared__ __align__(16) float BsF[2][256][32];
  __shared__ float redm[8], redn[8];
  const int tid  = threadIdx.x;
  const int lane = tid & 63;
  const int w    = tid >> 6;           // 0..7
  const int wm   = w >> 2, wn = w & 3; // 2 x 4
  const int lin  = blockIdx.x;
  const int xcd = lin & 7, rest = lin >> 3;
  const int bj  = rest & 15;
  const int bz  = xcd + ((rest >> 4) << 3);
  const int m0 = (bj >> 2) * 256, n0 = (bj & 3) * 256;
  const float* Ab = A + (size_t)bz * 524288 + (size_t)m0 * 512;
  const float* Bb = B + (size_t)bz * 524288 + (size_t)n0 * 512;

  f32x4 acc[8][4] = {};

#define STAGEF(bufb, ks)                                                             \
  {                                                                                  \
    const int k0_ = (ks) << 5;                                                       \
    _Pragma("unroll")                                                                \
    for (int i = 0; i < 4; ++i) {                                                    \
      const int ci = i * 512 + tid;                                                  \
      const int r  = ci >> 3;                                                        \
      const int sg = (ci & 7) ^ (r & 7);                                             \
      gld_lds16f(Ab + (size_t)r * 512 + k0_ + sg * 4,                                \
                 (char*)AsF + (bufb) + (size_t)ci * 16);                             \
      gld_lds16f(Bb + (size_t)r * 512 + k0_ + sg * 4,                                \
                 (char*)BsF + (bufb) + (size_t)ci * 16);                             \
    }                                                                                \
  }

  STAGEF(0, 0)
  STAGEF(32768, 1)

  const int fr = lane & 15;
  const int px = ((lane >> 4) << 1) ^ (lane & 7);   // physical chunk of logical 2j
  const int py = px ^ 1;                            // physical chunk of logical 2j+1
  const int eo0 = px << 2, eo1 = py << 2;           // f32 element offsets

  int cur = 0;
  for (int t = 0; t < 16; ++t) {
    if (t < 15) asm volatile("s_waitcnt vmcnt(8)" ::: "memory");
    else        asm volatile("s_waitcnt vmcnt(0)" ::: "memory");
    __builtin_amdgcn_s_barrier();
    __builtin_amdgcn_sched_barrier(0);
    const float* Ac = (const float*)((const char*)AsF + cur * 32768);
    const float* Bc = (const float*)((const char*)BsF + cur * 32768);
    f16x8 af[8], bfr[4];
#pragma unroll
    for (int m = 0; m < 8; ++m) {
      const float* p = Ac + (size_t)(wm * 128 + m * 16 + fr) * 32;
      af[m] = pack8(*(const float4*)(p + eo0), *(const float4*)(p + eo1));
    }
#pragma unroll
    for (int n = 0; n < 4; ++n) {
      const float* p = Bc + (size_t)(wn * 64 + n * 16 + fr) * 32;
      bfr[n] = pack8(*(const float4*)(p + eo0), *(const float4*)(p + eo1));
    }
    __builtin_amdgcn_s_setprio(1);
#pragma unroll
    for (int m = 0; m < 8; ++m)
#pragma unroll
      for (int n = 0; n < 4; ++n)
        acc[m][n] = __builtin_amdgcn_mfma_f32_16x16x32_f16(af[m], bfr[n], acc[m][n], 0, 0, 0);
    __builtin_amdgcn_s_setprio(0);
    __builtin_amdgcn_s_barrier();       // all waves done reading buf[cur]
    if (t + 2 < 16) STAGEF(cur * 32768, t + 2)
    cur ^= 1;
  }
#undef STAGEF

  const int col_l = lane & 15;
  const int row_l = (lane >> 4) << 2;
  f16* Ch = C + (size_t)bz * 1048576 + (size_t)m0 * 1024 + n0;
  float lmax = -3.402823466e38f, lmin = 3.402823466e38f;
#pragma unroll
  for (int m = 0; m < 8; ++m)
#pragma unroll
    for (int n = 0; n < 4; ++n)
#pragma unroll
      for (int r = 0; r < 4; ++r) {
        float val = acc[m][n][r] * scale;
        lmax = fmaxf(lmax, val); lmin = fminf(lmin, val);
        Ch[(size_t)(wm * 128 + m * 16 + row_l + r) * 1024 + (wn * 64 + n * 16 + col_l)] = (f16)val;
      }
#pragma unroll
  for (int off = 32; off >= 1; off >>= 1) {
    lmax = fmaxf(lmax, __shfl_xor(lmax, off));
    lmin = fminf(lmin, __shfl_xor(lmin, off));
  }
  if (lane == 0) { redm[w] = lmax; redn[w] = lmin; }
  __syncthreads();
  if (tid == 0) {
    float gm = redm[0], gn = redn[0];
#pragma unroll
    for (int i = 1; i < 8; ++i) { gm = fmaxf(gm, redm[i]); gn = fminf(gn, redn[i]); }
    mmarr[lin] = gm; mmarr[256 + lin] = gn;
  }
}

// reduce per-block max/min -> fb scalar; also counts nonzero mask bytes (dtype sniff)
__global__ __launch_bounds__(256)
void reduce_mm(const float* __restrict__ mmarr, int n,
               const float* __restrict__ fallback, float* __restrict__ fbv,
               const unsigned char* __restrict__ mask, unsigned* __restrict__ mm)
{
  __shared__ float rm[4], rn[4];
  __shared__ int redc[256];
  const int lane = threadIdx.x & 63, w = threadIdx.x >> 6;
  float mx = -3.402823466e38f, mn = 3.402823466e38f;
  for (int i = threadIdx.x; i < n; i += 256) {
    mx = fmaxf(mx, mmarr[i]);
    mn = fminf(mn, mmarr[n + i]);
  }
#pragma unroll
  for (int off = 32; off >= 1; off >>= 1) {
    mx = fmaxf(mx, __shfl_xor(mx, off));
    mn = fminf(mn, __shfl_xor(mn, off));
  }
  if (lane == 0) { rm[w] = mx; rn[w] = mn; }
  int c = 0;
  for (int i = threadIdx.x; i < 16384; i += 256) c += (mask[i] != 0) ? 1 : 0;
  redc[threadIdx.x] = c;
  __syncthreads();
  for (int s = 128; s > 0; s >>= 1) {
    if (threadIdx.x < s) redc[threadIdx.x] += redc[threadIdx.x + s];
    __syncthreads();
  }
  if (threadIdx.x == 0) {
    float gmax = fmaxf(fmaxf(rm[0], rm[1]), fmaxf(rm[2], rm[3]));
    float gmin = fminf(fminf(rn[0], rn[1]), fminf(rn[2], rn[3]));
    fbv[0] = 0.99f * fallback[0] + 0.005f * (gmax + gmin);
    mm[0] = (unsigned)redc[0];
  }
}

// merged front work: [0,2048) conv_v; [2048,2688) weight converts; [2688,4736) dv FC
__global__ __launch_bounds__(256)
void front_k(const float* __restrict__ v, f16* __restrict__ v16,
             const float* __restrict__ wv, const float* __restrict__ w1,
             const float* __restrict__ w2,
             f16* __restrict__ owv, f16* __restrict__ ow1, f16* __restrict__ ow2,
             const float* __restrict__ uq, const float* __restrict__ Wf,
             const float* __restrict__ bfv, float* __restrict__ dv)
{
  const int blk = blockIdx.x;
  if (blk < 2048) {
    const int i = blk * 256 + threadIdx.x;
#pragma unroll
    for (int it = 0; it < 4; ++it) {
      const size_t j = (size_t)i + (size_t)it * 524288;
      float4 x = *(const float4*)(v + j * 4);
      f16x4 o = { (f16)x.x, (f16)x.y, (f16)x.z, (f16)x.w };
      *(f16x4*)(v16 + j * 4) = o;
    }
  } else if (blk < 2688) {
    int i = (blk - 2048) * 256 + threadIdx.x;   // 0..163839
    const float* src; f16* dst; int j;
    if (i < 65536)       { src = wv; dst = owv; j = i; }
    else if (i < 131072) { src = w1; dst = ow1; j = i - 65536; }
    else                 { src = w2; dst = ow2; j = i - 131072; }
    float4 x = *(const float4*)(src + (size_t)j * 4);
    f16x4 o = { (f16)x.x, (f16)x.y, (f16)x.z, (f16)x.w };
    *(f16x4*)(dst + (size_t)j * 4) = o;
  } else {
    const int gw   = ((blk - 2688) * 256 + threadIdx.x) >> 6;  // 0..8191
    const int lane = threadIdx.x & 63;
    const int b = gw >> 9, j = gw & 511;
    const float* x  = uq + (size_t)b * 512;
    const float* wr = Wf + (size_t)j * 512;
    const int o = lane * 8;
    float4 x0 = *(const float4*)(x + o),  x1 = *(const float4*)(x + o + 4);
    float4 w0 = *(const float4*)(wr + o), w1v = *(const float4*)(wr + o + 4);
    float s = x0.x*w0.x + x0.y*w0.y + x0.z*w0.z + x0.w*w0.w
            + x1.x*w1v.x + x1.y*w1v.y + x1.z*w1v.z + x1.w*w1v.w;
#pragma unroll
    for (int off = 32; off >= 1; off >>= 1) s += __shfl_xor(s, off);
    if (lane == 0) dv[gw] = s + bfv[j];
  }
}

__global__ __launch_bounds__(256)
void softmax_rows(const f16* __restrict__ scores, const void* __restrict__ maskp,
                  const float* __restrict__ fbv, const unsigned* __restrict__ mm,
                  f16* __restrict__ Wt, float* __restrict__ wfb)
{
  __shared__ float red[8];
  const int row  = blockIdx.x;
  const int b    = row >> 10;
  const int tid  = threadIdx.x;
  const int lane = tid & 63, w = tid >> 6;
  const float fb = fbv[0];
  const unsigned mode = (mm[0] > 5000u) ? 1u : 0u;
  const f16* s = scores + (size_t)row * 1024;
  const int k0 = tid * 4;
  f16x4 sv = *(const f16x4*)(s + k0);
  float x[4];
  if (mode) {
    const unsigned char* m8 = (const unsigned char*)maskp + b * 1024 + k0;
    x[0] = m8[0] ? -1e9f : (float)sv[0];  x[1] = m8[1] ? -1e9f : (float)sv[1];
    x[2] = m8[2] ? -1e9f : (float)sv[2];  x[3] = m8[3] ? -1e9f : (float)sv[3];
  } else {
    const int* mi = (const int*)maskp + b * 1024 + k0;
    x[0] = mi[0] ? -1e9f : (float)sv[0];  x[1] = mi[1] ? -1e9f : (float)sv[1];
    x[2] = mi[2] ? -1e9f : (float)sv[2];  x[3] = mi[3] ? -1e9f : (float)sv[3];
  }
  float mx = fmaxf(fmaxf(x[0], x[1]), fmaxf(x[2], x[3]));
#pragma unroll
  for (int off = 32; off >= 1; off >>= 1) mx = fmaxf(mx, __shfl_xor(mx, off));
  if (lane == 0) red[w] = mx;
  __syncthreads();
  mx = fmaxf(fmaxf(fmaxf(red[0], red[1]), fmaxf(red[2], red[3])), fb);
  float e0 = expf(x[0] - mx), e1 = expf(x[1] - mx), e2 = expf(x[2] - mx), e3 = expf(x[3] - mx);
  float sum = (e0 + e1) + (e2 + e3);
#pragma unroll
  for (int off = 32; off >= 1; off >>= 1) sum += __shfl_xor(sum, off);
  if (lane == 0) red[4 + w] = sum;
  __syncthreads();
  float efb = expf(fb - mx);
  float Z = ((red[4] + red[5]) + (red[6] + red[7])) + efb;
  float inv = 1.0f / Z;
  f16x4 o = { (f16)(e0 * inv), (f16)(e1 * inv), (f16)(e2 * inv), (f16)(e3 * inv) };
  *(f16x4*)&Wt[(size_t)row * 1024 + k0] = o;
  if (tid == 0) wfb[row] = efb * inv;
}

// wave-per-output FC: Y[b,j] = act(X[b,:] . W[j,:] + bias[j])
template<int IN, int ACT>
__global__ __launch_bounds__(256)
void fc_wave(const float* __restrict__ X, const float* __restrict__ W,
             const float* __restrict__ bias, float* __restrict__ Y, int OutN)
{
  const int gw   = (blockIdx.x * 256 + threadIdx.x) >> 6;
  const int lane = threadIdx.x & 63;
  const int b = gw / OutN, j = gw - b * OutN;
  const float* x  = X + (size_t)b * IN;
  const float* wr = W + (size_t)j * IN;
  float s = 0.f;
  if constexpr (IN == 512) {
    const int o = lane * 8;
    float4 x0 = *(const float4*)(x + o),  x1 = *(const float4*)(x + o + 4);
    float4 w0 = *(const float4*)(wr + o), w1 = *(const float4*)(wr + o + 4);
    s = x0.x*w0.x + x0.y*w0.y + x0.z*w0.z + x0.w*w0.w
      + x1.x*w1.x + x1.y*w1.y + x1.z*w1.z + x1.w*w1.w;
  } else {
    const int o = lane * 4;
    float4 x0 = *(const float4*)(x + o);
    float4 w0 = *(const float4*)(wr + o);
    s = x0.x*w0.x + x0.y*w0.y + x0.z*w0.z + x0.w*w0.w;
  }
#pragma unroll
  for (int off = 32; off >= 1; off >>= 1) s += __shfl_xor(s, off);
  if (lane == 0) {
    float val = s + bias[ACT == 2 ? 0 : j];
    if constexpr (ACT == 1) val = fmaxf(val, 0.f);
    if constexpr (ACT == 2) val = tanhf(val);
    Y[gw] = val;
  }
}

__global__ __launch_bounds__(256)
void y_kernel(const f16* __restrict__ h2, const float* __restrict__ W3,
              const float* __restrict__ b3, float* __restrict__ outp)
{
  int row = blockIdx.x * 16 + (threadIdx.x >> 4);
  int l   = threadIdx.x & 15;
  const f16* h = h2 + (size_t)row * 256 + l * 16;
  float s = 0.f;
#pragma unroll
  for (int j = 0; j < 16; ++j) s += (float)h[j] * W3[l * 16 + j];
#pragma unroll
  for (int off = 1; off < 16; off <<= 1) s += __shfl_xor(s, off);
  if (l == 0) outp[row] = tanhf(s + b3[0]);
}

extern "C" void kernel_launch(void* const* d_in, const int* in_sizes, int n_in,
                              void* d_out, int out_size, void* d_ws, size_t ws_size,
                              hipStream_t stream) {
  const float* uq       = (const float*)d_in[0];
  const float* q        = (const float*)d_in[1];
  const float* kk       = (const float*)d_in[2];
  const float* v        = (const float*)d_in[3];
  const void*  mask     = d_in[4];
  const float* fallback = (const float*)d_in[5];
  const float* Wv = (const float*)d_in[6];
  const float* bv = (const float*)d_in[7];
  const float* Wf = (const float*)d_in[8];
  const float* bf = (const float*)d_in[9];
  const float* W1 = (const float*)d_in[10];
  const float* b1 = (const float*)d_in[11];
  const float* W2 = (const float*)d_in[12];
  const float* b2 = (const float*)d_in[13];
  const float* W3 = (const float*)d_in[14];
  const float* b3 = (const float*)d_in[15];
  float* outp = (float*)d_out;

  char* ws = (char*)d_ws;
  const size_t MB = 1ull << 20;
  f16*  scores = (f16*)ws;
  f16*  h1b  = (f16*)ws;
  f16*  h2b  = (f16*)(ws + 16 * MB);
  f16*  vpt  = (f16*)(ws + 32 * MB);
  f16*  outb = (f16*)(ws + 48 * MB);
  f16*  wts  = (f16*)(ws + 64 * MB);
  f16*  v16  = (f16*)(ws + 96 * MB);
  char* cst  = ws + 112 * MB;
  f16*  Wv16 = (f16*)(cst);
  f16*  W116 = (f16*)(cst + 512 * 1024);
  f16*  W216 = (f16*)(cst + 1024 * 1024);
  float* dv   = (float*)(cst + 1280 * 1024);
  float* wfb  = (float*)(cst + 1312 * 1024);
  float* h1d  = (float*)(cst + 1376 * 1024);
  float* h2d  = (float*)(cst + 1408 * 1024);
  unsigned* mm = (unsigned*)(cst + 1424 * 1024);
  float* fbv   = (float*)(cst + 1428 * 1024);
  float* mmarr = (float*)(cst + 1432 * 1024);   // 2 * 256 floats

  // conv_v + weight converts + dv FC in one dispatch
  front_k<<<4736, 256, 0, stream>>>(v, v16, Wv, W1, W2, Wv16, W116, W216,
                                    uq, Wf, bf, dv);

  // scores = q @ k^T / sqrt(512) -> f16, q/k read as f32 (256x256 tiles, 8 waves)
  gemm256_scores<<<256, 512, 0, stream>>>(q, kk, scores, 0.04419417382415922f, mmarr);

  reduce_mm<<<1, 256, 0, stream>>>(mmarr, 256, fallback, fbv,
                                   (const unsigned char*)mask, mm);

  softmax_rows<<<16384, 256, 0, stream>>>(scores, mask, fbv, mm, wts, wfb);

  // vpt[d][k] = sum_e Wv[d][e] v[k][e] + bv[d]
  gemm_bt<EPI_BIASR, true><<<512, 256, 0, stream>>>(
      Wv16, v16, vpt, 512, 512, 1024, 512,
      0LL, 524288LL, 524288LL,
      bv, 1.f, nullptr, 0, nullptr, nullptr, 8, 32);

  // out = weights @ vp + wfb*dv
  gemm_bt<EPI_OUT, true><<<512, 256, 0, stream>>>(
      wts, vpt, outb, 1024, 1024, 512, 1024,
      1048576LL, 524288LL, 524288LL,
      nullptr, 1.f, nullptr, 0, wfb, dv, 4, 32);

  // h1 = relu(out @ W1^T + b1)
  gemm_bt<EPI_RELU, false><<<512, 256, 0, stream>>>(
      outb, W116, h1b, 512, 512, 512, 512, 0LL, 0LL, 0LL,
      b1, 1.f, nullptr, 0, nullptr, nullptr, 4, 512);

  // h2 = relu(h1 @ W2^T + b2)
  gemm_bt<EPI_RELU, false><<<256, 256, 0, stream>>>(
      h1b, W216, h2b, 512, 512, 256, 512, 0LL, 0LL, 0LL,
      b2, 1.f, nullptr, 0, nullptr, nullptr, 2, 256);

  y_kernel<<<1024, 256, 0, stream>>>(h2b, W3, b3, outp);

  // default-values scorer branch (f32, wave-per-output)
  fc_wave<512, 1><<<2048, 256, 0, stream>>>(dv, W1, b1, h1d, 512);
  fc_wave<512, 1><<<1024, 256, 0, stream>>>(h1d, W2, b2, h2d, 256);
  fc_wave<256, 2><<<4, 256, 0, stream>>>(h2d, W3, b3, outp + 16384, 1);

  (void)in_sizes; (void)n_in; (void)out_size; (void)ws_size;
}

// Round 14
// 161.686 us; speedup vs baseline: 1.1767x; 1.0465x over previous
//
#include <hip/hip_runtime.h>

typedef _Float16 f16;
typedef f16  f16x8 __attribute__((ext_vector_type(8)));
typedef f16  f16x4 __attribute__((ext_vector_type(4)));
typedef __fp16 fp16x2 __attribute__((ext_vector_type(2)));
typedef float f32x4 __attribute__((ext_vector_type(4)));

__device__ __forceinline__ void gld_lds16(const f16* g, void* l) {
  __builtin_amdgcn_global_load_lds((const __attribute__((address_space(1))) void*)g,
                                   (__attribute__((address_space(3))) void*)l,
                                   16, 0, 0);
}

// pack 8 f32 -> f16x8 via v_cvt_pkrtz (RTZ)
__device__ __forceinline__ f16x8 pack8(float4 a, float4 b) {
  union { f16x8 v; fp16x2 h[4]; } u;
  u.h[0] = __builtin_amdgcn_cvt_pkrtz(a.x, a.y);
  u.h[1] = __builtin_amdgcn_cvt_pkrtz(a.z, a.w);
  u.h[2] = __builtin_amdgcn_cvt_pkrtz(b.x, b.y);
  u.h[3] = __builtin_amdgcn_cvt_pkrtz(b.z, b.w);
  return u.v;
}

enum { EPI_SCORES = 0, EPI_RELU = 2, EPI_OUT = 3, EPI_BIASR = 4 };

// C[M,N] = A[M,K] @ B[N,K]^T, 128x128 tile, BK=32, 4 waves (2x2), 16x16x32 f16 MFMA.
// 4-stage LDS pipeline (2 stages prefetch-ahead), counted vmcnt with epilogue drain
// 8->4->0, raw s_barrier, swizzled LDS. 64KB LDS -> 2 blocks/CU.
// NOTE (R6): keep 128x128 with >=2 blocks/CU; fatter tiles at 1 block/CU regressed.
template<int EPI, bool XMAP>
__global__ __launch_bounds__(256)
void gemm_bt(const f16* __restrict__ A, const f16* __restrict__ B, void* __restrict__ C,
             int lda, int ldb, int ldc, int K,
             long long sA, long long sB, long long sC,
             const float* __restrict__ bias, float scale,
             float* __restrict__ mmarr, int nmm,
             const float* __restrict__ wfb, const float* __restrict__ dvv,
             int nx, int nbz)
{
  __shared__ __align__(16) f16 As[4][128][32];
  __shared__ __align__(16) f16 Bs[4][128][32];
  const int tid  = threadIdx.x;
  const int lane = tid & 63;
  const int w    = tid >> 6;
  const int wm   = w >> 1, wn = w & 1;

  const int lin = blockIdx.x;
  int bz, bj;
  if constexpr (XMAP) {
    const int xcd = lin & 7, rest = lin >> 3;
    const int grp = rest / nbz;
    bj = rest - grp * nbz;
    bz = xcd + (grp << 3);
  } else {
    bz = lin / nbz; bj = lin - bz * nbz;
  }
  const int m0 = (bj / nx) * 128, n0 = (bj % nx) * 128;
  const f16* Ab = A + (size_t)bz * sA + (size_t)m0 * lda;
  const f16* Bb = B + (size_t)bz * sB + (size_t)n0 * ldb;

  f32x4 acc[4][4] = {};
  const int nsteps = K >> 5;

#define STAGE(bufb, ks)                                                              \
  {                                                                                  \
    const int k0_ = (ks) << 5;                                                       \
    _Pragma("unroll")                                                                \
    for (int i = 0; i < 2; ++i) {                                                    \
      const int ci = i * 256 + tid;                                                  \
      const int r  = ci >> 2;                                                        \
      const int sg = (ci & 3) ^ ((r >> 1) & 3);                                      \
      gld_lds16(Ab + (size_t)r * lda + k0_ + sg * 8,                                 \
                (char*)As + (bufb) + (size_t)(i * 256 + w * 64) * 16);               \
      gld_lds16(Bb + (size_t)r * ldb + k0_ + sg * 8,                                 \
                (char*)Bs + (bufb) + (size_t)(i * 256 + w * 64) * 16);               \
    }                                                                                \
  }

  STAGE(0, 0)
  if (1 < nsteps) STAGE(8192, 1)
  if (2 < nsteps) STAGE(16384, 2)

  const int elemoff = (((lane >> 4) ^ ((lane >> 1) & 3)) << 3);

  int cur = 0;
  for (int t = 0; t < nsteps; ++t) {
    if (t + 2 < nsteps)      asm volatile("s_waitcnt vmcnt(8)" ::: "memory");
    else if (t + 1 < nsteps) asm volatile("s_waitcnt vmcnt(4)" ::: "memory");
    else                     asm volatile("s_waitcnt vmcnt(0)" ::: "memory");
    __builtin_amdgcn_s_barrier();
    __builtin_amdgcn_sched_barrier(0);
    if (t + 3 < nsteps) STAGE(((cur + 3) & 3) * 8192, t + 3)
    f16x8 af[4], bfr[4];
#pragma unroll
    for (int m = 0; m < 4; ++m)
      af[m] = *(const f16x8*)&As[cur][wm * 64 + m * 16 + (lane & 15)][elemoff];
#pragma unroll
    for (int n = 0; n < 4; ++n)
      bfr[n] = *(const f16x8*)&Bs[cur][wn * 64 + n * 16 + (lane & 15)][elemoff];
    __builtin_amdgcn_s_setprio(1);
#pragma unroll
    for (int m = 0; m < 4; ++m)
#pragma unroll
      for (int n = 0; n < 4; ++n)
        acc[m][n] = __builtin_amdgcn_mfma_f32_16x16x32_f16(af[m], bfr[n], acc[m][n], 0, 0, 0);
    __builtin_amdgcn_s_setprio(0);
    cur = (cur + 1) & 3;
  }
#undef STAGE

  const int col_l = lane & 15;
  const int row_l = (lane >> 4) << 2;

  {
    f16* Ch = (f16*)C + (size_t)bz * sC + (size_t)m0 * ldc + n0;
#pragma unroll
    for (int m = 0; m < 4; ++m)
#pragma unroll
      for (int n = 0; n < 4; ++n)
#pragma unroll
        for (int r = 0; r < 4; ++r) {
          const int rr = wm * 64 + m * 16 + row_l + r;
          const int cc = wn * 64 + n * 16 + col_l;
          float val = acc[m][n][r];
          if constexpr (EPI == EPI_RELU) { val += bias[n0 + cc]; val = fmaxf(val, 0.0f); }
          if constexpr (EPI == EPI_BIASR) val += bias[m0 + rr];
          if constexpr (EPI == EPI_OUT)
            val += wfb[bz * 1024 + m0 + rr] * dvv[bz * 512 + n0 + cc];
          Ch[(size_t)rr * ldc + cc] = (f16)val;
        }
  }
  (void)scale; (void)mmarr; (void)nmm;
}

// 256x256 scores GEMM reading q,k in f32, REG-STAGED to f16 LDS:
// global f32 -> regs (8 dwordx4/thread/stage) -> cvt_pkrtz -> ds_write_b128 into the
// R5-proven f16 layout. 3 buffers (96KB), ONE __syncthreads per step, 2-ahead prefetch.
// R14 fix: write-buffer index (cur+2)%3 was wrong for cur==2 (gave 4 -> LDS clobber).
__global__ __launch_bounds__(512, 2)
void gemm256_scores(const float* __restrict__ A, const float* __restrict__ B, f16* __restrict__ C,
                    float scale, float* __restrict__ mmarr)
{
  __shared__ __align__(16) f16 As[3][256][32];
  __shared__ __align__(16) f16 Bs[3][256][32];
  __shared__ float redm[8], redn[8];
  const int tid  = threadIdx.x;
  const int lane = tid & 63;
  const int w    = tid >> 6;           // 0..7
  const int wm   = w >> 2, wn = w & 3; // 2 x 4
  const int lin  = blockIdx.x;
  const int xcd = lin & 7, rest = lin >> 3;
  const int bj  = rest & 15;
  const int bz  = xcd + ((rest >> 4) << 3);
  const int m0 = (bj >> 2) * 256, n0 = (bj & 3) * 256;
  const float* Ab = A + (size_t)bz * 524288 + (size_t)m0 * 512;
  const float* Bb = B + (size_t)bz * 524288 + (size_t)n0 * 512;

  // chunk ci: row r=ci>>2, src f16-chunk sg=(ci&3)^((r>>1)&3) -> f32 elems sg*8..+7.
  // ci1 = tid+512: same (ci&3), same ((r>>1)&3) (r+128; 64 ≡ 0 mod 4) -> same sg.
  const int r0  = tid >> 2;
  const int sg0 = (tid & 3) ^ ((r0 >> 1) & 3);
  const size_t offG = (size_t)r0 * 512 + sg0 * 8;      // f32 offset (add k0 per stage)
  f16* const dstA0 = (f16*)As + (size_t)tid * 8;       // + buf*8192 (f16 units)
  f16* const dstB0 = (f16*)Bs + (size_t)tid * 8;

  f32x4 acc[8][4] = {};

  // prologue: stages 0,1 synchronously
#pragma unroll
  for (int s = 0; s < 2; ++s) {
    const int k0 = s << 5;
    float4 a0 = *(const float4*)(Ab + offG + k0);
    float4 a1 = *(const float4*)(Ab + offG + k0 + 4);
    float4 a2 = *(const float4*)(Ab + offG + k0 + 65536);
    float4 a3 = *(const float4*)(Ab + offG + k0 + 65540);
    float4 b0 = *(const float4*)(Bb + offG + k0);
    float4 b1 = *(const float4*)(Bb + offG + k0 + 4);
    float4 b2 = *(const float4*)(Bb + offG + k0 + 65536);
    float4 b3 = *(const float4*)(Bb + offG + k0 + 65540);
    *(f16x8*)(dstA0 + s * 8192)        = pack8(a0, a1);
    *(f16x8*)(dstA0 + s * 8192 + 4096) = pack8(a2, a3);
    *(f16x8*)(dstB0 + s * 8192)        = pack8(b0, b1);
    *(f16x8*)(dstB0 + s * 8192 + 4096) = pack8(b2, b3);
  }
  __syncthreads();

  const int fr = lane & 15;
  const int elemoff = (((lane >> 4) ^ ((lane >> 1) & 3)) << 3);  // f16 elements

  int cur = 0;
  for (int t = 0; t < 16; ++t) {
    // issue global loads for stage t+2 (plain loads; waits land before pack8 below)
    float4 a0, a1, a2, a3, b0, b1, b2, b3;
    if (t + 2 < 16) {
      const int k0 = (t + 2) << 5;
      a0 = *(const float4*)(Ab + offG + k0);
      a1 = *(const float4*)(Ab + offG + k0 + 4);
      a2 = *(const float4*)(Ab + offG + k0 + 65536);
      a3 = *(const float4*)(Ab + offG + k0 + 65540);
      b0 = *(const float4*)(Bb + offG + k0);
      b1 = *(const float4*)(Bb + offG + k0 + 4);
      b2 = *(const float4*)(Bb + offG + k0 + 65536);
      b3 = *(const float4*)(Bb + offG + k0 + 65540);
    }
    f16x8 af[8], bfr[4];
#pragma unroll
    for (int m = 0; m < 8; ++m)
      af[m] = *(const f16x8*)&As[cur][wm * 128 + m * 16 + fr][elemoff];
#pragma unroll
    for (int n = 0; n < 4; ++n)
      bfr[n] = *(const f16x8*)&Bs[cur][wn * 64 + n * 16 + fr][elemoff];
    __builtin_amdgcn_s_setprio(1);
#pragma unroll
    for (int m = 0; m < 8; ++m)
#pragma unroll
      for (int n = 0; n < 4; ++n)
        acc[m][n] = __builtin_amdgcn_mfma_f32_16x16x32_f16(af[m], bfr[n], acc[m][n], 0, 0, 0);
    __builtin_amdgcn_s_setprio(0);
    if (t + 2 < 16) {
      int wb = cur + 2; if (wb >= 3) wb -= 3;   // (cur+2)%3, FIXED
      *(f16x8*)(dstA0 + wb * 8192)        = pack8(a0, a1);
      *(f16x8*)(dstA0 + wb * 8192 + 4096) = pack8(a2, a3);
      *(f16x8*)(dstB0 + wb * 8192)        = pack8(b0, b1);
      *(f16x8*)(dstB0 + wb * 8192 + 4096) = pack8(b2, b3);
    }
    __syncthreads();   // drains lgkm+vm; frees buf[cur], publishes buf[(cur+2)%3]
    cur = (cur + 1 == 3) ? 0 : cur + 1;
  }

  const int col_l = lane & 15;
  const int row_l = (lane >> 4) << 2;
  f16* Ch = C + (size_t)bz * 1048576 + (size_t)m0 * 1024 + n0;
  float lmax = -3.402823466e38f, lmin = 3.402823466e38f;
#pragma unroll
  for (int m = 0; m < 8; ++m)
#pragma unroll
    for (int n = 0; n < 4; ++n)
#pragma unroll
      for (int r = 0; r < 4; ++r) {
        float val = acc[m][n][r] * scale;
        lmax = fmaxf(lmax, val); lmin = fminf(lmin, val);
        Ch[(size_t)(wm * 128 + m * 16 + row_l + r) * 1024 + (wn * 64 + n * 16 + col_l)] = (f16)val;
      }
#pragma unroll
  for (int off = 32; off >= 1; off >>= 1) {
    lmax = fmaxf(lmax, __shfl_xor(lmax, off));
    lmin = fminf(lmin, __shfl_xor(lmin, off));
  }
  if (lane == 0) { redm[w] = lmax; redn[w] = lmin; }
  __syncthreads();
  if (tid == 0) {
    float gm = redm[0], gn = redn[0];
#pragma unroll
    for (int i = 1; i < 8; ++i) { gm = fmaxf(gm, redm[i]); gn = fminf(gn, redn[i]); }
    mmarr[lin] = gm; mmarr[256 + lin] = gn;
  }
}

// reduce per-block max/min -> fb scalar; also counts nonzero mask bytes (dtype sniff)
__global__ __launch_bounds__(256)
void reduce_mm(const float* __restrict__ mmarr, int n,
               const float* __restrict__ fallback, float* __restrict__ fbv,
               const unsigned char* __restrict__ mask, unsigned* __restrict__ mm)
{
  __shared__ float rm[4], rn[4];
  __shared__ int redc[256];
  const int lane = threadIdx.x & 63, w = threadIdx.x >> 6;
  float mx = -3.402823466e38f, mn = 3.402823466e38f;
  for (int i = threadIdx.x; i < n; i += 256) {
    mx = fmaxf(mx, mmarr[i]);
    mn = fminf(mn, mmarr[n + i]);
  }
#pragma unroll
  for (int off = 32; off >= 1; off >>= 1) {
    mx = fmaxf(mx, __shfl_xor(mx, off));
    mn = fminf(mn, __shfl_xor(mn, off));
  }
  if (lane == 0) { rm[w] = mx; rn[w] = mn; }
  int c = 0;
  for (int i = threadIdx.x; i < 16384; i += 256) c += (mask[i] != 0) ? 1 : 0;
  redc[threadIdx.x] = c;
  __syncthreads();
  for (int s = 128; s > 0; s >>= 1) {
    if (threadIdx.x < s) redc[threadIdx.x] += redc[threadIdx.x + s];
    __syncthreads();
  }
  if (threadIdx.x == 0) {
    float gmax = fmaxf(fmaxf(rm[0], rm[1]), fmaxf(rm[2], rm[3]));
    float gmin = fminf(fminf(rn[0], rn[1]), fminf(rn[2], rn[3]));
    fbv[0] = 0.99f * fallback[0] + 0.005f * (gmax + gmin);
    mm[0] = (unsigned)redc[0];
  }
}

// merged front work: [0,2048) conv_v; [2048,2688) weight converts; [2688,4736) dv FC
__global__ __launch_bounds__(256)
void front_k(const float* __restrict__ v, f16* __restrict__ v16,
             const float* __restrict__ wv, const float* __restrict__ w1,
             const float* __restrict__ w2,
             f16* __restrict__ owv, f16* __restrict__ ow1, f16* __restrict__ ow2,
             const float* __restrict__ uq, const float* __restrict__ Wf,
             const float* __restrict__ bfv, float* __restrict__ dv)
{
  const int blk = blockIdx.x;
  if (blk < 2048) {
    const int i = blk * 256 + threadIdx.x;
#pragma unroll
    for (int it = 0; it < 4; ++it) {
      const size_t j = (size_t)i + (size_t)it * 524288;
      float4 x = *(const float4*)(v + j * 4);
      f16x4 o = { (f16)x.x, (f16)x.y, (f16)x.z, (f16)x.w };
      *(f16x4*)(v16 + j * 4) = o;
    }
  } else if (blk < 2688) {
    int i = (blk - 2048) * 256 + threadIdx.x;   // 0..163839
    const float* src; f16* dst; int j;
    if (i < 65536)       { src = wv; dst = owv; j = i; }
    else if (i < 131072) { src = w1; dst = ow1; j = i - 65536; }
    else                 { src = w2; dst = ow2; j = i - 131072; }
    float4 x = *(const float4*)(src + (size_t)j * 4);
    f16x4 o = { (f16)x.x, (f16)x.y, (f16)x.z, (f16)x.w };
    *(f16x4*)(dst + (size_t)j * 4) = o;
  } else {
    const int gw   = ((blk - 2688) * 256 + threadIdx.x) >> 6;  // 0..8191
    const int lane = threadIdx.x & 63;
    const int b = gw >> 9, j = gw & 511;
    const float* x  = uq + (size_t)b * 512;
    const float* wr = Wf + (size_t)j * 512;
    const int o = lane * 8;
    float4 x0 = *(const float4*)(x + o),  x1 = *(const float4*)(x + o + 4);
    float4 w0 = *(const float4*)(wr + o), w1v = *(const float4*)(wr + o + 4);
    float s = x0.x*w0.x + x0.y*w0.y + x0.z*w0.z + x0.w*w0.w
            + x1.x*w1v.x + x1.y*w1v.y + x1.z*w1v.z + x1.w*w1v.w;
#pragma unroll
    for (int off = 32; off >= 1; off >>= 1) s += __shfl_xor(s, off);
    if (lane == 0) dv[gw] = s + bfv[j];
  }
}

__global__ __launch_bounds__(256)
void softmax_rows(const f16* __restrict__ scores, const void* __restrict__ maskp,
                  const float* __restrict__ fbv, const unsigned* __restrict__ mm,
                  f16* __restrict__ Wt, float* __restrict__ wfb)
{
  __shared__ float red[8];
  const int row  = blockIdx.x;
  const int b    = row >> 10;
  const int tid  = threadIdx.x;
  const int lane = tid & 63, w = tid >> 6;
  const float fb = fbv[0];
  const unsigned mode = (mm[0] > 5000u) ? 1u : 0u;
  const f16* s = scores + (size_t)row * 1024;
  const int k0 = tid * 4;
  f16x4 sv = *(const f16x4*)(s + k0);
  float x[4];
  if (mode) {
    const unsigned char* m8 = (const unsigned char*)maskp + b * 1024 + k0;
    x[0] = m8[0] ? -1e9f : (float)sv[0];  x[1] = m8[1] ? -1e9f : (float)sv[1];
    x[2] = m8[2] ? -1e9f : (float)sv[2];  x[3] = m8[3] ? -1e9f : (float)sv[3];
  } else {
    const int* mi = (const int*)maskp + b * 1024 + k0;
    x[0] = mi[0] ? -1e9f : (float)sv[0];  x[1] = mi[1] ? -1e9f : (float)sv[1];
    x[2] = mi[2] ? -1e9f : (float)sv[2];  x[3] = mi[3] ? -1e9f : (float)sv[3];
  }
  float mx = fmaxf(fmaxf(x[0], x[1]), fmaxf(x[2], x[3]));
#pragma unroll
  for (int off = 32; off >= 1; off >>= 1) mx = fmaxf(mx, __shfl_xor(mx, off));
  if (lane == 0) red[w] = mx;
  __syncthreads();
  mx = fmaxf(fmaxf(fmaxf(red[0], red[1]), fmaxf(red[2], red[3])), fb);
  float e0 = expf(x[0] - mx), e1 = expf(x[1] - mx), e2 = expf(x[2] - mx), e3 = expf(x[3] - mx);
  float sum = (e0 + e1) + (e2 + e3);
#pragma unroll
  for (int off = 32; off >= 1; off >>= 1) sum += __shfl_xor(sum, off);
  if (lane == 0) red[4 + w] = sum;
  __syncthreads();
  float efb = expf(fb - mx);
  float Z = ((red[4] + red[5]) + (red[6] + red[7])) + efb;
  float inv = 1.0f / Z;
  f16x4 o = { (f16)(e0 * inv), (f16)(e1 * inv), (f16)(e2 * inv), (f16)(e3 * inv) };
  *(f16x4*)&Wt[(size_t)row * 1024 + k0] = o;
  if (tid == 0) wfb[row] = efb * inv;
}

// wave-per-output FC: Y[b,j] = act(X[b,:] . W[j,:] + bias[j])
template<int IN, int ACT>
__global__ __launch_bounds__(256)
void fc_wave(const float* __restrict__ X, const float* __restrict__ W,
             const float* __restrict__ bias, float* __restrict__ Y, int OutN)
{
  const int gw   = (blockIdx.x * 256 + threadIdx.x) >> 6;
  const int lane = threadIdx.x & 63;
  const int b = gw / OutN, j = gw - b * OutN;
  const float* x  = X + (size_t)b * IN;
  const float* wr = W + (size_t)j * IN;
  float s = 0.f;
  if constexpr (IN == 512) {
    const int o = lane * 8;
    float4 x0 = *(const float4*)(x + o),  x1 = *(const float4*)(x + o + 4);
    float4 w0 = *(const float4*)(wr + o), w1 = *(const float4*)(wr + o + 4);
    s = x0.x*w0.x + x0.y*w0.y + x0.z*w0.z + x0.w*w0.w
      + x1.x*w1.x + x1.y*w1.y + x1.z*w1.z + x1.w*w1.w;
  } else {
    const int o = lane * 4;
    float4 x0 = *(const float4*)(x + o);
    float4 w0 = *(const float4*)(wr + o);
    s = x0.x*w0.x + x0.y*w0.y + x0.z*w0.z + x0.w*w0.w;
  }
#pragma unroll
  for (int off = 32; off >= 1; off >>= 1) s += __shfl_xor(s, off);
  if (lane == 0) {
    float val = s + bias[ACT == 2 ? 0 : j];
    if constexpr (ACT == 1) val = fmaxf(val, 0.f);
    if constexpr (ACT == 2) val = tanhf(val);
    Y[gw] = val;
  }
}

__global__ __launch_bounds__(256)
void y_kernel(const f16* __restrict__ h2, const float* __restrict__ W3,
              const float* __restrict__ b3, float* __restrict__ outp)
{
  int row = blockIdx.x * 16 + (threadIdx.x >> 4);
  int l   = threadIdx.x & 15;
  const f16* h = h2 + (size_t)row * 256 + l * 16;
  float s = 0.f;
#pragma unroll
  for (int j = 0; j < 16; ++j) s += (float)h[j] * W3[l * 16 + j];
#pragma unroll
  for (int off = 1; off < 16; off <<= 1) s += __shfl_xor(s, off);
  if (l == 0) outp[row] = tanhf(s + b3[0]);
}

extern "C" void kernel_launch(void* const* d_in, const int* in_sizes, int n_in,
                              void* d_out, int out_size, void* d_ws, size_t ws_size,
                              hipStream_t stream) {
  const float* uq       = (const float*)d_in[0];
  const float* q        = (const float*)d_in[1];
  const float* kk       = (const float*)d_in[2];
  const float* v        = (const float*)d_in[3];
  const void*  mask     = d_in[4];
  const float* fallback = (const float*)d_in[5];
  const float* Wv = (const float*)d_in[6];
  const float* bv = (const float*)d_in[7];
  const float* Wf = (const float*)d_in[8];
  const float* bf = (const float*)d_in[9];
  const float* W1 = (const float*)d_in[10];
  const float* b1 = (const float*)d_in[11];
  const float* W2 = (const float*)d_in[12];
  const float* b2 = (const float*)d_in[13];
  const float* W3 = (const float*)d_in[14];
  const float* b3 = (const float*)d_in[15];
  float* outp = (float*)d_out;

  char* ws = (char*)d_ws;
  const size_t MB = 1ull << 20;
  f16*  scores = (f16*)ws;
  f16*  h1b  = (f16*)ws;
  f16*  h2b  = (f16*)(ws + 16 * MB);
  f16*  vpt  = (f16*)(ws + 32 * MB);
  f16*  outb = (f16*)(ws + 48 * MB);
  f16*  wts  = (f16*)(ws + 64 * MB);
  f16*  v16  = (f16*)(ws + 96 * MB);
  char* cst  = ws + 112 * MB;
  f16*  Wv16 = (f16*)(cst);
  f16*  W116 = (f16*)(cst + 512 * 1024);
  f16*  W216 = (f16*)(cst + 1024 * 1024);
  float* dv   = (float*)(cst + 1280 * 1024);
  float* wfb  = (float*)(cst + 1312 * 1024);
  float* h1d  = (float*)(cst + 1376 * 1024);
  float* h2d  = (float*)(cst + 1408 * 1024);
  unsigned* mm = (unsigned*)(cst + 1424 * 1024);
  float* fbv   = (float*)(cst + 1428 * 1024);
  float* mmarr = (float*)(cst + 1432 * 1024);   // 2 * 256 floats

  // conv_v + weight converts + dv FC in one dispatch
  front_k<<<4736, 256, 0, stream>>>(v, v16, Wv, W1, W2, Wv16, W116, W216,
                                    uq, Wf, bf, dv);

  // scores = q @ k^T / sqrt(512) -> f16, q/k read as f32, reg-staged to f16 LDS
  gemm256_scores<<<256, 512, 0, stream>>>(q, kk, scores, 0.04419417382415922f, mmarr);

  reduce_mm<<<1, 256, 0, stream>>>(mmarr, 256, fallback, fbv,
                                   (const unsigned char*)mask, mm);

  softmax_rows<<<16384, 256, 0, stream>>>(scores, mask, fbv, mm, wts, wfb);

  // vpt[d][k] = sum_e Wv[d][e] v[k][e] + bv[d]
  gemm_bt<EPI_BIASR, true><<<512, 256, 0, stream>>>(
      Wv16, v16, vpt, 512, 512, 1024, 512,
      0LL, 524288LL, 524288LL,
      bv, 1.f, nullptr, 0, nullptr, nullptr, 8, 32);

  // out = weights @ vp + wfb*dv
  gemm_bt<EPI_OUT, true><<<512, 256, 0, stream>>>(
      wts, vpt, outb, 1024, 1024, 512, 1024,
      1048576LL, 524288LL, 524288LL,
      nullptr, 1.f, nullptr, 0, wfb, dv, 4, 32);

  // h1 = relu(out @ W1^T + b1)
  gemm_bt<EPI_RELU, false><<<512, 256, 0, stream>>>(
      outb, W116, h1b, 512, 512, 512, 512, 0LL, 0LL, 0LL,
      b1, 1.f, nullptr, 0, nullptr, nullptr, 4, 512);

  // h2 = relu(h1 @ W2^T + b2)
  gemm_bt<EPI_RELU, false><<<256, 256, 0, stream>>>(
      h1b, W216, h2b, 512, 512, 256, 512, 0LL, 0LL, 0LL,
      b2, 1.f, nullptr, 0, nullptr, nullptr, 2, 256);

  y_kernel<<<1024, 256, 0, stream>>>(h2b, W3, b3, outp);

  // default-values scorer branch (f32, wave-per-output)
  fc_wave<512, 1><<<2048, 256, 0, stream>>>(dv, W1, b1, h1d, 512);
  fc_wave<512, 1><<<1024, 256, 0, stream>>>(h1d, W2, b2, h2d, 256);
  fc_wave<256, 2><<<4, 256, 0, stream>>>(h2d, W3, b3, outp + 16384, 1);

  (void)in_sizes; (void)n_in; (void)out_size; (void)ws_size;
}

// Round 15
// 161.175 us; speedup vs baseline: 1.1804x; 1.0032x over previous
//
#include <hip/hip_runtime.h>

typedef _Float16 f16;
typedef f16  f16x8 __attribute__((ext_vector_type(8)));
typedef f16  f16x4 __attribute__((ext_vector_type(4)));
typedef __fp16 fp16x2 __attribute__((ext_vector_type(2)));
typedef float f32x4 __attribute__((ext_vector_type(4)));

__device__ __forceinline__ void gld_lds16(const f16* g, void* l) {
  __builtin_amdgcn_global_load_lds((const __attribute__((address_space(1))) void*)g,
                                   (__attribute__((address_space(3))) void*)l,
                                   16, 0, 0);
}

// pack 8 f32 -> f16x8 via v_cvt_pkrtz (RTZ)
__device__ __forceinline__ f16x8 pack8(float4 a, float4 b) {
  union { f16x8 v; fp16x2 h[4]; } u;
  u.h[0] = __builtin_amdgcn_cvt_pkrtz(a.x, a.y);
  u.h[1] = __builtin_amdgcn_cvt_pkrtz(a.z, a.w);
  u.h[2] = __builtin_amdgcn_cvt_pkrtz(b.x, b.y);
  u.h[3] = __builtin_amdgcn_cvt_pkrtz(b.z, b.w);
  return u.v;
}

enum { EPI_SCORES = 0, EPI_RELU = 2, EPI_OUT = 3, EPI_BIASR = 4 };

// C[M,N] = A[M,K] @ B[N,K]^T, 128x128 tile, BK=32, 4 waves (2x2), 16x16x32 f16 MFMA.
// 4-stage LDS pipeline, counted vmcnt drain 8->4->0, raw s_barrier, swizzled LDS.
// NOTE (R6): keep 128x128 with >=2 blocks/CU; fatter tiles at 1 block/CU regressed.
template<int EPI, bool XMAP>
__global__ __launch_bounds__(256)
void gemm_bt(const f16* __restrict__ A, const f16* __restrict__ B, void* __restrict__ C,
             int lda, int ldb, int ldc, int K,
             long long sA, long long sB, long long sC,
             const float* __restrict__ bias, float scale,
             float* __restrict__ mmarr, int nmm,
             const float* __restrict__ wfb, const float* __restrict__ dvv,
             int nx, int nbz)
{
  __shared__ __align__(16) f16 As[4][128][32];
  __shared__ __align__(16) f16 Bs[4][128][32];
  const int tid  = threadIdx.x;
  const int lane = tid & 63;
  const int w    = tid >> 6;
  const int wm   = w >> 1, wn = w & 1;

  const int lin = blockIdx.x;
  int bz, bj;
  if constexpr (XMAP) {
    const int xcd = lin & 7, rest = lin >> 3;
    const int grp = rest / nbz;
    bj = rest - grp * nbz;
    bz = xcd + (grp << 3);
  } else {
    bz = lin / nbz; bj = lin - bz * nbz;
  }
  const int m0 = (bj / nx) * 128, n0 = (bj % nx) * 128;
  const f16* Ab = A + (size_t)bz * sA + (size_t)m0 * lda;
  const f16* Bb = B + (size_t)bz * sB + (size_t)n0 * ldb;

  f32x4 acc[4][4] = {};
  const int nsteps = K >> 5;

#define STAGE(bufb, ks)                                                              \
  {                                                                                  \
    const int k0_ = (ks) << 5;                                                       \
    _Pragma("unroll")                                                                \
    for (int i = 0; i < 2; ++i) {                                                    \
      const int ci = i * 256 + tid;                                                  \
      const int r  = ci >> 2;                                                        \
      const int sg = (ci & 3) ^ ((r >> 1) & 3);                                      \
      gld_lds16(Ab + (size_t)r * lda + k0_ + sg * 8,                                 \
                (char*)As + (bufb) + (size_t)(i * 256 + w * 64) * 16);               \
      gld_lds16(Bb + (size_t)r * ldb + k0_ + sg * 8,                                 \
                (char*)Bs + (bufb) + (size_t)(i * 256 + w * 64) * 16);               \
    }                                                                                \
  }

  STAGE(0, 0)
  if (1 < nsteps) STAGE(8192, 1)
  if (2 < nsteps) STAGE(16384, 2)

  const int elemoff = (((lane >> 4) ^ ((lane >> 1) & 3)) << 3);

  int cur = 0;
  for (int t = 0; t < nsteps; ++t) {
    if (t + 2 < nsteps)      asm volatile("s_waitcnt vmcnt(8)" ::: "memory");
    else if (t + 1 < nsteps) asm volatile("s_waitcnt vmcnt(4)" ::: "memory");
    else                     asm volatile("s_waitcnt vmcnt(0)" ::: "memory");
    __builtin_amdgcn_s_barrier();
    __builtin_amdgcn_sched_barrier(0);
    if (t + 3 < nsteps) STAGE(((cur + 3) & 3) * 8192, t + 3)
    f16x8 af[4], bfr[4];
#pragma unroll
    for (int m = 0; m < 4; ++m)
      af[m] = *(const f16x8*)&As[cur][wm * 64 + m * 16 + (lane & 15)][elemoff];
#pragma unroll
    for (int n = 0; n < 4; ++n)
      bfr[n] = *(const f16x8*)&Bs[cur][wn * 64 + n * 16 + (lane & 15)][elemoff];
    __builtin_amdgcn_s_setprio(1);
#pragma unroll
    for (int m = 0; m < 4; ++m)
#pragma unroll
      for (int n = 0; n < 4; ++n)
        acc[m][n] = __builtin_amdgcn_mfma_f32_16x16x32_f16(af[m], bfr[n], acc[m][n], 0, 0, 0);
    __builtin_amdgcn_s_setprio(0);
    cur = (cur + 1) & 3;
  }
#undef STAGE

  const int col_l = lane & 15;
  const int row_l = (lane >> 4) << 2;

  {
    f16* Ch = (f16*)C + (size_t)bz * sC + (size_t)m0 * ldc + n0;
#pragma unroll
    for (int m = 0; m < 4; ++m)
#pragma unroll
      for (int n = 0; n < 4; ++n)
#pragma unroll
        for (int r = 0; r < 4; ++r) {
          const int rr = wm * 64 + m * 16 + row_l + r;
          const int cc = wn * 64 + n * 16 + col_l;
          float val = acc[m][n][r];
          if constexpr (EPI == EPI_RELU) { val += bias[n0 + cc]; val = fmaxf(val, 0.0f); }
          if constexpr (EPI == EPI_BIASR) val += bias[m0 + rr];
          if constexpr (EPI == EPI_OUT)
            val += wfb[bz * 1024 + m0 + rr] * dvv[bz * 512 + n0 + cc];
          Ch[(size_t)rr * ldc + cc] = (f16)val;
        }
  }
  (void)scale; (void)mmarr; (void)nmm;
}

// 256x256 scores GEMM reading q,k in f32, REG-STAGED to f16 LDS (proven R14):
// f32 -> regs -> cvt_pkrtz -> ds_write_b128; 3 buffers, one __syncthreads/step.
__global__ __launch_bounds__(512, 2)
void gemm256_scores(const float* __restrict__ A, const float* __restrict__ B, f16* __restrict__ C,
                    float scale, float* __restrict__ mmarr)
{
  __shared__ __align__(16) f16 As[3][256][32];
  __shared__ __align__(16) f16 Bs[3][256][32];
  __shared__ float redm[8], redn[8];
  const int tid  = threadIdx.x;
  const int lane = tid & 63;
  const int w    = tid >> 6;           // 0..7
  const int wm   = w >> 2, wn = w & 3; // 2 x 4
  const int lin  = blockIdx.x;
  const int xcd = lin & 7, rest = lin >> 3;
  const int bj  = rest & 15;
  const int bz  = xcd + ((rest >> 4) << 3);
  const int m0 = (bj >> 2) * 256, n0 = (bj & 3) * 256;
  const float* Ab = A + (size_t)bz * 524288 + (size_t)m0 * 512;
  const float* Bb = B + (size_t)bz * 524288 + (size_t)n0 * 512;

  const int r0  = tid >> 2;
  const int sg0 = (tid & 3) ^ ((r0 >> 1) & 3);
  const size_t offG = (size_t)r0 * 512 + sg0 * 8;      // f32 offset
  f16* const dstA0 = (f16*)As + (size_t)tid * 8;       // + buf*8192
  f16* const dstB0 = (f16*)Bs + (size_t)tid * 8;

  f32x4 acc[8][4] = {};

#pragma unroll
  for (int s = 0; s < 2; ++s) {
    const int k0 = s << 5;
    float4 a0 = *(const float4*)(Ab + offG + k0);
    float4 a1 = *(const float4*)(Ab + offG + k0 + 4);
    float4 a2 = *(const float4*)(Ab + offG + k0 + 65536);
    float4 a3 = *(const float4*)(Ab + offG + k0 + 65540);
    float4 b0 = *(const float4*)(Bb + offG + k0);
    float4 b1 = *(const float4*)(Bb + offG + k0 + 4);
    float4 b2 = *(const float4*)(Bb + offG + k0 + 65536);
    float4 b3 = *(const float4*)(Bb + offG + k0 + 65540);
    *(f16x8*)(dstA0 + s * 8192)        = pack8(a0, a1);
    *(f16x8*)(dstA0 + s * 8192 + 4096) = pack8(a2, a3);
    *(f16x8*)(dstB0 + s * 8192)        = pack8(b0, b1);
    *(f16x8*)(dstB0 + s * 8192 + 4096) = pack8(b2, b3);
  }
  __syncthreads();

  const int fr = lane & 15;
  const int elemoff = (((lane >> 4) ^ ((lane >> 1) & 3)) << 3);  // f16 elements

  int cur = 0;
  for (int t = 0; t < 16; ++t) {
    float4 a0, a1, a2, a3, b0, b1, b2, b3;
    if (t + 2 < 16) {
      const int k0 = (t + 2) << 5;
      a0 = *(const float4*)(Ab + offG + k0);
      a1 = *(const float4*)(Ab + offG + k0 + 4);
      a2 = *(const float4*)(Ab + offG + k0 + 65536);
      a3 = *(const float4*)(Ab + offG + k0 + 65540);
      b0 = *(const float4*)(Bb + offG + k0);
      b1 = *(const float4*)(Bb + offG + k0 + 4);
      b2 = *(const float4*)(Bb + offG + k0 + 65536);
      b3 = *(const float4*)(Bb + offG + k0 + 65540);
    }
    f16x8 af[8], bfr[4];
#pragma unroll
    for (int m = 0; m < 8; ++m)
      af[m] = *(const f16x8*)&As[cur][wm * 128 + m * 16 + fr][elemoff];
#pragma unroll
    for (int n = 0; n < 4; ++n)
      bfr[n] = *(const f16x8*)&Bs[cur][wn * 64 + n * 16 + fr][elemoff];
    __builtin_amdgcn_s_setprio(1);
#pragma unroll
    for (int m = 0; m < 8; ++m)
#pragma unroll
      for (int n = 0; n < 4; ++n)
        acc[m][n] = __builtin_amdgcn_mfma_f32_16x16x32_f16(af[m], bfr[n], acc[m][n], 0, 0, 0);
    __builtin_amdgcn_s_setprio(0);
    if (t + 2 < 16) {
      int wb = cur + 2; if (wb >= 3) wb -= 3;
      *(f16x8*)(dstA0 + wb * 8192)        = pack8(a0, a1);
      *(f16x8*)(dstA0 + wb * 8192 + 4096) = pack8(a2, a3);
      *(f16x8*)(dstB0 + wb * 8192)        = pack8(b0, b1);
      *(f16x8*)(dstB0 + wb * 8192 + 4096) = pack8(b2, b3);
    }
    __syncthreads();
    cur = (cur + 1 == 3) ? 0 : cur + 1;
  }

  const int col_l = lane & 15;
  const int row_l = (lane >> 4) << 2;
  f16* Ch = C + (size_t)bz * 1048576 + (size_t)m0 * 1024 + n0;
  float lmax = -3.402823466e38f, lmin = 3.402823466e38f;
#pragma unroll
  for (int m = 0; m < 8; ++m)
#pragma unroll
    for (int n = 0; n < 4; ++n)
#pragma unroll
      for (int r = 0; r < 4; ++r) {
        float val = acc[m][n][r] * scale;
        lmax = fmaxf(lmax, val); lmin = fminf(lmin, val);
        Ch[(size_t)(wm * 128 + m * 16 + row_l + r) * 1024 + (wn * 64 + n * 16 + col_l)] = (f16)val;
      }
#pragma unroll
  for (int off = 32; off >= 1; off >>= 1) {
    lmax = fmaxf(lmax, __shfl_xor(lmax, off));
    lmin = fminf(lmin, __shfl_xor(lmin, off));
  }
  if (lane == 0) { redm[w] = lmax; redn[w] = lmin; }
  __syncthreads();
  if (tid == 0) {
    float gm = redm[0], gn = redn[0];
#pragma unroll
    for (int i = 1; i < 8; ++i) { gm = fmaxf(gm, redm[i]); gn = fminf(gn, redn[i]); }
    mmarr[lin] = gm; mmarr[256 + lin] = gn;
  }
}

// vpt[d][k] = sum_e Wv[d][e]*v[k][e] + bv[d].  A = Wv16 (f16), B = v (f32, read
// DIRECTLY — conv_v eliminated). Both operands reg-staged to f16 LDS, 128x128 tile,
// 4 waves, 3 buffers (48KB -> 3 blocks/CU), one __syncthreads/step, 2-ahead prefetch.
// Same chunk involution as scores (ci: r=ci>>2, sg=(ci&3)^((r>>1)&3); ci1=tid+256
// -> +64 rows, same sg since 64 ≡ 0 mod 4). Grid 512: XMAP nbz=32 (4 m x 8 n).
__global__ __launch_bounds__(256)
void gemm_vpt(const f16* __restrict__ A, const float* __restrict__ B, f16* __restrict__ C,
              const float* __restrict__ bias)
{
  __shared__ __align__(16) f16 As[3][128][32];
  __shared__ __align__(16) f16 Bs[3][128][32];
  const int tid  = threadIdx.x;
  const int lane = tid & 63;
  const int w    = tid >> 6;
  const int wm   = w >> 1, wn = w & 1;
  const int lin  = blockIdx.x;
  const int xcd = lin & 7, rest = lin >> 3;
  const int grp = rest >> 5, bj = rest & 31;
  const int bz  = xcd + (grp << 3);
  const int m0 = (bj >> 3) * 128, n0 = (bj & 7) * 128;
  const f16*   Ab = A + (size_t)m0 * 512;                      // Wv16 (no batch)
  const float* Bb = B + (size_t)bz * 524288 + (size_t)n0 * 512; // v f32

  const int r0  = tid >> 2;
  const int sg0 = (tid & 3) ^ ((r0 >> 1) & 3);
  const size_t offA = (size_t)r0 * 512 + sg0 * 8;   // f16 elems
  const size_t offB = (size_t)r0 * 512 + sg0 * 8;   // f32 elems
  f16* const dstA0 = (f16*)As + (size_t)tid * 8;    // + buf*4096
  f16* const dstB0 = (f16*)Bs + (size_t)tid * 8;

  f32x4 acc[4][4] = {};

#pragma unroll
  for (int s = 0; s < 2; ++s) {
    const int k0 = s << 5;
    f16x8  a0 = *(const f16x8*)(Ab + offA + k0);
    f16x8  a1 = *(const f16x8*)(Ab + offA + k0 + 32768);   // +64 rows (f16)
    float4 b0 = *(const float4*)(Bb + offB + k0);
    float4 b1 = *(const float4*)(Bb + offB + k0 + 4);
    float4 b2 = *(const float4*)(Bb + offB + k0 + 32768);  // +64 rows (f32)
    float4 b3 = *(const float4*)(Bb + offB + k0 + 32772);
    *(f16x8*)(dstA0 + s * 4096)        = a0;
    *(f16x8*)(dstA0 + s * 4096 + 2048) = a1;
    *(f16x8*)(dstB0 + s * 4096)        = pack8(b0, b1);
    *(f16x8*)(dstB0 + s * 4096 + 2048) = pack8(b2, b3);
  }
  __syncthreads();

  const int fr = lane & 15;
  const int elemoff = (((lane >> 4) ^ ((lane >> 1) & 3)) << 3);

  int cur = 0;
  for (int t = 0; t < 16; ++t) {
    f16x8  a0, a1; float4 b0, b1, b2, b3;
    if (t + 2 < 16) {
      const int k0 = (t + 2) << 5;
      a0 = *(const f16x8*)(Ab + offA + k0);
      a1 = *(const f16x8*)(Ab + offA + k0 + 32768);
      b0 = *(const float4*)(Bb + offB + k0);
      b1 = *(const float4*)(Bb + offB + k0 + 4);
      b2 = *(const float4*)(Bb + offB + k0 + 32768);
      b3 = *(const float4*)(Bb + offB + k0 + 32772);
    }
    f16x8 af[4], bfr[4];
#pragma unroll
    for (int m = 0; m < 4; ++m)
      af[m] = *(const f16x8*)&As[cur][wm * 64 + m * 16 + fr][elemoff];
#pragma unroll
    for (int n = 0; n < 4; ++n)
      bfr[n] = *(const f16x8*)&Bs[cur][wn * 64 + n * 16 + fr][elemoff];
    __builtin_amdgcn_s_setprio(1);
#pragma unroll
    for (int m = 0; m < 4; ++m)
#pragma unroll
      for (int n = 0; n < 4; ++n)
        acc[m][n] = __builtin_amdgcn_mfma_f32_16x16x32_f16(af[m], bfr[n], acc[m][n], 0, 0, 0);
    __builtin_amdgcn_s_setprio(0);
    if (t + 2 < 16) {
      int wb = cur + 2; if (wb >= 3) wb -= 3;
      *(f16x8*)(dstA0 + wb * 4096)        = a0;
      *(f16x8*)(dstA0 + wb * 4096 + 2048) = a1;
      *(f16x8*)(dstB0 + wb * 4096)        = pack8(b0, b1);
      *(f16x8*)(dstB0 + wb * 4096 + 2048) = pack8(b2, b3);
    }
    __syncthreads();
    cur = (cur + 1 == 3) ? 0 : cur + 1;
  }

  const int col_l = lane & 15;
  const int row_l = (lane >> 4) << 2;
  f16* Ch = C + (size_t)bz * 524288 + (size_t)m0 * 1024 + n0;
#pragma unroll
  for (int m = 0; m < 4; ++m)
#pragma unroll
    for (int n = 0; n < 4; ++n)
#pragma unroll
      for (int r = 0; r < 4; ++r) {
        const int rr = wm * 64 + m * 16 + row_l + r;
        const int cc = wn * 64 + n * 16 + col_l;
        Ch[(size_t)rr * 1024 + cc] = (f16)(acc[m][n][r] + bias[m0 + rr]);
      }
}

// reduce per-block max/min -> fb scalar; also counts nonzero mask bytes (dtype sniff)
__global__ __launch_bounds__(256)
void reduce_mm(const float* __restrict__ mmarr, int n,
               const float* __restrict__ fallback, float* __restrict__ fbv,
               const unsigned char* __restrict__ mask, unsigned* __restrict__ mm)
{
  __shared__ float rm[4], rn[4];
  __shared__ int redc[256];
  const int lane = threadIdx.x & 63, w = threadIdx.x >> 6;
  float mx = -3.402823466e38f, mn = 3.402823466e38f;
  for (int i = threadIdx.x; i < n; i += 256) {
    mx = fmaxf(mx, mmarr[i]);
    mn = fminf(mn, mmarr[n + i]);
  }
#pragma unroll
  for (int off = 32; off >= 1; off >>= 1) {
    mx = fmaxf(mx, __shfl_xor(mx, off));
    mn = fminf(mn, __shfl_xor(mn, off));
  }
  if (lane == 0) { rm[w] = mx; rn[w] = mn; }
  int c = 0;
  for (int i = threadIdx.x; i < 16384; i += 256) c += (mask[i] != 0) ? 1 : 0;
  redc[threadIdx.x] = c;
  __syncthreads();
  for (int s = 128; s > 0; s >>= 1) {
    if (threadIdx.x < s) redc[threadIdx.x] += redc[threadIdx.x + s];
    __syncthreads();
  }
  if (threadIdx.x == 0) {
    float gmax = fmaxf(fmaxf(rm[0], rm[1]), fmaxf(rm[2], rm[3]));
    float gmin = fminf(fminf(rn[0], rn[1]), fminf(rn[2], rn[3]));
    fbv[0] = 0.99f * fallback[0] + 0.005f * (gmax + gmin);
    mm[0] = (unsigned)redc[0];
  }
}

// merged front work (conv_v ELIMINATED): [0,640) weight converts; [640,2688) dv FC
__global__ __launch_bounds__(256)
void front_k(const float* __restrict__ wv, const float* __restrict__ w1,
             const float* __restrict__ w2,
             f16* __restrict__ owv, f16* __restrict__ ow1, f16* __restrict__ ow2,
             const float* __restrict__ uq, const float* __restrict__ Wf,
             const float* __restrict__ bfv, float* __restrict__ dv)
{
  const int blk = blockIdx.x;
  if (blk < 640) {
    int i = blk * 256 + threadIdx.x;   // 0..163839
    const float* src; f16* dst; int j;
    if (i < 65536)       { src = wv; dst = owv; j = i; }
    else if (i < 131072) { src = w1; dst = ow1; j = i - 65536; }
    else                 { src = w2; dst = ow2; j = i - 131072; }
    float4 x = *(const float4*)(src + (size_t)j * 4);
    f16x4 o = { (f16)x.x, (f16)x.y, (f16)x.z, (f16)x.w };
    *(f16x4*)(dst + (size_t)j * 4) = o;
  } else {
    const int gw   = ((blk - 640) * 256 + threadIdx.x) >> 6;  // 0..8191
    const int lane = threadIdx.x & 63;
    const int b = gw >> 9, j = gw & 511;
    const float* x  = uq + (size_t)b * 512;
    const float* wr = Wf + (size_t)j * 512;
    const int o = lane * 8;
    float4 x0 = *(const float4*)(x + o),  x1 = *(const float4*)(x + o + 4);
    float4 w0 = *(const float4*)(wr + o), w1v = *(const float4*)(wr + o + 4);
    float s = x0.x*w0.x + x0.y*w0.y + x0.z*w0.z + x0.w*w0.w
            + x1.x*w1v.x + x1.y*w1v.y + x1.z*w1v.z + x1.w*w1v.w;
#pragma unroll
    for (int off = 32; off >= 1; off >>= 1) s += __shfl_xor(s, off);
    if (lane == 0) dv[gw] = s + bfv[j];
  }
}

__global__ __launch_bounds__(256)
void softmax_rows(const f16* __restrict__ scores, const void* __restrict__ maskp,
                  const float* __restrict__ fbv, const unsigned* __restrict__ mm,
                  f16* __restrict__ Wt, float* __restrict__ wfb)
{
  __shared__ float red[8];
  const int row  = blockIdx.x;
  const int b    = row >> 10;
  const int tid  = threadIdx.x;
  const int lane = tid & 63, w = tid >> 6;
  const float fb = fbv[0];
  const unsigned mode = (mm[0] > 5000u) ? 1u : 0u;
  const f16* s = scores + (size_t)row * 1024;
  const int k0 = tid * 4;
  f16x4 sv = *(const f16x4*)(s + k0);
  float x[4];
  if (mode) {
    const unsigned char* m8 = (const unsigned char*)maskp + b * 1024 + k0;
    x[0] = m8[0] ? -1e9f : (float)sv[0];  x[1] = m8[1] ? -1e9f : (float)sv[1];
    x[2] = m8[2] ? -1e9f : (float)sv[2];  x[3] = m8[3] ? -1e9f : (float)sv[3];
  } else {
    const int* mi = (const int*)maskp + b * 1024 + k0;
    x[0] = mi[0] ? -1e9f : (float)sv[0];  x[1] = mi[1] ? -1e9f : (float)sv[1];
    x[2] = mi[2] ? -1e9f : (float)sv[2];  x[3] = mi[3] ? -1e9f : (float)sv[3];
  }
  float mx = fmaxf(fmaxf(x[0], x[1]), fmaxf(x[2], x[3]));
#pragma unroll
  for (int off = 32; off >= 1; off >>= 1) mx = fmaxf(mx, __shfl_xor(mx, off));
  if (lane == 0) red[w] = mx;
  __syncthreads();
  mx = fmaxf(fmaxf(fmaxf(red[0], red[1]), fmaxf(red[2], red[3])), fb);
  float e0 = expf(x[0] - mx), e1 = expf(x[1] - mx), e2 = expf(x[2] - mx), e3 = expf(x[3] - mx);
  float sum = (e0 + e1) + (e2 + e3);
#pragma unroll
  for (int off = 32; off >= 1; off >>= 1) sum += __shfl_xor(sum, off);
  if (lane == 0) red[4 + w] = sum;
  __syncthreads();
  float efb = expf(fb - mx);
  float Z = ((red[4] + red[5]) + (red[6] + red[7])) + efb;
  float inv = 1.0f / Z;
  f16x4 o = { (f16)(e0 * inv), (f16)(e1 * inv), (f16)(e2 * inv), (f16)(e3 * inv) };
  *(f16x4*)&Wt[(size_t)row * 1024 + k0] = o;
  if (tid == 0) wfb[row] = efb * inv;
}

// wave-per-output FC: Y[b,j] = act(X[b,:] . W[j,:] + bias[j])
template<int IN, int ACT>
__global__ __launch_bounds__(256)
void fc_wave(const float* __restrict__ X, const float* __restrict__ W,
             const float* __restrict__ bias, float* __restrict__ Y, int OutN)
{
  const int gw   = (blockIdx.x * 256 + threadIdx.x) >> 6;
  const int lane = threadIdx.x & 63;
  const int b = gw / OutN, j = gw - b * OutN;
  const float* x  = X + (size_t)b * IN;
  const float* wr = W + (size_t)j * IN;
  float s = 0.f;
  if constexpr (IN == 512) {
    const int o = lane * 8;
    float4 x0 = *(const float4*)(x + o),  x1 = *(const float4*)(x + o + 4);
    float4 w0 = *(const float4*)(wr + o), w1 = *(const float4*)(wr + o + 4);
    s = x0.x*w0.x + x0.y*w0.y + x0.z*w0.z + x0.w*w0.w
      + x1.x*w1.x + x1.y*w1.y + x1.z*w1.z + x1.w*w1.w;
  } else {
    const int o = lane * 4;
    float4 x0 = *(const float4*)(x + o);
    float4 w0 = *(const float4*)(wr + o);
    s = x0.x*w0.x + x0.y*w0.y + x0.z*w0.z + x0.w*w0.w;
  }
#pragma unroll
  for (int off = 32; off >= 1; off >>= 1) s += __shfl_xor(s, off);
  if (lane == 0) {
    float val = s + bias[ACT == 2 ? 0 : j];
    if constexpr (ACT == 1) val = fmaxf(val, 0.f);
    if constexpr (ACT == 2) val = tanhf(val);
    Y[gw] = val;
  }
}

__global__ __launch_bounds__(256)
void y_kernel(const f16* __restrict__ h2, const float* __restrict__ W3,
              const float* __restrict__ b3, float* __restrict__ outp)
{
  int row = blockIdx.x * 16 + (threadIdx.x >> 4);
  int l   = threadIdx.x & 15;
  const f16* h = h2 + (size_t)row * 256 + l * 16;
  float s = 0.f;
#pragma unroll
  for (int j = 0; j < 16; ++j) s += (float)h[j] * W3[l * 16 + j];
#pragma unroll
  for (int off = 1; off < 16; off <<= 1) s += __shfl_xor(s, off);
  if (l == 0) outp[row] = tanhf(s + b3[0]);
}

extern "C" void kernel_launch(void* const* d_in, const int* in_sizes, int n_in,
                              void* d_out, int out_size, void* d_ws, size_t ws_size,
                              hipStream_t stream) {
  const float* uq       = (const float*)d_in[0];
  const float* q        = (const float*)d_in[1];
  const float* kk       = (const float*)d_in[2];
  const float* v        = (const float*)d_in[3];
  const void*  mask     = d_in[4];
  const float* fallback = (const float*)d_in[5];
  const float* Wv = (const float*)d_in[6];
  const float* bv = (const float*)d_in[7];
  const float* Wf = (const float*)d_in[8];
  const float* bf = (const float*)d_in[9];
  const float* W1 = (const float*)d_in[10];
  const float* b1 = (const float*)d_in[11];
  const float* W2 = (const float*)d_in[12];
  const float* b2 = (const float*)d_in[13];
  const float* W3 = (const float*)d_in[14];
  const float* b3 = (const float*)d_in[15];
  float* outp = (float*)d_out;

  char* ws = (char*)d_ws;
  const size_t MB = 1ull << 20;
  f16*  scores = (f16*)ws;
  f16*  h1b  = (f16*)ws;
  f16*  h2b  = (f16*)(ws + 16 * MB);
  f16*  vpt  = (f16*)(ws + 32 * MB);
  f16*  outb = (f16*)(ws + 48 * MB);
  f16*  wts  = (f16*)(ws + 64 * MB);
  char* cst  = ws + 112 * MB;
  f16*  Wv16 = (f16*)(cst);
  f16*  W116 = (f16*)(cst + 512 * 1024);
  f16*  W216 = (f16*)(cst + 1024 * 1024);
  float* dv   = (float*)(cst + 1280 * 1024);
  float* wfb  = (float*)(cst + 1312 * 1024);
  float* h1d  = (float*)(cst + 1376 * 1024);
  float* h2d  = (float*)(cst + 1408 * 1024);
  unsigned* mm = (unsigned*)(cst + 1424 * 1024);
  float* fbv   = (float*)(cst + 1428 * 1024);
  float* mmarr = (float*)(cst + 1432 * 1024);   // 2 * 256 floats

  // weight converts + dv FC (conv_v eliminated; vpt reads v f32 directly)
  front_k<<<2688, 256, 0, stream>>>(Wv, W1, W2, Wv16, W116, W216,
                                    uq, Wf, bf, dv);

  // scores = q @ k^T / sqrt(512) -> f16, q/k read as f32, reg-staged to f16 LDS
  gemm256_scores<<<256, 512, 0, stream>>>(q, kk, scores, 0.04419417382415922f, mmarr);

  reduce_mm<<<1, 256, 0, stream>>>(mmarr, 256, fallback, fbv,
                                   (const unsigned char*)mask, mm);

  softmax_rows<<<16384, 256, 0, stream>>>(scores, mask, fbv, mm, wts, wfb);

  // vpt[d][k] = sum_e Wv[d][e] v[k][e] + bv[d]  (v read f32 directly)
  gemm_vpt<<<512, 256, 0, stream>>>(Wv16, v, vpt, bv);

  // out = weights @ vp + wfb*dv
  gemm_bt<EPI_OUT, true><<<512, 256, 0, stream>>>(
      wts, vpt, outb, 1024, 1024, 512, 1024,
      1048576LL, 524288LL, 524288LL,
      nullptr, 1.f, nullptr, 0, wfb, dv, 4, 32);

  // h1 = relu(out @ W1^T + b1)
  gemm_bt<EPI_RELU, false><<<512, 256, 0, stream>>>(
      outb, W116, h1b, 512, 512, 512, 512, 0LL, 0LL, 0LL,
      b1, 1.f, nullptr, 0, nullptr, nullptr, 4, 512);

  // h2 = relu(h1 @ W2^T + b2)
  gemm_bt<EPI_RELU, false><<<256, 256, 0, stream>>>(
      h1b, W216, h2b, 512, 512, 256, 512, 0LL, 0LL, 0LL,
      b2, 1.f, nullptr, 0, nullptr, nullptr, 2, 256);

  y_kernel<<<1024, 256, 0, stream>>>(h2b, W3, b3, outp);

  // default-values scorer branch (f32, wave-per-output)
  fc_wave<512, 1><<<2048, 256, 0, stream>>>(dv, W1, b1, h1d, 512);
  fc_wave<512, 1><<<1024, 256, 0, stream>>>(h1d, W2, b2, h2d, 256);
  fc_wave<256, 2><<<4, 256, 0, stream>>>(h2d, W3, b3, outp + 16384, 1);

  (void)in_sizes; (void)n_in; (void)out_size; (void)ws_size;
}